// Round 10
// baseline (298.711 us; speedup 1.0000x reference)
//
#include <hip/hip_runtime.h>
#include <hip/hip_bf16.h>

#define NN 8192
#define EE 65536

typedef unsigned short u16;
typedef __attribute__((ext_vector_type(8))) short bf16x8;          // 8 bf16 = 4 VGPRs
typedef __attribute__((ext_vector_type(8))) unsigned short u16x8;  // 16 B load
typedef __attribute__((ext_vector_type(4))) float f32x4;

// Pre-split weight table offsets (elements, shared by h/l planes).
// W0..MAGB regions in MFMA-fragment-contiguous order; W3M/MAGB plane-major
// in the output dim. LINS/LINV/SKS/SKV row-major (R8 layout — the R9
// fragment-contiguous LINS/LINV went with the failed gather fusion).
#define OFF_W0    0        // 4   tiles (nt)
#define OFF_W1    2048     // 8   tiles (nt*2+ks)
#define OFF_W2    6144     // 8   tiles
#define OFF_W3M   10240    // 96  tiles ((g*4+nt)*3+ks)
#define OFF_MAGB  59392    // 40  tiles (p*4+nt)
#define OFF_LINS  79872    // 64 x 320
#define OFF_LINV  100352   // 64 x 512
#define OFF_SKS   133120   // 64 x 640  (skip_s reshaped [w][u*10+v], *1/fan)
#define OFF_SKV   174080   // 64 x 640  (skip_v)
#define WT_TOTAL  215040

// R8 plane schedule: each tpv plane is immediately followed by the wm planes
// that multiply it, so only ONE tpv plane (8 u32) is ever live in registers.
// kind: 0 = W3M tile-group (K=96, 3 ks sub-tiles), 1 = MAGB (K=32).
// tile: g for W3M, p for MAGB. role: -1 = tpv (save), else product plane idx.
__device__ const int PKIND[18] = {0,0,0, 0,0,1, 0,1,1,1, 0,1,1,1, 0,1,1,1};
__device__ const int PTILE[18] = {0,5,6, 3,7,0, 1,1,2,3, 2,4,5,6, 4,7,8,9};
__device__ const int PROLE[18] = {-1,0,1, -1,2,3, -1,4,5,6, -1,7,8,9, -1,10,11,12};

__device__ __forceinline__ u16 f2bf(float f) {
  __hip_bfloat16 h = __float2bfloat16(f);
  return *reinterpret_cast<u16*>(&h);
}
__device__ __forceinline__ float bf2f(u16 v) {
  union { unsigned int u; float f; } x; x.u = ((unsigned int)v) << 16; return x.f;
}
__device__ __forceinline__ void split2(float x, u16& h, u16& l) {
  __hip_bfloat16 bh = __float2bfloat16(x);
  h = *reinterpret_cast<u16*>(&bh);
  float r = x - __bfloat162float(bh);
  __hip_bfloat16 bl = __float2bfloat16(r);
  l = *reinterpret_cast<u16*>(&bl);
}

#define MFMA(a, b, c) __builtin_amdgcn_mfma_f32_16x16x32_bf16((a), (b), (c), 0, 0, 0)

// ---------------------------------------------------------------------------
// FUSED edge pipeline (R10 = R8 + BARRIER-FREE plane loop ONLY; the R9
// gather-fusion half failed correctness and is reverted — bisect).
// R8 was barrier-bound: 72 syncthreads (one per staged nt-step), each
// draining vmcnt so weight loads, plane stores and MFMA ran in lockstep
// (MfmaUtil 19.6 + VALUBusy 26 = half the issue slots idle; write rate only
// 1.7 TB/s). The LDS staging existed to dedupe the 4 waves' weight reads —
// but with fragment-contiguous tiles a direct load is a single 1 KB wave
// request that L1 dedupes naturally (the L0/L1/L2 MLP phase already runs
// this way, barrier-free). So: Bs dropped, weights loaded direct per step
// at the SAME addresses R8 staged from (byte-identical MFMA inputs); the
// unrolled nt x4 loop gives ~24 loads in flight per pl step; plane stores
// are never drained mid-kernel. LDS 40960 -> 28672. Numerics identical.
// ---------------------------------------------------------------------------
__global__ __launch_bounds__(256, 4) void k_edge(
    const u16* __restrict__ efm_h, const u16* __restrict__ efm_l,
    const u16* __restrict__ wt_h, const u16* __restrict__ wt_l,
    u16* __restrict__ cmbP)
{
  __shared__ u16 Hh[64 * 72], Hl[64 * 72];   // h, K=64 (18432 B)
  __shared__ u16 Ct[64 * 80];                // output staging, quad-XOR swizzled (10240 B)
  const int tid  = threadIdx.x;
  const size_t pos0 = (size_t)blockIdx.x * 64;
  const int wave = tid >> 6, lane = tid & 63;
  const int quad = lane >> 4, lrow = lane & 15;
  const int kbase = quad * 8;
  const int rw = wave * 16;

  // ---- E fragments directly from global (K=16 zero-padded to 32) ----
  bf16x8 eah = {}, eal = {};
  if (quad < 2) {
    eah = *reinterpret_cast<const bf16x8*>(&efm_h[(pos0 + rw + lrow) * 16 + kbase]);
    eal = *reinterpret_cast<const bf16x8*>(&efm_l[(pos0 + rw + lrow) * 16 + kbase]);
  }

  // ---- L0: h = silu(efm @ w0), K=32 (padded), N=64 — contiguous frag loads ----
  {
    #pragma unroll
    for (int nt = 0; nt < 4; ++nt) {
      const size_t bo = (size_t)nt * 512 + lane * 8;
      const bf16x8 fbh = *reinterpret_cast<const bf16x8*>(wt_h + OFF_W0 + bo);
      const bf16x8 fbl = *reinterpret_cast<const bf16x8*>(wt_l + OFF_W0 + bo);
      f32x4 acc = {};
      acc = MFMA(eah, fbh, acc); acc = MFMA(eah, fbl, acc); acc = MFMA(eal, fbh, acc);
      #pragma unroll
      for (int r = 0; r < 4; ++r) {
        float t = acc[r];
        t = t / (1.0f + __expf(-t));
        u16 hh, ll; split2(t, hh, ll);
        const int row = rw + quad * 4 + r, col = nt * 16 + lrow;
        Hh[row * 72 + col] = hh; Hl[row * 72 + col] = ll;
      }
    }
  }

  // ---- L1, L2: h = silu(h @ w), K=64, N=64, in-place ----
  #pragma unroll
  for (int layer = 0; layer < 2; ++layer) {
    const int OFF = layer ? OFF_W2 : OFF_W1;
    bf16x8 fah[2], fal[2];
    #pragma unroll
    for (int ks = 0; ks < 2; ++ks) {
      fah[ks] = *reinterpret_cast<const bf16x8*>(&Hh[(rw + lrow) * 72 + ks * 32 + kbase]);
      fal[ks] = *reinterpret_cast<const bf16x8*>(&Hl[(rw + lrow) * 72 + ks * 32 + kbase]);
    }
    f32x4 acc[4] = {};
    #pragma unroll
    for (int nt = 0; nt < 4; ++nt)
      #pragma unroll
      for (int ks = 0; ks < 2; ++ks) {
        const size_t bo = (size_t)(nt * 2 + ks) * 512 + lane * 8;
        const bf16x8 fbh = *reinterpret_cast<const bf16x8*>(wt_h + OFF + bo);
        const bf16x8 fbl = *reinterpret_cast<const bf16x8*>(wt_l + OFF + bo);
        acc[nt] = MFMA(fah[ks], fbh, acc[nt]);
        acc[nt] = MFMA(fah[ks], fbl, acc[nt]);
        acc[nt] = MFMA(fal[ks], fbh, acc[nt]);
      }
    #pragma unroll
    for (int nt = 0; nt < 4; ++nt)
      #pragma unroll
      for (int r = 0; r < 4; ++r) {
        float t = acc[nt][r];
        t = t / (1.0f + __expf(-t));
        u16 hh, ll; split2(t, hh, ll);
        const int row = rw + quad * 4 + r, col = nt * 16 + lrow;
        Hh[row * 72 + col] = hh; Hl[row * 72 + col] = ll;
      }
  }

  // ---- 18 plane computations, single live tpv plane, direct weight loads ----
  {
    bf16x8 fah[3], fal[3];
    #pragma unroll
    for (int ks = 0; ks < 2; ++ks) {
      fah[ks] = *reinterpret_cast<const bf16x8*>(&Hh[(rw + lrow) * 72 + ks * 32 + kbase]);
      fal[ks] = *reinterpret_cast<const bf16x8*>(&Hl[(rw + lrow) * 72 + ks * 32 + kbase]);
    }
    fah[2] = eah; fal[2] = eal;

    // wave-local store of the finished product plane from Ct
    auto STORE_P = [&](u16* dst) {
      #pragma unroll
      for (int i = 0; i < 2; ++i) {
        const int idx = lane + i * 64;       // 128 uint4 = 16 rows x 8 chunks
        const int rl = idx >> 3, c2 = idx & 7;
        const uint4 v4 = *reinterpret_cast<const uint4*>(
            &Ct[(rw + rl) * 80 + ((c2 * 8) ^ (((rl >> 2) & 3) << 4))]);
        *reinterpret_cast<uint4*>(&dst[(pos0 + rw + rl) * 64 + c2 * 8]) = v4;
      }
    };

    unsigned int tp[4][2];                   // current tpv plane only (8 u32)
    for (int pl = 0; pl < 18; ++pl) {
      const int kind = PKIND[pl], tile = PTILE[pl], role = PROLE[pl];
      #pragma unroll
      for (int nt = 0; nt < 4; ++nt) {
        f32x4 acc = {};
        if (kind == 0) {
          const size_t base = (size_t)OFF_W3M + (size_t)(tile * 4 + nt) * 1536 + lane * 8;
          #pragma unroll
          for (int ks = 0; ks < 3; ++ks) {
            const bf16x8 bh = *reinterpret_cast<const bf16x8*>(wt_h + base + ks * 512);
            const bf16x8 bl = *reinterpret_cast<const bf16x8*>(wt_l + base + ks * 512);
            acc = MFMA(fah[ks], bh, acc); acc = MFMA(fah[ks], bl, acc); acc = MFMA(fal[ks], bh, acc);
          }
        } else {
          const size_t base = (size_t)OFF_MAGB + (size_t)(tile * 4 + nt) * 512 + lane * 8;
          const bf16x8 bh = *reinterpret_cast<const bf16x8*>(wt_h + base);
          const bf16x8 bl = *reinterpret_cast<const bf16x8*>(wt_l + base);
          acc = MFMA(fah[2], bh, acc); acc = MFMA(fah[2], bl, acc); acc = MFMA(fal[2], bh, acc);
        }
        if (role < 0) {
          tp[nt][0] = (unsigned)f2bf(acc[0]) | ((unsigned)f2bf(acc[1]) << 16);
          tp[nt][1] = (unsigned)f2bf(acc[2]) | ((unsigned)f2bf(acc[3]) << 16);
        } else {
          #pragma unroll
          for (int r = 0; r < 4; ++r) {
            const float tv = bf2f((u16)((tp[nt][r >> 1] >> ((r & 1) * 16)) & 0xffffu));
            Ct[(rw + quad * 4 + r) * 80 + ((nt * 16 + lrow) ^ (quad << 4))] = f2bf(acc[r] * tv);
          }
        }
      }
      if (role >= 0) STORE_P(cmbP + (size_t)role * ((size_t)EE * 64));
    }
  }
}

// ---------------------------------------------------------------------------
// MFMA GEMM, fp32-equivalent via 3-term bf16 split (kept for the node linears).
// ---------------------------------------------------------------------------
template<int RT, int OUT, bool SILU, int DDIV>
__global__ __launch_bounds__(256) void k_mgemm(
    const u16* __restrict__ X1h, const u16* __restrict__ X1l, int x1rs, int K1,
    const u16* __restrict__ X2h, const u16* __restrict__ X2l, int x2rs, int K2,
    const u16* __restrict__ Wth, const u16* __restrict__ Wtl, int K,
    void* __restrict__ O1, void* __restrict__ O2, int ors,
    const float* __restrict__ dens)
{
  constexpr int NTN = (RT == 128) ? 4 : 1;
  constexpr int AIT = RT * 8 / 256;
  __shared__ u16 Ah[RT * 40];
  __shared__ u16 Al[RT * 40];
  __shared__ u16 Bh[64 * 40];
  __shared__ u16 Bl[64 * 40];
  const int tid  = threadIdx.x;
  const int row0 = blockIdx.x * RT;
  const int col0 = blockIdx.y * 64;
  const int wave = tid >> 6, lane = tid & 63;
  const int quad = lane >> 4, lrow = lane & 15;
  const int kbase = quad * 8;
  const int rw  = (RT == 128) ? wave * 32 : 0;
  const int ntb = (RT == 128) ? 0 : wave;

  f32x4 acc[2][NTN] = {};

  for (int k0 = 0; k0 < K; k0 += 32) {
    #pragma unroll
    for (int i = 0; i < AIT; ++i) {
      const int idx = tid + i * 256;
      const int b = idx / (RT * 4), rc = idx & (RT * 4 - 1);
      const int r = rc >> 2, c = rc & 3;
      const int gk = k0 + c * 8;
      uint4 v = make_uint4(0u, 0u, 0u, 0u);
      if (gk < K1)
        v = *reinterpret_cast<const uint4*>(&(b ? X1l : X1h)[(size_t)(row0 + r) * x1rs + gk]);
      else if (gk - K1 < K2)
        v = *reinterpret_cast<const uint4*>(&(b ? X2l : X2h)[(size_t)(row0 + r) * x2rs + gk - K1]);
      *reinterpret_cast<uint4*>(&(b ? Al : Ah)[r * 40 + c * 8]) = v;
    }
    #pragma unroll
    for (int i = 0; i < 2; ++i) {
      const int idx = tid + i * 256;
      const int b = idx >> 8, rc = idx & 255;
      const int n = rc >> 2, c = rc & 3;
      const uint4 v = *reinterpret_cast<const uint4*>(
          &(b ? Wtl : Wth)[(size_t)(col0 + n) * K + k0 + c * 8]);
      *reinterpret_cast<uint4*>(&(b ? Bl : Bh)[n * 40 + c * 8]) = v;
    }
    __syncthreads();

    bf16x8 fah[2], fal[2], fbh[NTN], fbl[NTN];
    #pragma unroll
    for (int mt = 0; mt < 2; ++mt) {
      const int ro = (rw + mt * 16 + lrow) * 40 + kbase;
      fah[mt] = *reinterpret_cast<const bf16x8*>(&Ah[ro]);
      fal[mt] = *reinterpret_cast<const bf16x8*>(&Al[ro]);
    }
    #pragma unroll
    for (int nt = 0; nt < NTN; ++nt) {
      const int ro = ((ntb + nt) * 16 + lrow) * 40 + kbase;
      fbh[nt] = *reinterpret_cast<const bf16x8*>(&Bh[ro]);
      fbl[nt] = *reinterpret_cast<const bf16x8*>(&Bl[ro]);
    }
    #pragma unroll
    for (int mt = 0; mt < 2; ++mt)
      #pragma unroll
      for (int nt = 0; nt < NTN; ++nt) {
        acc[mt][nt] = MFMA(fah[mt], fbh[nt], acc[mt][nt]);
        acc[mt][nt] = MFMA(fah[mt], fbl[nt], acc[mt][nt]);
        acc[mt][nt] = MFMA(fal[mt], fbh[nt], acc[mt][nt]);
      }
    __syncthreads();
  }

  #pragma unroll
  for (int mt = 0; mt < 2; ++mt)
    #pragma unroll
    for (int nt = 0; nt < NTN; ++nt)
      #pragma unroll
      for (int r = 0; r < 4; ++r) {
        const int grow = row0 + rw + mt * 16 + quad * 4 + r;
        const int gcol = col0 + (ntb + nt) * 16 + lrow;
        float t = acc[mt][nt][r];
        if (SILU) t = t / (1.0f + __expf(-t));
        if (DDIV > 0) t *= 1.0f / (dens[grow / DDIV] + 1.0f);
        const size_t oi = (size_t)grow * ors + gcol;
        if (OUT == 0) {
          reinterpret_cast<float*>(O1)[oi] = t;
        } else if (OUT == 1) {
          u16 hh, ll;
          split2(t, hh, ll);
          reinterpret_cast<u16*>(O1)[oi] = hh;
          reinterpret_cast<u16*>(O2)[oi] = ll;
        } else {
          reinterpret_cast<u16*>(O1)[oi] = f2bf(t);
        }
      }
}

// ---------------------------------------------------------------------------
// Skip contraction as MFMA GEMM, MERGED, writing DIRECTLY into out (N,64,4).
// ---------------------------------------------------------------------------
__global__ __launch_bounds__(256) void k_skipm(
    const float* __restrict__ ms2, const float* __restrict__ mv2,
    const float* __restrict__ na,
    const u16* __restrict__ wt_h, const u16* __restrict__ wt_l,
    float* __restrict__ out)
{
  __shared__ u16 Ah[32 * 40];
  __shared__ u16 Al[32 * 40];
  __shared__ u16 Bh[64 * 40];
  __shared__ u16 Bl[64 * 40];
  const int tid  = threadIdx.x;
  const bool isv = blockIdx.x >= (NN / 32);
  const int row0 = (isv ? (blockIdx.x - NN / 32) : blockIdx.x) * 32;
  const float* C = isv ? mv2 : ms2;
  const u16* Bth = wt_h + (isv ? OFF_SKV : OFF_SKS);
  const u16* Btl = wt_l + (isv ? OFF_SKV : OFF_SKS);
  const int wave = tid >> 6, lane = tid & 63;
  const int quad = lane >> 4, lrow = lane & 15;
  const int kbase = quad * 8;

  f32x4 acc[2] = {};

  for (int k0 = 0; k0 < 640; k0 += 32) {
    #pragma unroll
    for (int i = 0; i < 4; ++i) {
      const int e = tid + i * 256;
      const int r = e >> 5, kk = e & 31;
      const int k = k0 + kk;
      const int u = k / 10, v = k - u * 10;
      const int row = row0 + r;
      const int n = isv ? (row / 3) : row;
      const float t = C[(size_t)row * 64 + u] * na[n * 10 + v];
      u16 hh, ll;
      split2(t, hh, ll);
      Ah[r * 40 + kk] = hh;
      Al[r * 40 + kk] = ll;
    }
    #pragma unroll
    for (int i = 0; i < 2; ++i) {
      const int idx = tid + i * 256;
      const int b = idx >> 8, rc = idx & 255;
      const int nw = rc >> 2, c = rc & 3;
      const uint4 v4 = *reinterpret_cast<const uint4*>(
          &(b ? Btl : Bth)[(size_t)nw * 640 + k0 + c * 8]);
      *reinterpret_cast<uint4*>(&(b ? Bl : Bh)[nw * 40 + c * 8]) = v4;
    }
    __syncthreads();

    bf16x8 fah[2], fal[2], fbh, fbl;
    #pragma unroll
    for (int mt = 0; mt < 2; ++mt) {
      const int ro = (mt * 16 + lrow) * 40 + kbase;
      fah[mt] = *reinterpret_cast<const bf16x8*>(&Ah[ro]);
      fal[mt] = *reinterpret_cast<const bf16x8*>(&Al[ro]);
    }
    {
      const int ro = (wave * 16 + lrow) * 40 + kbase;
      fbh = *reinterpret_cast<const bf16x8*>(&Bh[ro]);
      fbl = *reinterpret_cast<const bf16x8*>(&Bl[ro]);
    }
    #pragma unroll
    for (int mt = 0; mt < 2; ++mt) {
      acc[mt] = MFMA(fah[mt], fbh, acc[mt]);
      acc[mt] = MFMA(fah[mt], fbl, acc[mt]);
      acc[mt] = MFMA(fal[mt], fbh, acc[mt]);
    }
    __syncthreads();
  }

  #pragma unroll
  for (int mt = 0; mt < 2; ++mt)
    #pragma unroll
    for (int r = 0; r < 4; ++r) {
      const int row = row0 + mt * 16 + quad * 4 + r;
      const int w = wave * 16 + lrow;
      if (isv) {
        const int n = row / 3, i = row - n * 3;
        out[(size_t)n * 256 + w * 4 + 1 + i] = acc[mt][r];
      } else {
        out[(size_t)row * 256 + w * 4] = acc[mt][r];
      }
    }
}

// ---------------------------------------------------------------------------
// fp32 tiled GEMM (node up-projections): OUT = scale * X@W
// ---------------------------------------------------------------------------
template<int RT>
__global__ __launch_bounds__(256) void k_gemm(
    const float* __restrict__ X, int xrs, int xes, int xco, int xcob,
    const float* __restrict__ W, int K, int NOUT,
    float scale, float* __restrict__ OUTp, int ors, int oob)
{
  constexpr int RPT = RT / 16;
  __shared__ float Xs[RT * 65];
  __shared__ float Ws[64 * 64];
  const int tid  = threadIdx.x;
  const int row0 = blockIdx.x * RT;
  const int col0 = blockIdx.y * 64;
  const int z    = blockIdx.z;
  const int xc   = xco + z * xcob;
  const int oo   = z * oob;
  const int ci = tid & 15;
  const int ri = tid >> 4;
  float acc[RPT][4] = {};

  for (int k0 = 0; k0 < K; k0 += 64) {
    const int kc  = (K - k0 >= 64) ? 64 : (K - k0);
    const int ksh = (kc == 64) ? 6 : 4;
    for (int idx = tid; idx < kc * RT; idx += 256) {
      const int r = idx >> ksh, kk = idx & (kc - 1);
      Xs[r * 65 + kk] = X[(size_t)(row0 + r) * xrs + xc + (size_t)(k0 + kk) * xes];
    }
    for (int idx = tid; idx < (kc << 6); idx += 256) {
      const int kk = idx >> 6, c = idx & 63;
      Ws[kk * 64 + c] = W[(size_t)(k0 + kk) * NOUT + col0 + c];
    }
    __syncthreads();
    for (int kk = 0; kk < kc; ++kk) {
      const float4 wv = *reinterpret_cast<const float4*>(&Ws[kk * 64 + ci * 4]);
      #pragma unroll
      for (int j = 0; j < RPT; ++j) {
        const float x = Xs[(ri * RPT + j) * 65 + kk];
        acc[j][0] += x * wv.x; acc[j][1] += x * wv.y;
        acc[j][2] += x * wv.z; acc[j][3] += x * wv.w;
      }
    }
    __syncthreads();
  }

  #pragma unroll
  for (int j = 0; j < RPT; ++j) {
    const int row = row0 + ri * RPT + j;
    *reinterpret_cast<float4*>(OUTp + (size_t)row * ors + oo + col0 + ci * 4) =
        make_float4(acc[j][0] * scale, acc[j][1] * scale, acc[j][2] * scale, acc[j][3] * scale);
  }
}

// ---------------------------------------------------------------------------
// CSR build
// ---------------------------------------------------------------------------
__global__ __launch_bounds__(256) void k_count(const int* __restrict__ rcv, int* __restrict__ counts) {
  const int e = blockIdx.x * 256 + threadIdx.x;
  atomicAdd(&counts[rcv[e]], 1);
}

__global__ __launch_bounds__(1024) void k_scan(const int* __restrict__ counts,
                                               int* __restrict__ offs, int* __restrict__ cursor) {
  __shared__ int part[1024];
  const int tid = threadIdx.x;
  int local[8];
  int s = 0;
  #pragma unroll
  for (int j = 0; j < 8; ++j) { local[j] = s; s += counts[tid * 8 + j]; }
  part[tid] = s;
  __syncthreads();
  for (int off = 1; off < 1024; off <<= 1) {
    int v = 0;
    if (tid >= off) v = part[tid - off];
    __syncthreads();
    part[tid] += v;
    __syncthreads();
  }
  const int base = part[tid] - s;
  #pragma unroll
  for (int j = 0; j < 8; ++j) {
    const int o = base + local[j];
    offs[tid * 8 + j] = o;
    cursor[tid * 8 + j] = o;
  }
  if (tid == 1023) offs[NN] = part[1023];
}

__global__ __launch_bounds__(256) void k_fill(const int* __restrict__ rcv,
                                              int* __restrict__ cursor, int* __restrict__ perm) {
  const int e = blockIdx.x * 256 + threadIdx.x;
  const int pos = atomicAdd(&cursor[rcv[e]], 1);
  perm[pos] = e;
}

// ---------------------------------------------------------------------------
// Build the pre-split, pre-scaled weight table. Fragment-contiguous tiles;
// W3M/MAGB value maps plane-major in the output dim (R8 layout, verbatim).
// ---------------------------------------------------------------------------
__global__ __launch_bounds__(256) void k_permw(
    const float* __restrict__ w0, const float* __restrict__ w1,
    const float* __restrict__ w2, const float* __restrict__ w3,
    const float* __restrict__ mag_w, const float* __restrict__ lin_s,
    const float* __restrict__ lin_v, const float* __restrict__ skip_s,
    const float* __restrict__ skip_v,
    u16* __restrict__ wt_h, u16* __restrict__ wt_l)
{
  const int id = blockIdx.x * 256 + threadIdx.x;   // WT_TOTAL threads
  float val = 0.f;
  if (id < OFF_W1) {                       // W0: 4 tiles (nt)
    const int i = id - OFF_W0;
    const int tile = i >> 9, rem = i & 511, lane = rem >> 3, e = rem & 7;
    const int quad = lane >> 4, lrow = lane & 15;
    const int n = tile * 16 + lrow, k = quad * 8 + e;
    val = (k < 16) ? w0[k * 64 + n] * 0.25f : 0.f;
  } else if (id < OFF_W2) {                // W1: 8 tiles (nt*2+ks)
    const int i = id - OFF_W1;
    const int tile = i >> 9, rem = i & 511, lane = rem >> 3, e = rem & 7;
    const int quad = lane >> 4, lrow = lane & 15;
    const int n = (tile >> 1) * 16 + lrow, k = (tile & 1) * 32 + quad * 8 + e;
    val = w1[k * 64 + n] * 0.125f;
  } else if (id < OFF_W3M) {               // W2: 8 tiles
    const int i = id - OFF_W2;
    const int tile = i >> 9, rem = i & 511, lane = rem >> 3, e = rem & 7;
    const int quad = lane >> 4, lrow = lane & 15;
    const int n = (tile >> 1) * 16 + lrow, k = (tile & 1) * 32 + quad * 8 + e;
    val = w2[k * 64 + n] * 0.125f;
  } else if (id < OFF_MAGB) {              // W3M: 96 tiles ((g*4+nt)*3+ks), plane-major
    const int i = id - OFF_W3M;
    const int tile = i >> 9, rem = i & 511, lane = rem >> 3, e = rem & 7;
    const int quad = lane >> 4, lrow = lane & 15;
    const int gnt = tile / 3, ks = tile - gnt * 3;
    const int n = (gnt >> 2) * 64 + (gnt & 3) * 16 + lrow;   // plane g = n>>6
    const int k = ks * 32 + quad * 8 + e;
    if (n < 320) {                         // tpv planes 0-4, w3 natural (j*64+u)
      val = (k < 64) ? w3[k * 320 + n] * 0.125f : 0.f;
    } else {                               // wm planes 0-2 (from mag rows)
      const int p = (n - 320) >> 6, u = n & 63;
      val = (k >= 64 && k < 80) ? mag_w[(k - 64) * 832 + p * 64 + u] * 0.25f : 0.f;
    }
  } else if (id < OFF_LINS) {              // MAGB: 40 tiles (p*4+nt), plane-major
    const int i = id - OFF_MAGB;
    const int tile = i >> 9, rem = i & 511, lane = rem >> 3, e = rem & 7;
    const int quad = lane >> 4, lrow = lane & 15;
    const int n = (tile >> 2) * 64 + (tile & 3) * 16 + lrow; // p = n>>6, u = n&63
    const int k = quad * 8 + e;
    const int p = n >> 6, u = n & 63;
    val = (k < 16) ? mag_w[k * 832 + (3 + p) * 64 + u] * 0.25f : 0.f;
  } else if (id < OFF_LINV) {
    const int i = id - OFF_LINS, n = i / 320, k = i - n * 320;
    val = lin_s[k * 64 + n] * 0.05590169944f;
  } else if (id < OFF_SKS) {
    const int i = id - OFF_LINV, n = i >> 9, k = i & 511;
    val = lin_v[k * 64 + n] * 0.04419417382f;
  } else if (id < OFF_SKV) {
    const int i = id - OFF_SKS, w = i / 640, k = i - w * 640;
    val = skip_s[k * 64 + w] * 0.03952847075f;   // [u*10+v][w], 1/sqrt(640)
  } else if (id < WT_TOTAL) {
    const int i = id - OFF_SKV, w = i / 640, k = i - w * 640;
    val = skip_v[k * 64 + w] * 0.03952847075f;
  } else {
    return;
  }
  u16 hh, ll;
  split2(val, hh, ll);
  wt_h[id] = hh;
  wt_l[id] = ll;
}

// ---------------------------------------------------------------------------
// Permute edge data into receiver-grouped (perm) order + precompute:
//   snd_perm, ya_perm, dq_perm (tanh(q^2)), efm split pair.
// ---------------------------------------------------------------------------
__global__ __launch_bounds__(256) void k_build(
    const int* __restrict__ perm, const int* __restrict__ snd,
    const float* __restrict__ edge_attrs, const float* __restrict__ edge_feats,
    const float* __restrict__ mm_inv, const float* __restrict__ dens_w,
    int* __restrict__ snd_perm, float* __restrict__ ya_perm,
    float* __restrict__ dq_perm, u16* __restrict__ efm_h, u16* __restrict__ efm_l)
{
  const int pos = blockIdx.x * 256 + threadIdx.x;
  const int e = perm[pos];
  const int s = snd[e];
  snd_perm[pos] = s;
  reinterpret_cast<float4*>(ya_perm)[pos] = reinterpret_cast<const float4*>(edge_attrs)[e];
  const float4 ef0 = reinterpret_cast<const float4*>(edge_feats)[e * 2];
  const float4 ef1 = reinterpret_cast<const float4*>(edge_feats)[e * 2 + 1];
  const float4 mi0 = reinterpret_cast<const float4*>(mm_inv)[s * 2];
  const float4 mi1 = reinterpret_cast<const float4*>(mm_inv)[s * 2 + 1];
  float q = ef0.x * dens_w[0] + ef0.y * dens_w[1] + ef0.z * dens_w[2] + ef0.w * dens_w[3]
          + ef1.x * dens_w[4] + ef1.y * dens_w[5] + ef1.z * dens_w[6] + ef1.w * dens_w[7];
  q *= 0.35355339059f;   // 1/sqrt(8)
  dq_perm[pos] = tanhf(q * q);
  float vals[16] = { ef0.x, ef0.y, ef0.z, ef0.w, ef1.x, ef1.y, ef1.z, ef1.w,
                     mi0.x, mi0.y, mi0.z, mi0.w, mi1.x, mi1.y, mi1.z, mi1.w };
  u16 hh[16], ll[16];
  #pragma unroll
  for (int i = 0; i < 16; ++i) split2(vals[i], hh[i], ll[i]);
  reinterpret_cast<uint4*>(&efm_h[(size_t)pos * 16])[0] = reinterpret_cast<uint4*>(hh)[0];
  reinterpret_cast<uint4*>(&efm_h[(size_t)pos * 16])[1] = reinterpret_cast<uint4*>(hh)[1];
  reinterpret_cast<uint4*>(&efm_l[(size_t)pos * 16])[0] = reinterpret_cast<uint4*>(ll)[0];
  reinterpret_cast<uint4*>(&efm_l[(size_t)pos * 16])[1] = reinterpret_cast<uint4*>(ll)[1];
}

// ---------------------------------------------------------------------------
// Gather: TWO half-waves per node (halved serial edge chain, LDS reduction).
// Reads the 13 product planes c_p (tpv folded into the coefficients in
// k_edge); per edge each lane reads 13 x 2 B (one 128 B segment per plane).
// R8 version, verbatim (writes ms/mv h/l pairs for the k_mgemm node linears).
// ---------------------------------------------------------------------------
__global__ __launch_bounds__(256) void k_gather(
    const int* __restrict__ snd_perm,
    const float* __restrict__ ya_perm,
    const float* __restrict__ dq_perm,
    const float* __restrict__ mm_attrs,
    const float* __restrict__ s_buf,
    const float* __restrict__ v_buf,
    const u16* __restrict__ cmbP,
    const int* __restrict__ offs,
    u16* __restrict__ ms_h, u16* __restrict__ ms_l,
    u16* __restrict__ mv_h, u16* __restrict__ mv_l,
    float* __restrict__ dens)
{
  __shared__ float red[2][30][64];
  const int tid  = threadIdx.x;
  const int lane = tid & 63;
  const int nib  = tid >> 7;                 // node within block (0/1)
  const int half = (tid >> 6) & 1;           // segment half (0/1)
  const int n = blockIdx.x * 2 + nib;

  float acc_s[5] = {0.f, 0.f, 0.f, 0.f, 0.f};
  float acc_v[8][3] = {};
  float dacc = 0.f;
  const int start0 = offs[n], end0 = offs[n + 1];
  const int mid = start0 + ((end0 - start0 + 1) >> 1);
  const int start = half ? mid : start0;
  const int end   = half ? end0 : mid;

  int s_nx = 0;
  if (start < end) s_nx = snd_perm[start];
  for (int pos = start; pos < end; ++pos) {
    const int s = s_nx;
    if (pos + 1 < end) s_nx = snd_perm[pos + 1];

    const float4 ya = reinterpret_cast<const float4*>(ya_perm)[pos];
    const float4 mm = reinterpret_cast<const float4*>(mm_attrs)[s];
    dacc += dq_perm[pos];
    const float y0 = ya.x, y1x = ya.y, y1y = ya.z, y1z = ya.w;
    const float m0 = mm.x, m1x = mm.y, m1y = mm.z, m1z = mm.w;
    const float xs  = s_buf[s * 64 + lane];
    const float xvx = v_buf[(s * 3 + 0) * 64 + lane];
    const float xvy = v_buf[(s * 3 + 1) * 64 + lane];
    const float xvz = v_buf[(s * 3 + 2) * 64 + lane];

    float cp[13];
    #pragma unroll
    for (int p = 0; p < 13; ++p)
      cp[p] = bf2f(cmbP[(size_t)p * ((size_t)EE * 64) + (size_t)pos * 64 + lane]);

    // geometry (tpv folded into cp in k_edge)
    const float gs0 = xs * y0;
    const float gd  = (xvx * y1x + xvy * y1y + xvz * y1z) * 0.57735026919f;
    const float g0x = xs * y1x, g0y = xs * y1y, g0z = xs * y1z;
    const float g1x = xvx * y0, g1y = xvy * y0, g1z = xvz * y0;
    const float g2x = (xvy * y1z - xvz * y1y) * 0.70710678119f;
    const float g2y = (xvz * y1x - xvx * y1z) * 0.70710678119f;
    const float g2z = (xvx * y1y - xvy * y1x) * 0.70710678119f;

    acc_s[0]    += cp[0] * gs0 * m0;
    acc_v[0][0] += cp[1] * gs0 * m1x; acc_v[0][1] += cp[1] * gs0 * m1y; acc_v[0][2] += cp[1] * gs0 * m1z;
    acc_s[1]    += cp[2] * gd * m0;
    acc_v[1][0] += cp[3] * gd * m1x; acc_v[1][1] += cp[3] * gd * m1y; acc_v[1][2] += cp[3] * gd * m1z;

#define VV_BLOCK(vx, vy, vz, cA, cB, cC, vslotA, sslot, vslotB)                           \
    acc_v[vslotA][0] += (cA) * (vx) * m0;                                                 \
    acc_v[vslotA][1] += (cA) * (vy) * m0;                                                 \
    acc_v[vslotA][2] += (cA) * (vz) * m0;                                                 \
    acc_s[sslot] += (cB) * ((vx) * m1x + (vy) * m1y + (vz) * m1z) * 0.57735026919f;       \
    {                                                                                     \
      const float ccx = (vy) * m1z - (vz) * m1y;                                          \
      const float ccy = (vz) * m1x - (vx) * m1z;                                          \
      const float ccz = (vx) * m1y - (vy) * m1x;                                          \
      acc_v[vslotB][0] += (cC) * ccx * 0.70710678119f;                                    \
      acc_v[vslotB][1] += (cC) * ccy * 0.70710678119f;                                    \
      acc_v[vslotB][2] += (cC) * ccz * 0.70710678119f;                                    \
    }

    VV_BLOCK(g0x, g0y, g0z, cp[4], cp[5], cp[6], 2, 2, 3)
    VV_BLOCK(g1x, g1y, g1z, cp[7], cp[8], cp[9], 4, 3, 5)
    VV_BLOCK(g2x, g2y, g2z, cp[10], cp[11], cp[12], 6, 4, 7)
#undef VV_BLOCK
  }

  // ---- combine the two half-waves of each node via LDS ----
  if (half == 1) {
    #pragma unroll
    for (int j = 0; j < 5; ++j) red[nib][j][lane] = acc_s[j];
    #pragma unroll
    for (int p = 0; p < 8; ++p)
      #pragma unroll
      for (int i = 0; i < 3; ++i) red[nib][5 + p * 3 + i][lane] = acc_v[p][i];
    red[nib][29][lane] = dacc;
  }
  __syncthreads();
  if (half == 0) {
    #pragma unroll
    for (int j = 0; j < 5; ++j) acc_s[j] += red[nib][j][lane];
    #pragma unroll
    for (int p = 0; p < 8; ++p)
      #pragma unroll
      for (int i = 0; i < 3; ++i) acc_v[p][i] += red[nib][5 + p * 3 + i][lane];
    dacc += red[nib][29][lane];

    #pragma unroll
    for (int j = 0; j < 5; ++j) {
      u16 hh, ll;
      split2(acc_s[j], hh, ll);
      ms_h[(size_t)n * 320 + j * 64 + lane] = hh;
      ms_l[(size_t)n * 320 + j * 64 + lane] = ll;
    }
    #pragma unroll
    for (int p = 0; p < 8; ++p)
      #pragma unroll
      for (int i = 0; i < 3; ++i) {
        u16 hh, ll;
        split2(acc_v[p][i], hh, ll);
        mv_h[((size_t)n * 3 + i) * 512 + p * 64 + lane] = hh;
        mv_l[((size_t)n * 3 + i) * 512 + p * 64 + lane] = ll;
      }
    if (lane == 0) dens[n] = dacc;
  }
}

// ---------------------------------------------------------------------------
extern "C" void kernel_launch(void* const* d_in, const int* in_sizes, int n_in,
                              void* d_out, int out_size, void* d_ws, size_t ws_size,
                              hipStream_t stream)
{
  const float* node_attrs = (const float*)d_in[0];
  const float* node_feats = (const float*)d_in[1];
  const float* edge_attrs = (const float*)d_in[2];
  const float* edge_feats = (const float*)d_in[3];
  const int*   edge_index = (const int*)d_in[4];
  const float* mm_inv     = (const float*)d_in[5];
  const float* mm_attrs   = (const float*)d_in[6];
  const float* W_up_s     = (const float*)d_in[7];
  const float* W_up_v     = (const float*)d_in[8];
  const float* w0         = (const float*)d_in[9];
  const float* w1         = (const float*)d_in[10];
  const float* w2         = (const float*)d_in[11];
  const float* w3         = (const float*)d_in[12];
  const float* mag_w      = (const float*)d_in[13];
  const float* dens_w     = (const float*)d_in[14];
  const float* lin_s      = (const float*)d_in[15];
  const float* lin_v      = (const float*)d_in[16];
  const float* skip_s     = (const float*)d_in[17];
  const float* skip_v     = (const float*)d_in[18];
  float* out = (float*)d_out;

  char* wp = (char*)d_ws;
  auto alloc = [&](size_t b) { char* p = wp; wp += (b + 255) & ~(size_t)255; return p; };
  float* s_buf  = (float*)alloc((size_t)NN * 64 * 4);       // 2.10 MB
  float* v_buf  = (float*)alloc((size_t)NN * 192 * 4);      // 6.29 MB
  float* ya_p   = (float*)alloc((size_t)EE * 4 * 4);        // 1.05 MB
  float* dq_p   = (float*)alloc((size_t)EE * 4);            // 0.26 MB
  int*   snd_p  = (int*)alloc((size_t)EE * 4);              // 0.26 MB
  u16*   efm_h  = (u16*)alloc((size_t)EE * 16 * 2);         // 2.10 MB
  u16*   efm_l  = (u16*)alloc((size_t)EE * 16 * 2);         // 2.10 MB
  u16*   hA_h   = (u16*)alloc((size_t)EE * 64 * 2);         // 8.39 MB (ms2/mv2 backing)
  u16*   hA_l   = (u16*)alloc((size_t)EE * 64 * 2);         // 8.39 MB
  u16*   hB_h   = (u16*)alloc((size_t)EE * 64 * 2);         // 8.39 MB (ms backing)
  u16*   hB_l   = (u16*)alloc((size_t)EE * 64 * 2);         // 8.39 MB
  u16*   cmbP   = (u16*)alloc((size_t)13 * EE * 64 * 2);    // 109 MB  [13][EE][64]
  u16*   mv_h   = (u16*)alloc((size_t)NN * 1536 * 2);       // 25.2 MB
  u16*   mv_l   = (u16*)alloc((size_t)NN * 1536 * 2);       // 25.2 MB
  float* dens   = (float*)alloc((size_t)NN * 4);
  int*   counts = (int*)alloc((size_t)NN * 4);
  int*   offs   = (int*)alloc((size_t)(NN + 1) * 4);
  int*   cursor = (int*)alloc((size_t)NN * 4);
  int*   perm   = (int*)alloc((size_t)EE * 4);
  u16*   wt_h   = (u16*)alloc((size_t)WT_TOTAL * 2);        // 0.43 MB
  u16*   wt_l   = (u16*)alloc((size_t)WT_TOTAL * 2);        // 0.43 MB
  u16*   ms_h   = hB_h;            // NN*320*2 = 5.25 MB <= 8.39 MB
  u16*   ms_l   = hB_l;
  float* ms2    = (float*)hA_h;    // 2.10 MB <= 8.39 MB
  float* mv2    = (float*)hA_l;    // 6.29 MB <= 8.39 MB

  const int* snd = edge_index;
  const int* rcv = edge_index + EE;

  // CSR + permuted edge data + pre-split fragment-ordered weight table
  hipMemsetAsync(counts, 0, (size_t)NN * 4, stream);
  k_count<<<EE / 256, 256, 0, stream>>>(rcv, counts);
  k_scan<<<1, 1024, 0, stream>>>(counts, offs, cursor);
  k_fill<<<EE / 256, 256, 0, stream>>>(rcv, cursor, perm);
  k_build<<<EE / 256, 256, 0, stream>>>(perm, snd, edge_attrs, edge_feats, mm_inv, dens_w,
                                        snd_p, ya_p, dq_p, efm_h, efm_l);
  k_permw<<<(WT_TOTAL + 255) / 256, 256, 0, stream>>>(w0, w1, w2, w3, mag_w, lin_s, lin_v,
                                                     skip_s, skip_v, wt_h, wt_l);

  // node up-projections (fp32 path)
  k_gemm<32><<<dim3(NN / 32, 1, 1), 256, 0, stream>>>(
      node_feats, 256, 1, 0, 0, W_up_s, 64, 64, 0.125f, s_buf, 64, 0);
  k_gemm<32><<<dim3(NN / 32, 1, 3), 256, 0, stream>>>(
      node_feats, 256, 3, 64, 1, W_up_v, 64, 64, 0.125f, v_buf, 192, 64);

  // FUSED edge pipeline: w0/w1/w2 + 13 product planes (tpv folded in)
  k_edge<<<EE / 64, 256, 0, stream>>>(efm_h, efm_l, wt_h, wt_l, cmbP);

  // per-node gather (2 half-waves/node) + tensor product + segment sum
  k_gather<<<NN / 2, 256, 0, stream>>>(snd_p, ya_p, dq_p, mm_attrs,
                                       s_buf, v_buf, cmbP, offs,
                                       ms_h, ms_l, mv_h, mv_l, dens);

  // node linears on MFMA (RT=32) with density division fused
  k_mgemm<32, 0, false, 1><<<dim3(NN / 32, 1), 256, 0, stream>>>(
      ms_h, ms_l, 320, 320, nullptr, nullptr, 0, 0,
      wt_h + OFF_LINS, wt_l + OFF_LINS, 320, ms2, nullptr, 64, dens);
  k_mgemm<32, 0, false, 3><<<dim3(NN * 3 / 32, 1), 256, 0, stream>>>(
      mv_h, mv_l, 512, 512, nullptr, nullptr, 0, 0,
      wt_h + OFF_LINV, wt_l + OFF_LINV, 512, mv2, nullptr, 64, dens);

  // skip contraction on MFMA (merged s+v, direct write into out (N,64,4))
  k_skipm<<<NN / 32 + NN * 3 / 32, 256, 0, stream>>>(
      ms2, mv2, node_attrs, wt_h, wt_l, out);
}

// Round 11
// 282.579 us; speedup vs baseline: 1.0571x; 1.0571x over previous
//
#include <hip/hip_runtime.h>
#include <hip/hip_bf16.h>

#define NN 8192
#define EE 65536

typedef unsigned short u16;
typedef __attribute__((ext_vector_type(8))) short bf16x8;          // 8 bf16 = 4 VGPRs
typedef __attribute__((ext_vector_type(8))) unsigned short u16x8;  // 16 B load
typedef __attribute__((ext_vector_type(4))) float f32x4;

// Pre-split weight table offsets (elements, shared by h/l planes).
// R11: the W3M region's structural zeros are REMOVED. tpv planes (w3) keep
// only ks=0,1 (k<64 is their entire support); wm0-2 move into a unified
// 13-plane MAG region with their k-window remapped [64,80) -> [0,16)
// (exactly eah's nonzero quads). Per plane-step MFMA: tpv 9->6, wm0-2 9->3.
// Values bit-identical (dropped MFMAs contributed exact fp32 zeros).
//   W3M5: 40 tiles ((j*4+nt)*2+ks), j = tpv plane 0..4, K=64
//   MAG:  52 tiles (p*4+nt), p = wm plane 0..12, K=32
#define OFF_W0    0        // 4   tiles (nt)
#define OFF_W1    2048     // 8   tiles (nt*2+ks)
#define OFF_W2    6144     // 8   tiles
#define OFF_W3M5  10240    // 40  tiles
#define OFF_MAG   30720    // 52  tiles
#define OFF_LINS  57344    // 64 x 320 (row-major, k_mgemm)
#define OFF_LINV  77824    // 64 x 512
#define OFF_SKS   110592   // 64 x 640  (skip_s reshaped [w][u*10+v], *1/fan)
#define OFF_SKV   151552   // 64 x 640  (skip_v)
#define WT_TOTAL  192512

// Plane schedule (single live tpv plane, R8 discipline):
// kind: 0 = tpv (K=64, 2 ks sub-tiles, A = h), 1 = wm (K=32, A = efm).
// tile: tpv index j for kind0; wm plane p for kind1 (== product plane idx).
__device__ const int PKIND[18] = {0,1,1, 0,1,1, 0,1,1,1, 0,1,1,1, 0,1,1,1};
__device__ const int PTILE[18] = {0,0,1, 3,2,3, 1,4,5,6, 2,7,8,9, 4,10,11,12};
__device__ const int PROLE[18] = {-1,0,1, -1,2,3, -1,4,5,6, -1,7,8,9, -1,10,11,12};

__device__ __forceinline__ u16 f2bf(float f) {
  __hip_bfloat16 h = __float2bfloat16(f);
  return *reinterpret_cast<u16*>(&h);
}
__device__ __forceinline__ float bf2f(u16 v) {
  union { unsigned int u; float f; } x; x.u = ((unsigned int)v) << 16; return x.f;
}
__device__ __forceinline__ void split2(float x, u16& h, u16& l) {
  __hip_bfloat16 bh = __float2bfloat16(x);
  h = *reinterpret_cast<u16*>(&bh);
  float r = x - __bfloat162float(bh);
  __hip_bfloat16 bl = __float2bfloat16(r);
  l = *reinterpret_cast<u16*>(&bl);
}

#define MFMA(a, b, c) __builtin_amdgcn_mfma_f32_16x16x32_bf16((a), (b), (c), 0, 0, 0)

// ---------------------------------------------------------------------------
// FUSED edge pipeline (R11 = R8's staged/barriered structure — R10 proved
// direct loads regress (61.5->69.3us: 4 waves' separate requests beat L1
// dedupe; the cooperative LDS stage is cheaper) — with the zero-tile cut:
// per-block MFMA 408 -> 276, staged weight bytes -27%. Numerics identical.
// ---------------------------------------------------------------------------
__global__ __launch_bounds__(256, 4) void k_edge(
    const u16* __restrict__ efm_h, const u16* __restrict__ efm_l,
    const u16* __restrict__ wt_h, const u16* __restrict__ wt_l,
    u16* __restrict__ cmbP)
{
  __shared__ u16 Hh[64 * 72], Hl[64 * 72];   // h, K=64 (18432 B)
  __shared__ u16 Bs[2][2048];                // staged B tiles: h at 0, l at 1024 (8192 B)
  __shared__ u16 Ct[64 * 80];                // output staging, quad-XOR swizzled (10240 B)
  const int tid  = threadIdx.x;
  const size_t pos0 = (size_t)blockIdx.x * 64;
  const int wave = tid >> 6, lane = tid & 63;
  const int quad = lane >> 4, lrow = lane & 15;
  const int kbase = quad * 8;
  const int rw = wave * 16;

  // ---- E fragments directly from global (K=16 zero-padded to 32) ----
  bf16x8 eah = {}, eal = {};
  if (quad < 2) {
    eah = *reinterpret_cast<const bf16x8*>(&efm_h[(pos0 + rw + lrow) * 16 + kbase]);
    eal = *reinterpret_cast<const bf16x8*>(&efm_l[(pos0 + rw + lrow) * 16 + kbase]);
  }

  // ---- L0: h = silu(efm @ w0), K=32 (padded), N=64 — contiguous frag loads ----
  {
    #pragma unroll
    for (int nt = 0; nt < 4; ++nt) {
      const size_t bo = (size_t)nt * 512 + lane * 8;
      const bf16x8 fbh = *reinterpret_cast<const bf16x8*>(wt_h + OFF_W0 + bo);
      const bf16x8 fbl = *reinterpret_cast<const bf16x8*>(wt_l + OFF_W0 + bo);
      f32x4 acc = {};
      acc = MFMA(eah, fbh, acc); acc = MFMA(eah, fbl, acc); acc = MFMA(eal, fbh, acc);
      #pragma unroll
      for (int r = 0; r < 4; ++r) {
        float t = acc[r];
        t = t / (1.0f + __expf(-t));
        u16 hh, ll; split2(t, hh, ll);
        const int row = rw + quad * 4 + r, col = nt * 16 + lrow;
        Hh[row * 72 + col] = hh; Hl[row * 72 + col] = ll;
      }
    }
  }

  // ---- L1, L2: h = silu(h @ w), K=64, N=64, in-place ----
  #pragma unroll
  for (int layer = 0; layer < 2; ++layer) {
    const int OFF = layer ? OFF_W2 : OFF_W1;
    bf16x8 fah[2], fal[2];
    #pragma unroll
    for (int ks = 0; ks < 2; ++ks) {
      fah[ks] = *reinterpret_cast<const bf16x8*>(&Hh[(rw + lrow) * 72 + ks * 32 + kbase]);
      fal[ks] = *reinterpret_cast<const bf16x8*>(&Hl[(rw + lrow) * 72 + ks * 32 + kbase]);
    }
    f32x4 acc[4] = {};
    #pragma unroll
    for (int nt = 0; nt < 4; ++nt)
      #pragma unroll
      for (int ks = 0; ks < 2; ++ks) {
        const size_t bo = (size_t)(nt * 2 + ks) * 512 + lane * 8;
        const bf16x8 fbh = *reinterpret_cast<const bf16x8*>(wt_h + OFF + bo);
        const bf16x8 fbl = *reinterpret_cast<const bf16x8*>(wt_l + OFF + bo);
        acc[nt] = MFMA(fah[ks], fbh, acc[nt]);
        acc[nt] = MFMA(fah[ks], fbl, acc[nt]);
        acc[nt] = MFMA(fal[ks], fbh, acc[nt]);
      }
    #pragma unroll
    for (int nt = 0; nt < 4; ++nt)
      #pragma unroll
      for (int r = 0; r < 4; ++r) {
        float t = acc[nt][r];
        t = t / (1.0f + __expf(-t));
        u16 hh, ll; split2(t, hh, ll);
        const int row = rw + quad * 4 + r, col = nt * 16 + lrow;
        Hh[row * 72 + col] = hh; Hl[row * 72 + col] = ll;
      }
  }

  // ---- 18 plane computations, single live tpv plane, LDS-staged weights ----
  {
    bf16x8 fah[2], fal[2];
    #pragma unroll
    for (int ks = 0; ks < 2; ++ks) {
      fah[ks] = *reinterpret_cast<const bf16x8*>(&Hh[(rw + lrow) * 72 + ks * 32 + kbase]);
      fal[ks] = *reinterpret_cast<const bf16x8*>(&Hl[(rw + lrow) * 72 + ks * 32 + kbase]);
    }

    // stage step (pl, nt) into Bs[buf]: kind0 = 1024 h + 1024 l elems;
    // kind1 = 512 h + 512 l.
    auto STAGE = [&](int pl, int nt, int buf) {
      if (PKIND[pl]) {
        const size_t src = (size_t)OFF_MAG + (size_t)(PTILE[pl] * 4 + nt) * 512;
        if (tid < 128) {
          const int b = (tid >= 64);
          const int off = (tid - (b ? 64 : 0)) * 8;
          *reinterpret_cast<uint4*>(&Bs[buf][(b ? 1024 : 0) + off]) =
              *reinterpret_cast<const uint4*>((b ? wt_l : wt_h) + src + off);
        }
      } else {
        const size_t src = (size_t)OFF_W3M5 + (size_t)(PTILE[pl] * 4 + nt) * 1024;
        const int b = (tid >= 128);
        const int off = (tid - (b ? 128 : 0)) * 8;
        *reinterpret_cast<uint4*>(&Bs[buf][(b ? 1024 : 0) + off]) =
            *reinterpret_cast<const uint4*>((b ? wt_l : wt_h) + src + off);
      }
    };

    // wave-local store of the finished product plane from Ct
    auto STORE_P = [&](u16* dst) {
      #pragma unroll
      for (int i = 0; i < 2; ++i) {
        const int idx = lane + i * 64;       // 128 uint4 = 16 rows x 8 chunks
        const int rl = idx >> 3, c2 = idx & 7;
        const uint4 v4 = *reinterpret_cast<const uint4*>(
            &Ct[(rw + rl) * 80 + ((c2 * 8) ^ (((rl >> 2) & 3) << 4))]);
        *reinterpret_cast<uint4*>(&dst[(pos0 + rw + rl) * 64 + c2 * 8]) = v4;
      }
    };

    unsigned int tp[4][2];                   // current tpv plane only (8 u32)
    int buf = 0;
    STAGE(0, 0, 0);
    for (int pl = 0; pl < 18; ++pl) {
      const int kind = PKIND[pl], role = PROLE[pl];
      #pragma unroll
      for (int nt = 0; nt < 4; ++nt) {
        __syncthreads();                     // Bs[buf] staged; readers of buf^1 done
        if (nt < 3) STAGE(pl, nt + 1, buf ^ 1);
        else if (pl + 1 < 18) STAGE(pl + 1, 0, buf ^ 1);
        f32x4 acc = {};
        if (kind == 0) {
          #pragma unroll
          for (int ks = 0; ks < 2; ++ks) {
            const bf16x8 bh = *reinterpret_cast<const bf16x8*>(&Bs[buf][ks * 512 + lane * 8]);
            const bf16x8 bl = *reinterpret_cast<const bf16x8*>(&Bs[buf][1024 + ks * 512 + lane * 8]);
            acc = MFMA(fah[ks], bh, acc); acc = MFMA(fah[ks], bl, acc); acc = MFMA(fal[ks], bh, acc);
          }
        } else {
          const bf16x8 bh = *reinterpret_cast<const bf16x8*>(&Bs[buf][lane * 8]);
          const bf16x8 bl = *reinterpret_cast<const bf16x8*>(&Bs[buf][1024 + lane * 8]);
          acc = MFMA(eah, bh, acc); acc = MFMA(eah, bl, acc); acc = MFMA(eal, bh, acc);
        }
        if (role < 0) {
          tp[nt][0] = (unsigned)f2bf(acc[0]) | ((unsigned)f2bf(acc[1]) << 16);
          tp[nt][1] = (unsigned)f2bf(acc[2]) | ((unsigned)f2bf(acc[3]) << 16);
        } else {
          #pragma unroll
          for (int r = 0; r < 4; ++r) {
            const float tv = bf2f((u16)((tp[nt][r >> 1] >> ((r & 1) * 16)) & 0xffffu));
            Ct[(rw + quad * 4 + r) * 80 + ((nt * 16 + lrow) ^ (quad << 4))] = f2bf(acc[r] * tv);
          }
        }
        buf ^= 1;
      }
      if (role >= 0) STORE_P(cmbP + (size_t)role * ((size_t)EE * 64));
    }
  }
}

// ---------------------------------------------------------------------------
// MFMA GEMM, fp32-equivalent via 3-term bf16 split (kept for the node linears).
// ---------------------------------------------------------------------------
template<int RT, int OUT, bool SILU, int DDIV>
__global__ __launch_bounds__(256) void k_mgemm(
    const u16* __restrict__ X1h, const u16* __restrict__ X1l, int x1rs, int K1,
    const u16* __restrict__ X2h, const u16* __restrict__ X2l, int x2rs, int K2,
    const u16* __restrict__ Wth, const u16* __restrict__ Wtl, int K,
    void* __restrict__ O1, void* __restrict__ O2, int ors,
    const float* __restrict__ dens)
{
  constexpr int NTN = (RT == 128) ? 4 : 1;
  constexpr int AIT = RT * 8 / 256;
  __shared__ u16 Ah[RT * 40];
  __shared__ u16 Al[RT * 40];
  __shared__ u16 Bh[64 * 40];
  __shared__ u16 Bl[64 * 40];
  const int tid  = threadIdx.x;
  const int row0 = blockIdx.x * RT;
  const int col0 = blockIdx.y * 64;
  const int wave = tid >> 6, lane = tid & 63;
  const int quad = lane >> 4, lrow = lane & 15;
  const int kbase = quad * 8;
  const int rw  = (RT == 128) ? wave * 32 : 0;
  const int ntb = (RT == 128) ? 0 : wave;

  f32x4 acc[2][NTN] = {};

  for (int k0 = 0; k0 < K; k0 += 32) {
    #pragma unroll
    for (int i = 0; i < AIT; ++i) {
      const int idx = tid + i * 256;
      const int b = idx / (RT * 4), rc = idx & (RT * 4 - 1);
      const int r = rc >> 2, c = rc & 3;
      const int gk = k0 + c * 8;
      uint4 v = make_uint4(0u, 0u, 0u, 0u);
      if (gk < K1)
        v = *reinterpret_cast<const uint4*>(&(b ? X1l : X1h)[(size_t)(row0 + r) * x1rs + gk]);
      else if (gk - K1 < K2)
        v = *reinterpret_cast<const uint4*>(&(b ? X2l : X2h)[(size_t)(row0 + r) * x2rs + gk - K1]);
      *reinterpret_cast<uint4*>(&(b ? Al : Ah)[r * 40 + c * 8]) = v;
    }
    #pragma unroll
    for (int i = 0; i < 2; ++i) {
      const int idx = tid + i * 256;
      const int b = idx >> 8, rc = idx & 255;
      const int n = rc >> 2, c = rc & 3;
      const uint4 v = *reinterpret_cast<const uint4*>(
          &(b ? Wtl : Wth)[(size_t)(col0 + n) * K + k0 + c * 8]);
      *reinterpret_cast<uint4*>(&(b ? Bl : Bh)[n * 40 + c * 8]) = v;
    }
    __syncthreads();

    bf16x8 fah[2], fal[2], fbh[NTN], fbl[NTN];
    #pragma unroll
    for (int mt = 0; mt < 2; ++mt) {
      const int ro = (rw + mt * 16 + lrow) * 40 + kbase;
      fah[mt] = *reinterpret_cast<const bf16x8*>(&Ah[ro]);
      fal[mt] = *reinterpret_cast<const bf16x8*>(&Al[ro]);
    }
    #pragma unroll
    for (int nt = 0; nt < NTN; ++nt) {
      const int ro = ((ntb + nt) * 16 + lrow) * 40 + kbase;
      fbh[nt] = *reinterpret_cast<const bf16x8*>(&Bh[ro]);
      fbl[nt] = *reinterpret_cast<const bf16x8*>(&Bl[ro]);
    }
    #pragma unroll
    for (int mt = 0; mt < 2; ++mt)
      #pragma unroll
      for (int nt = 0; nt < NTN; ++nt) {
        acc[mt][nt] = MFMA(fah[mt], fbh[nt], acc[mt][nt]);
        acc[mt][nt] = MFMA(fah[mt], fbl[nt], acc[mt][nt]);
        acc[mt][nt] = MFMA(fal[mt], fbh[nt], acc[mt][nt]);
      }
    __syncthreads();
  }

  #pragma unroll
  for (int mt = 0; mt < 2; ++mt)
    #pragma unroll
    for (int nt = 0; nt < NTN; ++nt)
      #pragma unroll
      for (int r = 0; r < 4; ++r) {
        const int grow = row0 + rw + mt * 16 + quad * 4 + r;
        const int gcol = col0 + (ntb + nt) * 16 + lrow;
        float t = acc[mt][nt][r];
        if (SILU) t = t / (1.0f + __expf(-t));
        if (DDIV > 0) t *= 1.0f / (dens[grow / DDIV] + 1.0f);
        const size_t oi = (size_t)grow * ors + gcol;
        if (OUT == 0) {
          reinterpret_cast<float*>(O1)[oi] = t;
        } else if (OUT == 1) {
          u16 hh, ll;
          split2(t, hh, ll);
          reinterpret_cast<u16*>(O1)[oi] = hh;
          reinterpret_cast<u16*>(O2)[oi] = ll;
        } else {
          reinterpret_cast<u16*>(O1)[oi] = f2bf(t);
        }
      }
}

// ---------------------------------------------------------------------------
// Skip contraction as MFMA GEMM, MERGED, writing DIRECTLY into out (N,64,4).
// ---------------------------------------------------------------------------
__global__ __launch_bounds__(256) void k_skipm(
    const float* __restrict__ ms2, const float* __restrict__ mv2,
    const float* __restrict__ na,
    const u16* __restrict__ wt_h, const u16* __restrict__ wt_l,
    float* __restrict__ out)
{
  __shared__ u16 Ah[32 * 40];
  __shared__ u16 Al[32 * 40];
  __shared__ u16 Bh[64 * 40];
  __shared__ u16 Bl[64 * 40];
  const int tid  = threadIdx.x;
  const bool isv = blockIdx.x >= (NN / 32);
  const int row0 = (isv ? (blockIdx.x - NN / 32) : blockIdx.x) * 32;
  const float* C = isv ? mv2 : ms2;
  const u16* Bth = wt_h + (isv ? OFF_SKV : OFF_SKS);
  const u16* Btl = wt_l + (isv ? OFF_SKV : OFF_SKS);
  const int wave = tid >> 6, lane = tid & 63;
  const int quad = lane >> 4, lrow = lane & 15;
  const int kbase = quad * 8;

  f32x4 acc[2] = {};

  for (int k0 = 0; k0 < 640; k0 += 32) {
    #pragma unroll
    for (int i = 0; i < 4; ++i) {
      const int e = tid + i * 256;
      const int r = e >> 5, kk = e & 31;
      const int k = k0 + kk;
      const int u = k / 10, v = k - u * 10;
      const int row = row0 + r;
      const int n = isv ? (row / 3) : row;
      const float t = C[(size_t)row * 64 + u] * na[n * 10 + v];
      u16 hh, ll;
      split2(t, hh, ll);
      Ah[r * 40 + kk] = hh;
      Al[r * 40 + kk] = ll;
    }
    #pragma unroll
    for (int i = 0; i < 2; ++i) {
      const int idx = tid + i * 256;
      const int b = idx >> 8, rc = idx & 255;
      const int nw = rc >> 2, c = rc & 3;
      const uint4 v4 = *reinterpret_cast<const uint4*>(
          &(b ? Btl : Bth)[(size_t)nw * 640 + k0 + c * 8]);
      *reinterpret_cast<uint4*>(&(b ? Bl : Bh)[nw * 40 + c * 8]) = v4;
    }
    __syncthreads();

    bf16x8 fah[2], fal[2], fbh, fbl;
    #pragma unroll
    for (int mt = 0; mt < 2; ++mt) {
      const int ro = (mt * 16 + lrow) * 40 + kbase;
      fah[mt] = *reinterpret_cast<const bf16x8*>(&Ah[ro]);
      fal[mt] = *reinterpret_cast<const bf16x8*>(&Al[ro]);
    }
    {
      const int ro = (wave * 16 + lrow) * 40 + kbase;
      fbh = *reinterpret_cast<const bf16x8*>(&Bh[ro]);
      fbl = *reinterpret_cast<const bf16x8*>(&Bl[ro]);
    }
    #pragma unroll
    for (int mt = 0; mt < 2; ++mt) {
      acc[mt] = MFMA(fah[mt], fbh, acc[mt]);
      acc[mt] = MFMA(fah[mt], fbl, acc[mt]);
      acc[mt] = MFMA(fal[mt], fbh, acc[mt]);
    }
    __syncthreads();
  }

  #pragma unroll
  for (int mt = 0; mt < 2; ++mt)
    #pragma unroll
    for (int r = 0; r < 4; ++r) {
      const int row = row0 + mt * 16 + quad * 4 + r;
      const int w = wave * 16 + lrow;
      if (isv) {
        const int n = row / 3, i = row - n * 3;
        out[(size_t)n * 256 + w * 4 + 1 + i] = acc[mt][r];
      } else {
        out[(size_t)row * 256 + w * 4] = acc[mt][r];
      }
    }
}

// ---------------------------------------------------------------------------
// fp32 tiled GEMM (node up-projections): OUT = scale * X@W
// ---------------------------------------------------------------------------
template<int RT>
__global__ __launch_bounds__(256) void k_gemm(
    const float* __restrict__ X, int xrs, int xes, int xco, int xcob,
    const float* __restrict__ W, int K, int NOUT,
    float scale, float* __restrict__ OUTp, int ors, int oob)
{
  constexpr int RPT = RT / 16;
  __shared__ float Xs[RT * 65];
  __shared__ float Ws[64 * 64];
  const int tid  = threadIdx.x;
  const int row0 = blockIdx.x * RT;
  const int col0 = blockIdx.y * 64;
  const int z    = blockIdx.z;
  const int xc   = xco + z * xcob;
  const int oo   = z * oob;
  const int ci = tid & 15;
  const int ri = tid >> 4;
  float acc[RPT][4] = {};

  for (int k0 = 0; k0 < K; k0 += 64) {
    const int kc  = (K - k0 >= 64) ? 64 : (K - k0);
    const int ksh = (kc == 64) ? 6 : 4;
    for (int idx = tid; idx < kc * RT; idx += 256) {
      const int r = idx >> ksh, kk = idx & (kc - 1);
      Xs[r * 65 + kk] = X[(size_t)(row0 + r) * xrs + xc + (size_t)(k0 + kk) * xes];
    }
    for (int idx = tid; idx < (kc << 6); idx += 256) {
      const int kk = idx >> 6, c = idx & 63;
      Ws[kk * 64 + c] = W[(size_t)(k0 + kk) * NOUT + col0 + c];
    }
    __syncthreads();
    for (int kk = 0; kk < kc; ++kk) {
      const float4 wv = *reinterpret_cast<const float4*>(&Ws[kk * 64 + ci * 4]);
      #pragma unroll
      for (int j = 0; j < RPT; ++j) {
        const float x = Xs[(ri * RPT + j) * 65 + kk];
        acc[j][0] += x * wv.x; acc[j][1] += x * wv.y;
        acc[j][2] += x * wv.z; acc[j][3] += x * wv.w;
      }
    }
    __syncthreads();
  }

  #pragma unroll
  for (int j = 0; j < RPT; ++j) {
    const int row = row0 + ri * RPT + j;
    *reinterpret_cast<float4*>(OUTp + (size_t)row * ors + oo + col0 + ci * 4) =
        make_float4(acc[j][0] * scale, acc[j][1] * scale, acc[j][2] * scale, acc[j][3] * scale);
  }
}

// ---------------------------------------------------------------------------
// CSR build
// ---------------------------------------------------------------------------
__global__ __launch_bounds__(256) void k_count(const int* __restrict__ rcv, int* __restrict__ counts) {
  const int e = blockIdx.x * 256 + threadIdx.x;
  atomicAdd(&counts[rcv[e]], 1);
}

__global__ __launch_bounds__(1024) void k_scan(const int* __restrict__ counts,
                                               int* __restrict__ offs, int* __restrict__ cursor) {
  __shared__ int part[1024];
  const int tid = threadIdx.x;
  int local[8];
  int s = 0;
  #pragma unroll
  for (int j = 0; j < 8; ++j) { local[j] = s; s += counts[tid * 8 + j]; }
  part[tid] = s;
  __syncthreads();
  for (int off = 1; off < 1024; off <<= 1) {
    int v = 0;
    if (tid >= off) v = part[tid - off];
    __syncthreads();
    part[tid] += v;
    __syncthreads();
  }
  const int base = part[tid] - s;
  #pragma unroll
  for (int j = 0; j < 8; ++j) {
    const int o = base + local[j];
    offs[tid * 8 + j] = o;
    cursor[tid * 8 + j] = o;
  }
  if (tid == 1023) offs[NN] = part[1023];
}

__global__ __launch_bounds__(256) void k_fill(const int* __restrict__ rcv,
                                              int* __restrict__ cursor, int* __restrict__ perm) {
  const int e = blockIdx.x * 256 + threadIdx.x;
  const int pos = atomicAdd(&cursor[rcv[e]], 1);
  perm[pos] = e;
}

// ---------------------------------------------------------------------------
// Build the pre-split, pre-scaled weight table. Fragment-contiguous tiles;
// R11: W3M5 region = tpv planes only (K=64); MAG region = all 13 wm planes
// (K=32, wm0-2's k-window remapped [64,80) -> [0,16)). Same values.
// ---------------------------------------------------------------------------
__global__ __launch_bounds__(256) void k_permw(
    const float* __restrict__ w0, const float* __restrict__ w1,
    const float* __restrict__ w2, const float* __restrict__ w3,
    const float* __restrict__ mag_w, const float* __restrict__ lin_s,
    const float* __restrict__ lin_v, const float* __restrict__ skip_s,
    const float* __restrict__ skip_v,
    u16* __restrict__ wt_h, u16* __restrict__ wt_l)
{
  const int id = blockIdx.x * 256 + threadIdx.x;   // WT_TOTAL threads
  float val = 0.f;
  if (id < OFF_W1) {                       // W0: 4 tiles (nt)
    const int i = id - OFF_W0;
    const int tile = i >> 9, rem = i & 511, lane = rem >> 3, e = rem & 7;
    const int quad = lane >> 4, lrow = lane & 15;
    const int n = tile * 16 + lrow, k = quad * 8 + e;
    val = (k < 16) ? w0[k * 64 + n] * 0.25f : 0.f;
  } else if (id < OFF_W2) {                // W1: 8 tiles (nt*2+ks)
    const int i = id - OFF_W1;
    const int tile = i >> 9, rem = i & 511, lane = rem >> 3, e = rem & 7;
    const int quad = lane >> 4, lrow = lane & 15;
    const int n = (tile >> 1) * 16 + lrow, k = (tile & 1) * 32 + quad * 8 + e;
    val = w1[k * 64 + n] * 0.125f;
  } else if (id < OFF_W3M5) {              // W2: 8 tiles
    const int i = id - OFF_W2;
    const int tile = i >> 9, rem = i & 511, lane = rem >> 3, e = rem & 7;
    const int quad = lane >> 4, lrow = lane & 15;
    const int n = (tile >> 1) * 16 + lrow, k = (tile & 1) * 32 + quad * 8 + e;
    val = w2[k * 64 + n] * 0.125f;
  } else if (id < OFF_MAG) {               // W3M5: 40 tiles ((j*4+nt)*2+ks), K=64
    const int i = id - OFF_W3M5;
    const int tile = i >> 9, rem = i & 511, lane = rem >> 3, e = rem & 7;
    const int quad = lane >> 4, lrow = lane & 15;
    const int gnt = tile >> 1, ks = tile & 1;
    const int n = (gnt >> 2) * 64 + (gnt & 3) * 16 + lrow;   // tpv plane j = n>>6
    const int k = ks * 32 + quad * 8 + e;                    // k < 64
    val = w3[k * 320 + n] * 0.125f;
  } else if (id < OFF_LINS) {              // MAG: 52 tiles (p*4+nt), K=32
    const int i = id - OFF_MAG;
    const int tile = i >> 9, rem = i & 511, lane = rem >> 3, e = rem & 7;
    const int quad = lane >> 4, lrow = lane & 15;
    const int n = (tile >> 2) * 64 + (tile & 3) * 16 + lrow; // p = n>>6, u = n&63
    const int k = quad * 8 + e;
    const int p = n >> 6, u = n & 63;
    val = (k < 16) ? mag_w[k * 832 + p * 64 + u] * 0.25f : 0.f;
  } else if (id < OFF_LINV) {
    const int i = id - OFF_LINS, n = i / 320, k = i - n * 320;
    val = lin_s[k * 64 + n] * 0.05590169944f;
  } else if (id < OFF_SKS) {
    const int i = id - OFF_LINV, n = i >> 9, k = i & 511;
    val = lin_v[k * 64 + n] * 0.04419417382f;
  } else if (id < OFF_SKV) {
    const int i = id - OFF_SKS, w = i / 640, k = i - w * 640;
    val = skip_s[k * 64 + w] * 0.03952847075f;   // [u*10+v][w], 1/sqrt(640)
  } else if (id < WT_TOTAL) {
    const int i = id - OFF_SKV, w = i / 640, k = i - w * 640;
    val = skip_v[k * 64 + w] * 0.03952847075f;
  } else {
    return;
  }
  u16 hh, ll;
  split2(val, hh, ll);
  wt_h[id] = hh;
  wt_l[id] = ll;
}

// ---------------------------------------------------------------------------
// Permute edge data into receiver-grouped (perm) order + precompute:
//   snd_perm, ya_perm, dq_perm (tanh(q^2)), efm split pair.
// ---------------------------------------------------------------------------
__global__ __launch_bounds__(256) void k_build(
    const int* __restrict__ perm, const int* __restrict__ snd,
    const float* __restrict__ edge_attrs, const float* __restrict__ edge_feats,
    const float* __restrict__ mm_inv, const float* __restrict__ dens_w,
    int* __restrict__ snd_perm, float* __restrict__ ya_perm,
    float* __restrict__ dq_perm, u16* __restrict__ efm_h, u16* __restrict__ efm_l)
{
  const int pos = blockIdx.x * 256 + threadIdx.x;
  const int e = perm[pos];
  const int s = snd[e];
  snd_perm[pos] = s;
  reinterpret_cast<float4*>(ya_perm)[pos] = reinterpret_cast<const float4*>(edge_attrs)[e];
  const float4 ef0 = reinterpret_cast<const float4*>(edge_feats)[e * 2];
  const float4 ef1 = reinterpret_cast<const float4*>(edge_feats)[e * 2 + 1];
  const float4 mi0 = reinterpret_cast<const float4*>(mm_inv)[s * 2];
  const float4 mi1 = reinterpret_cast<const float4*>(mm_inv)[s * 2 + 1];
  float q = ef0.x * dens_w[0] + ef0.y * dens_w[1] + ef0.z * dens_w[2] + ef0.w * dens_w[3]
          + ef1.x * dens_w[4] + ef1.y * dens_w[5] + ef1.z * dens_w[6] + ef1.w * dens_w[7];
  q *= 0.35355339059f;   // 1/sqrt(8)
  dq_perm[pos] = tanhf(q * q);
  float vals[16] = { ef0.x, ef0.y, ef0.z, ef0.w, ef1.x, ef1.y, ef1.z, ef1.w,
                     mi0.x, mi0.y, mi0.z, mi0.w, mi1.x, mi1.y, mi1.z, mi1.w };
  u16 hh[16], ll[16];
  #pragma unroll
  for (int i = 0; i < 16; ++i) split2(vals[i], hh[i], ll[i]);
  reinterpret_cast<uint4*>(&efm_h[(size_t)pos * 16])[0] = reinterpret_cast<uint4*>(hh)[0];
  reinterpret_cast<uint4*>(&efm_h[(size_t)pos * 16])[1] = reinterpret_cast<uint4*>(hh)[1];
  reinterpret_cast<uint4*>(&efm_l[(size_t)pos * 16])[0] = reinterpret_cast<uint4*>(ll)[0];
  reinterpret_cast<uint4*>(&efm_l[(size_t)pos * 16])[1] = reinterpret_cast<uint4*>(ll)[1];
}

// ---------------------------------------------------------------------------
// Gather: TWO half-waves per node (halved serial edge chain, LDS reduction).
// Reads the 13 product planes c_p; per edge each lane reads 13 x 2 B (one
// 128 B segment per plane). R8 version, verbatim.
// ---------------------------------------------------------------------------
__global__ __launch_bounds__(256) void k_gather(
    const int* __restrict__ snd_perm,
    const float* __restrict__ ya_perm,
    const float* __restrict__ dq_perm,
    const float* __restrict__ mm_attrs,
    const float* __restrict__ s_buf,
    const float* __restrict__ v_buf,
    const u16* __restrict__ cmbP,
    const int* __restrict__ offs,
    u16* __restrict__ ms_h, u16* __restrict__ ms_l,
    u16* __restrict__ mv_h, u16* __restrict__ mv_l,
    float* __restrict__ dens)
{
  __shared__ float red[2][30][64];
  const int tid  = threadIdx.x;
  const int lane = tid & 63;
  const int nib  = tid >> 7;                 // node within block (0/1)
  const int half = (tid >> 6) & 1;           // segment half (0/1)
  const int n = blockIdx.x * 2 + nib;

  float acc_s[5] = {0.f, 0.f, 0.f, 0.f, 0.f};
  float acc_v[8][3] = {};
  float dacc = 0.f;
  const int start0 = offs[n], end0 = offs[n + 1];
  const int mid = start0 + ((end0 - start0 + 1) >> 1);
  const int start = half ? mid : start0;
  const int end   = half ? end0 : mid;

  int s_nx = 0;
  if (start < end) s_nx = snd_perm[start];
  for (int pos = start; pos < end; ++pos) {
    const int s = s_nx;
    if (pos + 1 < end) s_nx = snd_perm[pos + 1];

    const float4 ya = reinterpret_cast<const float4*>(ya_perm)[pos];
    const float4 mm = reinterpret_cast<const float4*>(mm_attrs)[s];
    dacc += dq_perm[pos];
    const float y0 = ya.x, y1x = ya.y, y1y = ya.z, y1z = ya.w;
    const float m0 = mm.x, m1x = mm.y, m1y = mm.z, m1z = mm.w;
    const float xs  = s_buf[s * 64 + lane];
    const float xvx = v_buf[(s * 3 + 0) * 64 + lane];
    const float xvy = v_buf[(s * 3 + 1) * 64 + lane];
    const float xvz = v_buf[(s * 3 + 2) * 64 + lane];

    float cp[13];
    #pragma unroll
    for (int p = 0; p < 13; ++p)
      cp[p] = bf2f(cmbP[(size_t)p * ((size_t)EE * 64) + (size_t)pos * 64 + lane]);

    // geometry (tpv folded into cp in k_edge)
    const float gs0 = xs * y0;
    const float gd  = (xvx * y1x + xvy * y1y + xvz * y1z) * 0.57735026919f;
    const float g0x = xs * y1x, g0y = xs * y1y, g0z = xs * y1z;
    const float g1x = xvx * y0, g1y = xvy * y0, g1z = xvz * y0;
    const float g2x = (xvy * y1z - xvz * y1y) * 0.70710678119f;
    const float g2y = (xvz * y1x - xvx * y1z) * 0.70710678119f;
    const float g2z = (xvx * y1y - xvy * y1x) * 0.70710678119f;

    acc_s[0]    += cp[0] * gs0 * m0;
    acc_v[0][0] += cp[1] * gs0 * m1x; acc_v[0][1] += cp[1] * gs0 * m1y; acc_v[0][2] += cp[1] * gs0 * m1z;
    acc_s[1]    += cp[2] * gd * m0;
    acc_v[1][0] += cp[3] * gd * m1x; acc_v[1][1] += cp[3] * gd * m1y; acc_v[1][2] += cp[3] * gd * m1z;

#define VV_BLOCK(vx, vy, vz, cA, cB, cC, vslotA, sslot, vslotB)                           \
    acc_v[vslotA][0] += (cA) * (vx) * m0;                                                 \
    acc_v[vslotA][1] += (cA) * (vy) * m0;                                                 \
    acc_v[vslotA][2] += (cA) * (vz) * m0;                                                 \
    acc_s[sslot] += (cB) * ((vx) * m1x + (vy) * m1y + (vz) * m1z) * 0.57735026919f;       \
    {                                                                                     \
      const float ccx = (vy) * m1z - (vz) * m1y;                                          \
      const float ccy = (vz) * m1x - (vx) * m1z;                                          \
      const float ccz = (vx) * m1y - (vy) * m1x;                                          \
      acc_v[vslotB][0] += (cC) * ccx * 0.70710678119f;                                    \
      acc_v[vslotB][1] += (cC) * ccy * 0.70710678119f;                                    \
      acc_v[vslotB][2] += (cC) * ccz * 0.70710678119f;                                    \
    }

    VV_BLOCK(g0x, g0y, g0z, cp[4], cp[5], cp[6], 2, 2, 3)
    VV_BLOCK(g1x, g1y, g1z, cp[7], cp[8], cp[9], 4, 3, 5)
    VV_BLOCK(g2x, g2y, g2z, cp[10], cp[11], cp[12], 6, 4, 7)
#undef VV_BLOCK
  }

  // ---- combine the two half-waves of each node via LDS ----
  if (half == 1) {
    #pragma unroll
    for (int j = 0; j < 5; ++j) red[nib][j][lane] = acc_s[j];
    #pragma unroll
    for (int p = 0; p < 8; ++p)
      #pragma unroll
      for (int i = 0; i < 3; ++i) red[nib][5 + p * 3 + i][lane] = acc_v[p][i];
    red[nib][29][lane] = dacc;
  }
  __syncthreads();
  if (half == 0) {
    #pragma unroll
    for (int j = 0; j < 5; ++j) acc_s[j] += red[nib][j][lane];
    #pragma unroll
    for (int p = 0; p < 8; ++p)
      #pragma unroll
      for (int i = 0; i < 3; ++i) acc_v[p][i] += red[nib][5 + p * 3 + i][lane];
    dacc += red[nib][29][lane];

    #pragma unroll
    for (int j = 0; j < 5; ++j) {
      u16 hh, ll;
      split2(acc_s[j], hh, ll);
      ms_h[(size_t)n * 320 + j * 64 + lane] = hh;
      ms_l[(size_t)n * 320 + j * 64 + lane] = ll;
    }
    #pragma unroll
    for (int p = 0; p < 8; ++p)
      #pragma unroll
      for (int i = 0; i < 3; ++i) {
        u16 hh, ll;
        split2(acc_v[p][i], hh, ll);
        mv_h[((size_t)n * 3 + i) * 512 + p * 64 + lane] = hh;
        mv_l[((size_t)n * 3 + i) * 512 + p * 64 + lane] = ll;
      }
    if (lane == 0) dens[n] = dacc;
  }
}

// ---------------------------------------------------------------------------
extern "C" void kernel_launch(void* const* d_in, const int* in_sizes, int n_in,
                              void* d_out, int out_size, void* d_ws, size_t ws_size,
                              hipStream_t stream)
{
  const float* node_attrs = (const float*)d_in[0];
  const float* node_feats = (const float*)d_in[1];
  const float* edge_attrs = (const float*)d_in[2];
  const float* edge_feats = (const float*)d_in[3];
  const int*   edge_index = (const int*)d_in[4];
  const float* mm_inv     = (const float*)d_in[5];
  const float* mm_attrs   = (const float*)d_in[6];
  const float* W_up_s     = (const float*)d_in[7];
  const float* W_up_v     = (const float*)d_in[8];
  const float* w0         = (const float*)d_in[9];
  const float* w1         = (const float*)d_in[10];
  const float* w2         = (const float*)d_in[11];
  const float* w3         = (const float*)d_in[12];
  const float* mag_w      = (const float*)d_in[13];
  const float* dens_w     = (const float*)d_in[14];
  const float* lin_s      = (const float*)d_in[15];
  const float* lin_v      = (const float*)d_in[16];
  const float* skip_s     = (const float*)d_in[17];
  const float* skip_v     = (const float*)d_in[18];
  float* out = (float*)d_out;

  char* wp = (char*)d_ws;
  auto alloc = [&](size_t b) { char* p = wp; wp += (b + 255) & ~(size_t)255; return p; };
  float* s_buf  = (float*)alloc((size_t)NN * 64 * 4);       // 2.10 MB
  float* v_buf  = (float*)alloc((size_t)NN * 192 * 4);      // 6.29 MB
  float* ya_p   = (float*)alloc((size_t)EE * 4 * 4);        // 1.05 MB
  float* dq_p   = (float*)alloc((size_t)EE * 4);            // 0.26 MB
  int*   snd_p  = (int*)alloc((size_t)EE * 4);              // 0.26 MB
  u16*   efm_h  = (u16*)alloc((size_t)EE * 16 * 2);         // 2.10 MB
  u16*   efm_l  = (u16*)alloc((size_t)EE * 16 * 2);         // 2.10 MB
  u16*   hA_h   = (u16*)alloc((size_t)EE * 64 * 2);         // 8.39 MB (ms2/mv2 backing)
  u16*   hA_l   = (u16*)alloc((size_t)EE * 64 * 2);         // 8.39 MB
  u16*   hB_h   = (u16*)alloc((size_t)EE * 64 * 2);         // 8.39 MB (ms backing)
  u16*   hB_l   = (u16*)alloc((size_t)EE * 64 * 2);         // 8.39 MB
  u16*   cmbP   = (u16*)alloc((size_t)13 * EE * 64 * 2);    // 109 MB  [13][EE][64]
  u16*   mv_h   = (u16*)alloc((size_t)NN * 1536 * 2);       // 25.2 MB
  u16*   mv_l   = (u16*)alloc((size_t)NN * 1536 * 2);       // 25.2 MB
  float* dens   = (float*)alloc((size_t)NN * 4);
  int*   counts = (int*)alloc((size_t)NN * 4);
  int*   offs   = (int*)alloc((size_t)(NN + 1) * 4);
  int*   cursor = (int*)alloc((size_t)NN * 4);
  int*   perm   = (int*)alloc((size_t)EE * 4);
  u16*   wt_h   = (u16*)alloc((size_t)WT_TOTAL * 2);        // 0.39 MB
  u16*   wt_l   = (u16*)alloc((size_t)WT_TOTAL * 2);        // 0.39 MB
  u16*   ms_h   = hB_h;            // NN*320*2 = 5.25 MB <= 8.39 MB
  u16*   ms_l   = hB_l;
  float* ms2    = (float*)hA_h;    // 2.10 MB <= 8.39 MB
  float* mv2    = (float*)hA_l;    // 6.29 MB <= 8.39 MB

  const int* snd = edge_index;
  const int* rcv = edge_index + EE;

  // CSR + permuted edge data + pre-split fragment-ordered weight table
  hipMemsetAsync(counts, 0, (size_t)NN * 4, stream);
  k_count<<<EE / 256, 256, 0, stream>>>(rcv, counts);
  k_scan<<<1, 1024, 0, stream>>>(counts, offs, cursor);
  k_fill<<<EE / 256, 256, 0, stream>>>(rcv, cursor, perm);
  k_build<<<EE / 256, 256, 0, stream>>>(perm, snd, edge_attrs, edge_feats, mm_inv, dens_w,
                                        snd_p, ya_p, dq_p, efm_h, efm_l);
  k_permw<<<(WT_TOTAL + 255) / 256, 256, 0, stream>>>(w0, w1, w2, w3, mag_w, lin_s, lin_v,
                                                     skip_s, skip_v, wt_h, wt_l);

  // node up-projections (fp32 path)
  k_gemm<32><<<dim3(NN / 32, 1, 1), 256, 0, stream>>>(
      node_feats, 256, 1, 0, 0, W_up_s, 64, 64, 0.125f, s_buf, 64, 0);
  k_gemm<32><<<dim3(NN / 32, 1, 3), 256, 0, stream>>>(
      node_feats, 256, 3, 64, 1, W_up_v, 64, 64, 0.125f, v_buf, 192, 64);

  // FUSED edge pipeline: w0/w1/w2 + 13 product planes (tpv folded in)
  k_edge<<<EE / 64, 256, 0, stream>>>(efm_h, efm_l, wt_h, wt_l, cmbP);

  // per-node gather (2 half-waves/node) + tensor product + segment sum
  k_gather<<<NN / 2, 256, 0, stream>>>(snd_p, ya_p, dq_p, mm_attrs,
                                       s_buf, v_buf, cmbP, offs,
                                       ms_h, ms_l, mv_h, mv_l, dens);

  // node linears on MFMA (RT=32) with density division fused
  k_mgemm<32, 0, false, 1><<<dim3(NN / 32, 1), 256, 0, stream>>>(
      ms_h, ms_l, 320, 320, nullptr, nullptr, 0, 0,
      wt_h + OFF_LINS, wt_l + OFF_LINS, 320, ms2, nullptr, 64, dens);
  k_mgemm<32, 0, false, 3><<<dim3(NN * 3 / 32, 1), 256, 0, stream>>>(
      mv_h, mv_l, 512, 512, nullptr, nullptr, 0, 0,
      wt_h + OFF_LINV, wt_l + OFF_LINV, 512, mv2, nullptr, 64, dens);

  // skip contraction on MFMA (merged s+v, direct write into out (N,64,4))
  k_skipm<<<NN / 32 + NN * 3 / 32, 256, 0, stream>>>(
      ms2, mv2, node_attrs, wt_h, wt_l, out);
}

// Round 13
// 262.129 us; speedup vs baseline: 1.1396x; 1.0780x over previous
//
#include <hip/hip_runtime.h>
#include <hip/hip_bf16.h>

#define NN 8192
#define EE 65536

typedef unsigned short u16;
typedef __attribute__((ext_vector_type(8))) short bf16x8;          // 8 bf16 = 4 VGPRs
typedef __attribute__((ext_vector_type(8))) unsigned short u16x8;  // 16 B load
typedef __attribute__((ext_vector_type(4))) float f32x4;

// Pre-split weight table offsets (elements, shared by h/l planes).
// R11 zero-trimmed layout (verbatim). LINS/LINV row-major (k_mgemm).
//   W3M5: 40 tiles ((j*4+nt)*2+ks), j = tpv plane 0..4, K=64
//   MAG:  52 tiles (p*4+nt), p = wm plane 0..12, K=32
#define OFF_W0    0        // 4   tiles (nt)
#define OFF_W1    2048     // 8   tiles (nt*2+ks)
#define OFF_W2    6144     // 8   tiles
#define OFF_W3M5  10240    // 40  tiles
#define OFF_MAG   30720    // 52  tiles
#define OFF_LINS  57344    // 64 x 320 (row-major, k_mgemm)
#define OFF_LINV  77824    // 64 x 512
#define OFF_SKS   110592   // 64 x 640  (skip_s reshaped [w][u*10+v], *1/fan)
#define OFF_SKV   151552   // 64 x 640  (skip_v)
#define WT_TOTAL  192512

// Plane schedule (single live tpv plane):
// kind: 0 = tpv (K=64, 2 ks sub-tiles, A = h), 1 = wm (K=32, A = efm).
__device__ const int PKIND[18] = {0,1,1, 0,1,1, 0,1,1,1, 0,1,1,1, 0,1,1,1};
__device__ const int PTILE[18] = {0,0,1, 3,2,3, 1,4,5,6, 2,7,8,9, 4,10,11,12};
__device__ const int PROLE[18] = {-1,0,1, -1,2,3, -1,4,5,6, -1,7,8,9, -1,10,11,12};

__device__ __forceinline__ u16 f2bf(float f) {
  __hip_bfloat16 h = __float2bfloat16(f);
  return *reinterpret_cast<u16*>(&h);
}
__device__ __forceinline__ float bf2f(u16 v) {
  union { unsigned int u; float f; } x; x.u = ((unsigned int)v) << 16; return x.f;
}
__device__ __forceinline__ void split2(float x, u16& h, u16& l) {
  __hip_bfloat16 bh = __float2bfloat16(x);
  h = *reinterpret_cast<u16*>(&bh);
  float r = x - __bfloat162float(bh);
  __hip_bfloat16 bl = __float2bfloat16(r);
  l = *reinterpret_cast<u16*>(&bl);
}

#define MFMA(a, b, c) __builtin_amdgcn_mfma_f32_16x16x32_bf16((a), (b), (c), 0, 0, 0)

// ---------------------------------------------------------------------------
// FUSED edge pipeline (R11, unchanged): staged/barriered with zero-tile cut.
// ---------------------------------------------------------------------------
__global__ __launch_bounds__(256, 4) void k_edge(
    const u16* __restrict__ efm_h, const u16* __restrict__ efm_l,
    const u16* __restrict__ wt_h, const u16* __restrict__ wt_l,
    u16* __restrict__ cmbP)
{
  __shared__ u16 Hh[64 * 72], Hl[64 * 72];   // h, K=64 (18432 B)
  __shared__ u16 Bs[2][2048];                // staged B tiles: h at 0, l at 1024 (8192 B)
  __shared__ u16 Ct[64 * 80];                // output staging, quad-XOR swizzled (10240 B)
  const int tid  = threadIdx.x;
  const size_t pos0 = (size_t)blockIdx.x * 64;
  const int wave = tid >> 6, lane = tid & 63;
  const int quad = lane >> 4, lrow = lane & 15;
  const int kbase = quad * 8;
  const int rw = wave * 16;

  // ---- E fragments directly from global (K=16 zero-padded to 32) ----
  bf16x8 eah = {}, eal = {};
  if (quad < 2) {
    eah = *reinterpret_cast<const bf16x8*>(&efm_h[(pos0 + rw + lrow) * 16 + kbase]);
    eal = *reinterpret_cast<const bf16x8*>(&efm_l[(pos0 + rw + lrow) * 16 + kbase]);
  }

  // ---- L0: h = silu(efm @ w0), K=32 (padded), N=64 — contiguous frag loads ----
  {
    #pragma unroll
    for (int nt = 0; nt < 4; ++nt) {
      const size_t bo = (size_t)nt * 512 + lane * 8;
      const bf16x8 fbh = *reinterpret_cast<const bf16x8*>(wt_h + OFF_W0 + bo);
      const bf16x8 fbl = *reinterpret_cast<const bf16x8*>(wt_l + OFF_W0 + bo);
      f32x4 acc = {};
      acc = MFMA(eah, fbh, acc); acc = MFMA(eah, fbl, acc); acc = MFMA(eal, fbh, acc);
      #pragma unroll
      for (int r = 0; r < 4; ++r) {
        float t = acc[r];
        t = t / (1.0f + __expf(-t));
        u16 hh, ll; split2(t, hh, ll);
        const int row = rw + quad * 4 + r, col = nt * 16 + lrow;
        Hh[row * 72 + col] = hh; Hl[row * 72 + col] = ll;
      }
    }
  }

  // ---- L1, L2: h = silu(h @ w), K=64, N=64, in-place ----
  #pragma unroll
  for (int layer = 0; layer < 2; ++layer) {
    const int OFF = layer ? OFF_W2 : OFF_W1;
    bf16x8 fah[2], fal[2];
    #pragma unroll
    for (int ks = 0; ks < 2; ++ks) {
      fah[ks] = *reinterpret_cast<const bf16x8*>(&Hh[(rw + lrow) * 72 + ks * 32 + kbase]);
      fal[ks] = *reinterpret_cast<const bf16x8*>(&Hl[(rw + lrow) * 72 + ks * 32 + kbase]);
    }
    f32x4 acc[4] = {};
    #pragma unroll
    for (int nt = 0; nt < 4; ++nt)
      #pragma unroll
      for (int ks = 0; ks < 2; ++ks) {
        const size_t bo = (size_t)(nt * 2 + ks) * 512 + lane * 8;
        const bf16x8 fbh = *reinterpret_cast<const bf16x8*>(wt_h + OFF + bo);
        const bf16x8 fbl = *reinterpret_cast<const bf16x8*>(wt_l + OFF + bo);
        acc[nt] = MFMA(fah[ks], fbh, acc[nt]);
        acc[nt] = MFMA(fah[ks], fbl, acc[nt]);
        acc[nt] = MFMA(fal[ks], fbh, acc[nt]);
      }
    #pragma unroll
    for (int nt = 0; nt < 4; ++nt)
      #pragma unroll
      for (int r = 0; r < 4; ++r) {
        float t = acc[nt][r];
        t = t / (1.0f + __expf(-t));
        u16 hh, ll; split2(t, hh, ll);
        const int row = rw + quad * 4 + r, col = nt * 16 + lrow;
        Hh[row * 72 + col] = hh; Hl[row * 72 + col] = ll;
      }
  }

  // ---- 18 plane computations, single live tpv plane, LDS-staged weights ----
  {
    bf16x8 fah[2], fal[2];
    #pragma unroll
    for (int ks = 0; ks < 2; ++ks) {
      fah[ks] = *reinterpret_cast<const bf16x8*>(&Hh[(rw + lrow) * 72 + ks * 32 + kbase]);
      fal[ks] = *reinterpret_cast<const bf16x8*>(&Hl[(rw + lrow) * 72 + ks * 32 + kbase]);
    }

    auto STAGE = [&](int pl, int nt, int buf) {
      if (PKIND[pl]) {
        const size_t src = (size_t)OFF_MAG + (size_t)(PTILE[pl] * 4 + nt) * 512;
        if (tid < 128) {
          const int b = (tid >= 64);
          const int off = (tid - (b ? 64 : 0)) * 8;
          *reinterpret_cast<uint4*>(&Bs[buf][(b ? 1024 : 0) + off]) =
              *reinterpret_cast<const uint4*>((b ? wt_l : wt_h) + src + off);
        }
      } else {
        const size_t src = (size_t)OFF_W3M5 + (size_t)(PTILE[pl] * 4 + nt) * 1024;
        const int b = (tid >= 128);
        const int off = (tid - (b ? 128 : 0)) * 8;
        *reinterpret_cast<uint4*>(&Bs[buf][(b ? 1024 : 0) + off]) =
            *reinterpret_cast<const uint4*>((b ? wt_l : wt_h) + src + off);
      }
    };

    auto STORE_P = [&](u16* dst) {
      #pragma unroll
      for (int i = 0; i < 2; ++i) {
        const int idx = lane + i * 64;       // 128 uint4 = 16 rows x 8 chunks
        const int rl = idx >> 3, c2 = idx & 7;
        const uint4 v4 = *reinterpret_cast<const uint4*>(
            &Ct[(rw + rl) * 80 + ((c2 * 8) ^ (((rl >> 2) & 3) << 4))]);
        *reinterpret_cast<uint4*>(&dst[(pos0 + rw + rl) * 64 + c2 * 8]) = v4;
      }
    };

    unsigned int tp[4][2];                   // current tpv plane only (8 u32)
    int buf = 0;
    STAGE(0, 0, 0);
    for (int pl = 0; pl < 18; ++pl) {
      const int kind = PKIND[pl], role = PROLE[pl];
      #pragma unroll
      for (int nt = 0; nt < 4; ++nt) {
        __syncthreads();                     // Bs[buf] staged; readers of buf^1 done
        if (nt < 3) STAGE(pl, nt + 1, buf ^ 1);
        else if (pl + 1 < 18) STAGE(pl + 1, 0, buf ^ 1);
        f32x4 acc = {};
        if (kind == 0) {
          #pragma unroll
          for (int ks = 0; ks < 2; ++ks) {
            const bf16x8 bh = *reinterpret_cast<const bf16x8*>(&Bs[buf][ks * 512 + lane * 8]);
            const bf16x8 bl = *reinterpret_cast<const bf16x8*>(&Bs[buf][1024 + ks * 512 + lane * 8]);
            acc = MFMA(fah[ks], bh, acc); acc = MFMA(fah[ks], bl, acc); acc = MFMA(fal[ks], bh, acc);
          }
        } else {
          const bf16x8 bh = *reinterpret_cast<const bf16x8*>(&Bs[buf][lane * 8]);
          const bf16x8 bl = *reinterpret_cast<const bf16x8*>(&Bs[buf][1024 + lane * 8]);
          acc = MFMA(eah, bh, acc); acc = MFMA(eah, bl, acc); acc = MFMA(eal, bh, acc);
        }
        if (role < 0) {
          tp[nt][0] = (unsigned)f2bf(acc[0]) | ((unsigned)f2bf(acc[1]) << 16);
          tp[nt][1] = (unsigned)f2bf(acc[2]) | ((unsigned)f2bf(acc[3]) << 16);
        } else {
          #pragma unroll
          for (int r = 0; r < 4; ++r) {
            const float tv = bf2f((u16)((tp[nt][r >> 1] >> ((r & 1) * 16)) & 0xffffu));
            Ct[(rw + quad * 4 + r) * 80 + ((nt * 16 + lrow) ^ (quad << 4))] = f2bf(acc[r] * tv);
          }
        }
        buf ^= 1;
      }
      if (role >= 0) STORE_P(cmbP + (size_t)role * ((size_t)EE * 64));
    }
  }
}

// ---------------------------------------------------------------------------
// MFMA GEMM. AL=true: fp32-equivalent via 3-term bf16 split (A has h+l).
// AL=false (R13): A is SINGLE bf16 (h only) — 2 MFMAs/step, half the A
// traffic. B always h+l split. OUT: 0 = fp32. DDIV: *= 1/(dens[row/DDIV]+1).
// ---------------------------------------------------------------------------
template<int RT, int OUT, bool SILU, int DDIV, bool AL>
__global__ __launch_bounds__(256) void k_mgemm(
    const u16* __restrict__ X1h, const u16* __restrict__ X1l, int x1rs, int K1,
    const u16* __restrict__ X2h, const u16* __restrict__ X2l, int x2rs, int K2,
    const u16* __restrict__ Wth, const u16* __restrict__ Wtl, int K,
    void* __restrict__ O1, void* __restrict__ O2, int ors,
    const float* __restrict__ dens)
{
  constexpr int NTN = (RT == 128) ? 4 : 1;
  constexpr int AIT = RT * 8 / 256;
  __shared__ u16 Ah[RT * 40];
  __shared__ u16 Al[RT * 40];
  __shared__ u16 Bh[64 * 40];
  __shared__ u16 Bl[64 * 40];
  const int tid  = threadIdx.x;
  const int row0 = blockIdx.x * RT;
  const int col0 = blockIdx.y * 64;
  const int wave = tid >> 6, lane = tid & 63;
  const int quad = lane >> 4, lrow = lane & 15;
  const int kbase = quad * 8;
  const int rw  = (RT == 128) ? wave * 32 : 0;
  const int ntb = (RT == 128) ? 0 : wave;

  f32x4 acc[2][NTN] = {};

  for (int k0 = 0; k0 < K; k0 += 32) {
    #pragma unroll
    for (int i = 0; i < AIT; ++i) {
      const int idx = tid + i * 256;
      const int b = idx / (RT * 4), rc = idx & (RT * 4 - 1);
      const int r = rc >> 2, c = rc & 3;
      const int gk = k0 + c * 8;
      if (AL || b == 0) {
        uint4 v = make_uint4(0u, 0u, 0u, 0u);
        if (gk < K1)
          v = *reinterpret_cast<const uint4*>(&(b ? X1l : X1h)[(size_t)(row0 + r) * x1rs + gk]);
        else if (gk - K1 < K2)
          v = *reinterpret_cast<const uint4*>(&(b ? X2l : X2h)[(size_t)(row0 + r) * x2rs + gk - K1]);
        *reinterpret_cast<uint4*>(&(b ? Al : Ah)[r * 40 + c * 8]) = v;
      }
    }
    #pragma unroll
    for (int i = 0; i < 2; ++i) {
      const int idx = tid + i * 256;
      const int b = idx >> 8, rc = idx & 255;
      const int n = rc >> 2, c = rc & 3;
      const uint4 v = *reinterpret_cast<const uint4*>(
          &(b ? Wtl : Wth)[(size_t)(col0 + n) * K + k0 + c * 8]);
      *reinterpret_cast<uint4*>(&(b ? Bl : Bh)[n * 40 + c * 8]) = v;
    }
    __syncthreads();

    bf16x8 fah[2], fal[2], fbh[NTN], fbl[NTN];
    #pragma unroll
    for (int mt = 0; mt < 2; ++mt) {
      const int ro = (rw + mt * 16 + lrow) * 40 + kbase;
      fah[mt] = *reinterpret_cast<const bf16x8*>(&Ah[ro]);
      if constexpr (AL) fal[mt] = *reinterpret_cast<const bf16x8*>(&Al[ro]);
    }
    #pragma unroll
    for (int nt = 0; nt < NTN; ++nt) {
      const int ro = ((ntb + nt) * 16 + lrow) * 40 + kbase;
      fbh[nt] = *reinterpret_cast<const bf16x8*>(&Bh[ro]);
      fbl[nt] = *reinterpret_cast<const bf16x8*>(&Bl[ro]);
    }
    #pragma unroll
    for (int mt = 0; mt < 2; ++mt)
      #pragma unroll
      for (int nt = 0; nt < NTN; ++nt) {
        acc[mt][nt] = MFMA(fah[mt], fbh[nt], acc[mt][nt]);
        acc[mt][nt] = MFMA(fah[mt], fbl[nt], acc[mt][nt]);
        if constexpr (AL) acc[mt][nt] = MFMA(fal[mt], fbh[nt], acc[mt][nt]);
      }
    __syncthreads();
  }

  #pragma unroll
  for (int mt = 0; mt < 2; ++mt)
    #pragma unroll
    for (int nt = 0; nt < NTN; ++nt)
      #pragma unroll
      for (int r = 0; r < 4; ++r) {
        const int grow = row0 + rw + mt * 16 + quad * 4 + r;
        const int gcol = col0 + (ntb + nt) * 16 + lrow;
        float t = acc[mt][nt][r];
        if (SILU) t = t / (1.0f + __expf(-t));
        if (DDIV > 0) t *= 1.0f / (dens[grow / DDIV] + 1.0f);
        const size_t oi = (size_t)grow * ors + gcol;
        if (OUT == 0) {
          reinterpret_cast<float*>(O1)[oi] = t;
        } else if (OUT == 1) {
          u16 hh, ll;
          split2(t, hh, ll);
          reinterpret_cast<u16*>(O1)[oi] = hh;
          reinterpret_cast<u16*>(O2)[oi] = ll;
        } else {
          reinterpret_cast<u16*>(O1)[oi] = f2bf(t);
        }
      }
}

// ---------------------------------------------------------------------------
// Skip contraction as MFMA GEMM, MERGED, writing DIRECTLY into out (N,64,4).
// ---------------------------------------------------------------------------
__global__ __launch_bounds__(256) void k_skipm(
    const float* __restrict__ ms2, const float* __restrict__ mv2,
    const float* __restrict__ na,
    const u16* __restrict__ wt_h, const u16* __restrict__ wt_l,
    float* __restrict__ out)
{
  __shared__ u16 Ah[32 * 40];
  __shared__ u16 Al[32 * 40];
  __shared__ u16 Bh[64 * 40];
  __shared__ u16 Bl[64 * 40];
  const int tid  = threadIdx.x;
  const bool isv = blockIdx.x >= (NN / 32);
  const int row0 = (isv ? (blockIdx.x - NN / 32) : blockIdx.x) * 32;
  const float* C = isv ? mv2 : ms2;
  const u16* Bth = wt_h + (isv ? OFF_SKV : OFF_SKS);
  const u16* Btl = wt_l + (isv ? OFF_SKV : OFF_SKS);
  const int wave = tid >> 6, lane = tid & 63;
  const int quad = lane >> 4, lrow = lane & 15;
  const int kbase = quad * 8;

  f32x4 acc[2] = {};

  for (int k0 = 0; k0 < 640; k0 += 32) {
    #pragma unroll
    for (int i = 0; i < 4; ++i) {
      const int e = tid + i * 256;
      const int r = e >> 5, kk = e & 31;
      const int k = k0 + kk;
      const int u = k / 10, v = k - u * 10;
      const int row = row0 + r;
      const int n = isv ? (row / 3) : row;
      const float t = C[(size_t)row * 64 + u] * na[n * 10 + v];
      u16 hh, ll;
      split2(t, hh, ll);
      Ah[r * 40 + kk] = hh;
      Al[r * 40 + kk] = ll;
    }
    #pragma unroll
    for (int i = 0; i < 2; ++i) {
      const int idx = tid + i * 256;
      const int b = idx >> 8, rc = idx & 255;
      const int nw = rc >> 2, c = rc & 3;
      const uint4 v4 = *reinterpret_cast<const uint4*>(
          &(b ? Btl : Bth)[(size_t)nw * 640 + k0 + c * 8]);
      *reinterpret_cast<uint4*>(&(b ? Bl : Bh)[nw * 40 + c * 8]) = v4;
    }
    __syncthreads();

    bf16x8 fah[2], fal[2], fbh, fbl;
    #pragma unroll
    for (int mt = 0; mt < 2; ++mt) {
      const int ro = (mt * 16 + lrow) * 40 + kbase;
      fah[mt] = *reinterpret_cast<const bf16x8*>(&Ah[ro]);
      fal[mt] = *reinterpret_cast<const bf16x8*>(&Al[ro]);
    }
    {
      const int ro = (wave * 16 + lrow) * 40 + kbase;
      fbh = *reinterpret_cast<const bf16x8*>(&Bh[ro]);
      fbl = *reinterpret_cast<const bf16x8*>(&Bl[ro]);
    }
    #pragma unroll
    for (int mt = 0; mt < 2; ++mt) {
      acc[mt] = MFMA(fah[mt], fbh, acc[mt]);
      acc[mt] = MFMA(fah[mt], fbl, acc[mt]);
      acc[mt] = MFMA(fal[mt], fbh, acc[mt]);
    }
    __syncthreads();
  }

  #pragma unroll
  for (int mt = 0; mt < 2; ++mt)
    #pragma unroll
    for (int r = 0; r < 4; ++r) {
      const int row = row0 + mt * 16 + quad * 4 + r;
      const int w = wave * 16 + lrow;
      if (isv) {
        const int n = row / 3, i = row - n * 3;
        out[(size_t)n * 256 + w * 4 + 1 + i] = acc[mt][r];
      } else {
        out[(size_t)row * 256 + w * 4] = acc[mt][r];
      }
    }
}

// ---------------------------------------------------------------------------
// fp32 tiled GEMM (node up-projections): OUT = scale * X@W
// ---------------------------------------------------------------------------
template<int RT>
__global__ __launch_bounds__(256) void k_gemm(
    const float* __restrict__ X, int xrs, int xes, int xco, int xcob,
    const float* __restrict__ W, int K, int NOUT,
    float scale, float* __restrict__ OUTp, int ors, int oob)
{
  constexpr int RPT = RT / 16;
  __shared__ float Xs[RT * 65];
  __shared__ float Ws[64 * 64];
  const int tid  = threadIdx.x;
  const int row0 = blockIdx.x * RT;
  const int col0 = blockIdx.y * 64;
  const int z    = blockIdx.z;
  const int xc   = xco + z * xcob;
  const int oo   = z * oob;
  const int ci = tid & 15;
  const int ri = tid >> 4;
  float acc[RPT][4] = {};

  for (int k0 = 0; k0 < K; k0 += 64) {
    const int kc  = (K - k0 >= 64) ? 64 : (K - k0);
    const int ksh = (kc == 64) ? 6 : 4;
    for (int idx = tid; idx < kc * RT; idx += 256) {
      const int r = idx >> ksh, kk = idx & (kc - 1);
      Xs[r * 65 + kk] = X[(size_t)(row0 + r) * xrs + xc + (size_t)(k0 + kk) * xes];
    }
    for (int idx = tid; idx < (kc << 6); idx += 256) {
      const int kk = idx >> 6, c = idx & 63;
      Ws[kk * 64 + c] = W[(size_t)(k0 + kk) * NOUT + col0 + c];
    }
    __syncthreads();
    for (int kk = 0; kk < kc; ++kk) {
      const float4 wv = *reinterpret_cast<const float4*>(&Ws[kk * 64 + ci * 4]);
      #pragma unroll
      for (int j = 0; j < RPT; ++j) {
        const float x = Xs[(ri * RPT + j) * 65 + kk];
        acc[j][0] += x * wv.x; acc[j][1] += x * wv.y;
        acc[j][2] += x * wv.z; acc[j][3] += x * wv.w;
      }
    }
    __syncthreads();
  }

  #pragma unroll
  for (int j = 0; j < RPT; ++j) {
    const int row = row0 + ri * RPT + j;
    *reinterpret_cast<float4*>(OUTp + (size_t)row * ors + oo + col0 + ci * 4) =
        make_float4(acc[j][0] * scale, acc[j][1] * scale, acc[j][2] * scale, acc[j][3] * scale);
  }
}

// ---------------------------------------------------------------------------
// CSR build
// ---------------------------------------------------------------------------
__global__ __launch_bounds__(256) void k_count(const int* __restrict__ rcv, int* __restrict__ counts) {
  const int e = blockIdx.x * 256 + threadIdx.x;
  atomicAdd(&counts[rcv[e]], 1);
}

__global__ __launch_bounds__(1024) void k_scan(const int* __restrict__ counts,
                                               int* __restrict__ offs, int* __restrict__ cursor) {
  __shared__ int part[1024];
  const int tid = threadIdx.x;
  int local[8];
  int s = 0;
  #pragma unroll
  for (int j = 0; j < 8; ++j) { local[j] = s; s += counts[tid * 8 + j]; }
  part[tid] = s;
  __syncthreads();
  for (int off = 1; off < 1024; off <<= 1) {
    int v = 0;
    if (tid >= off) v = part[tid - off];
    __syncthreads();
    part[tid] += v;
    __syncthreads();
  }
  const int base = part[tid] - s;
  #pragma unroll
  for (int j = 0; j < 8; ++j) {
    const int o = base + local[j];
    offs[tid * 8 + j] = o;
    cursor[tid * 8 + j] = o;
  }
  if (tid == 1023) offs[NN] = part[1023];
}

__global__ __launch_bounds__(256) void k_fill(const int* __restrict__ rcv,
                                              int* __restrict__ cursor, int* __restrict__ perm) {
  const int e = blockIdx.x * 256 + threadIdx.x;
  const int pos = atomicAdd(&cursor[rcv[e]], 1);
  perm[pos] = e;
}

// ---------------------------------------------------------------------------
// Build the pre-split, pre-scaled weight table (R11 layout, verbatim).
// ---------------------------------------------------------------------------
__global__ __launch_bounds__(256) void k_permw(
    const float* __restrict__ w0, const float* __restrict__ w1,
    const float* __restrict__ w2, const float* __restrict__ w3,
    const float* __restrict__ mag_w, const float* __restrict__ lin_s,
    const float* __restrict__ lin_v, const float* __restrict__ skip_s,
    const float* __restrict__ skip_v,
    u16* __restrict__ wt_h, u16* __restrict__ wt_l)
{
  const int id = blockIdx.x * 256 + threadIdx.x;   // WT_TOTAL threads
  float val = 0.f;
  if (id < OFF_W1) {                       // W0: 4 tiles (nt)
    const int i = id - OFF_W0;
    const int tile = i >> 9, rem = i & 511, lane = rem >> 3, e = rem & 7;
    const int quad = lane >> 4, lrow = lane & 15;
    const int n = tile * 16 + lrow, k = quad * 8 + e;
    val = (k < 16) ? w0[k * 64 + n] * 0.25f : 0.f;
  } else if (id < OFF_W2) {                // W1: 8 tiles (nt*2+ks)
    const int i = id - OFF_W1;
    const int tile = i >> 9, rem = i & 511, lane = rem >> 3, e = rem & 7;
    const int quad = lane >> 4, lrow = lane & 15;
    const int n = (tile >> 1) * 16 + lrow, k = (tile & 1) * 32 + quad * 8 + e;
    val = w1[k * 64 + n] * 0.125f;
  } else if (id < OFF_W3M5) {              // W2: 8 tiles
    const int i = id - OFF_W2;
    const int tile = i >> 9, rem = i & 511, lane = rem >> 3, e = rem & 7;
    const int quad = lane >> 4, lrow = lane & 15;
    const int n = (tile >> 1) * 16 + lrow, k = (tile & 1) * 32 + quad * 8 + e;
    val = w2[k * 64 + n] * 0.125f;
  } else if (id < OFF_MAG) {               // W3M5: 40 tiles ((j*4+nt)*2+ks), K=64
    const int i = id - OFF_W3M5;
    const int tile = i >> 9, rem = i & 511, lane = rem >> 3, e = rem & 7;
    const int quad = lane >> 4, lrow = lane & 15;
    const int gnt = tile >> 1, ks = tile & 1;
    const int n = (gnt >> 2) * 64 + (gnt & 3) * 16 + lrow;   // tpv plane j = n>>6
    const int k = ks * 32 + quad * 8 + e;                    // k < 64
    val = w3[k * 320 + n] * 0.125f;
  } else if (id < OFF_LINS) {              // MAG: 52 tiles (p*4+nt), K=32
    const int i = id - OFF_MAG;
    const int tile = i >> 9, rem = i & 511, lane = rem >> 3, e = rem & 7;
    const int quad = lane >> 4, lrow = lane & 15;
    const int n = (tile >> 2) * 64 + (tile & 3) * 16 + lrow; // p = n>>6, u = n&63
    const int k = quad * 8 + e;
    const int p = n >> 6, u = n & 63;
    val = (k < 16) ? mag_w[k * 832 + p * 64 + u] * 0.25f : 0.f;
  } else if (id < OFF_LINV) {
    const int i = id - OFF_LINS, n = i / 320, k = i - n * 320;
    val = lin_s[k * 64 + n] * 0.05590169944f;
  } else if (id < OFF_SKS) {
    const int i = id - OFF_LINV, n = i >> 9, k = i & 511;
    val = lin_v[k * 64 + n] * 0.04419417382f;
  } else if (id < OFF_SKV) {
    const int i = id - OFF_SKS, w = i / 640, k = i - w * 640;
    val = skip_s[k * 64 + w] * 0.03952847075f;   // [u*10+v][w], 1/sqrt(640)
  } else if (id < WT_TOTAL) {
    const int i = id - OFF_SKV, w = i / 640, k = i - w * 640;
    val = skip_v[k * 64 + w] * 0.03952847075f;
  } else {
    return;
  }
  u16 hh, ll;
  split2(val, hh, ll);
  wt_h[id] = hh;
  wt_l[id] = ll;
}

// ---------------------------------------------------------------------------
// Permute edge data into receiver-grouped (perm) order + precompute:
//   snd_perm, ya_perm, dq_perm (tanh(q^2)), efm split pair.
// ---------------------------------------------------------------------------
__global__ __launch_bounds__(256) void k_build(
    const int* __restrict__ perm, const int* __restrict__ snd,
    const float* __restrict__ edge_attrs, const float* __restrict__ edge_feats,
    const float* __restrict__ mm_inv, const float* __restrict__ dens_w,
    int* __restrict__ snd_perm, float* __restrict__ ya_perm,
    float* __restrict__ dq_perm, u16* __restrict__ efm_h, u16* __restrict__ efm_l)
{
  const int pos = blockIdx.x * 256 + threadIdx.x;
  const int e = perm[pos];
  const int s = snd[e];
  snd_perm[pos] = s;
  reinterpret_cast<float4*>(ya_perm)[pos] = reinterpret_cast<const float4*>(edge_attrs)[e];
  const float4 ef0 = reinterpret_cast<const float4*>(edge_feats)[e * 2];
  const float4 ef1 = reinterpret_cast<const float4*>(edge_feats)[e * 2 + 1];
  const float4 mi0 = reinterpret_cast<const float4*>(mm_inv)[s * 2];
  const float4 mi1 = reinterpret_cast<const float4*>(mm_inv)[s * 2 + 1];
  float q = ef0.x * dens_w[0] + ef0.y * dens_w[1] + ef0.z * dens_w[2] + ef0.w * dens_w[3]
          + ef1.x * dens_w[4] + ef1.y * dens_w[5] + ef1.z * dens_w[6] + ef1.w * dens_w[7];
  q *= 0.35355339059f;   // 1/sqrt(8)
  dq_perm[pos] = tanhf(q * q);
  float vals[16] = { ef0.x, ef0.y, ef0.z, ef0.w, ef1.x, ef1.y, ef1.z, ef1.w,
                     mi0.x, mi0.y, mi0.z, mi0.w, mi1.x, mi1.y, mi1.z, mi1.w };
  u16 hh[16], ll[16];
  #pragma unroll
  for (int i = 0; i < 16; ++i) split2(vals[i], hh[i], ll[i]);
  reinterpret_cast<uint4*>(&efm_h[(size_t)pos * 16])[0] = reinterpret_cast<uint4*>(hh)[0];
  reinterpret_cast<uint4*>(&efm_h[(size_t)pos * 16])[1] = reinterpret_cast<uint4*>(hh)[1];
  reinterpret_cast<uint4*>(&efm_l[(size_t)pos * 16])[0] = reinterpret_cast<uint4*>(ll)[0];
  reinterpret_cast<uint4*>(&efm_l[(size_t)pos * 16])[1] = reinterpret_cast<uint4*>(ll)[1];
}

// ---------------------------------------------------------------------------
// Gather: TWO half-waves per node (halved serial edge chain, LDS reduction).
// R13: ms/mv written as SINGLE bf16 (h only) — halves the node-linear
// round trip (60.8 -> 30.4 MB). The lin GEMM A-operand loses its l-plane
// (~2^-9 rel error); B stays h+l split.
// ---------------------------------------------------------------------------
__global__ __launch_bounds__(256) void k_gather(
    const int* __restrict__ snd_perm,
    const float* __restrict__ ya_perm,
    const float* __restrict__ dq_perm,
    const float* __restrict__ mm_attrs,
    const float* __restrict__ s_buf,
    const float* __restrict__ v_buf,
    const u16* __restrict__ cmbP,
    const int* __restrict__ offs,
    u16* __restrict__ ms_h, u16* __restrict__ mv_h,
    float* __restrict__ dens)
{
  __shared__ float red[2][30][64];
  const int tid  = threadIdx.x;
  const int lane = tid & 63;
  const int nib  = tid >> 7;                 // node within block (0/1)
  const int half = (tid >> 6) & 1;           // segment half (0/1)
  const int n = blockIdx.x * 2 + nib;

  float acc_s[5] = {0.f, 0.f, 0.f, 0.f, 0.f};
  float acc_v[8][3] = {};
  float dacc = 0.f;
  const int start0 = offs[n], end0 = offs[n + 1];
  const int mid = start0 + ((end0 - start0 + 1) >> 1);
  const int start = half ? mid : start0;
  const int end   = half ? end0 : mid;

  int s_nx = 0;
  if (start < end) s_nx = snd_perm[start];
  for (int pos = start; pos < end; ++pos) {
    const int s = s_nx;
    if (pos + 1 < end) s_nx = snd_perm[pos + 1];

    const float4 ya = reinterpret_cast<const float4*>(ya_perm)[pos];
    const float4 mm = reinterpret_cast<const float4*>(mm_attrs)[s];
    dacc += dq_perm[pos];
    const float y0 = ya.x, y1x = ya.y, y1y = ya.z, y1z = ya.w;
    const float m0 = mm.x, m1x = mm.y, m1y = mm.z, m1z = mm.w;
    const float xs  = s_buf[s * 64 + lane];
    const float xvx = v_buf[(s * 3 + 0) * 64 + lane];
    const float xvy = v_buf[(s * 3 + 1) * 64 + lane];
    const float xvz = v_buf[(s * 3 + 2) * 64 + lane];

    float cp[13];
    #pragma unroll
    for (int p = 0; p < 13; ++p)
      cp[p] = bf2f(cmbP[(size_t)p * ((size_t)EE * 64) + (size_t)pos * 64 + lane]);

    // geometry (tpv folded into cp in k_edge)
    const float gs0 = xs * y0;
    const float gd  = (xvx * y1x + xvy * y1y + xvz * y1z) * 0.57735026919f;
    const float g0x = xs * y1x, g0y = xs * y1y, g0z = xs * y1z;
    const float g1x = xvx * y0, g1y = xvy * y0, g1z = xvz * y0;
    const float g2x = (xvy * y1z - xvz * y1y) * 0.70710678119f;
    const float g2y = (xvz * y1x - xvx * y1z) * 0.70710678119f;
    const float g2z = (xvx * y1y - xvy * y1x) * 0.70710678119f;

    acc_s[0]    += cp[0] * gs0 * m0;
    acc_v[0][0] += cp[1] * gs0 * m1x; acc_v[0][1] += cp[1] * gs0 * m1y; acc_v[0][2] += cp[1] * gs0 * m1z;
    acc_s[1]    += cp[2] * gd * m0;
    acc_v[1][0] += cp[3] * gd * m1x; acc_v[1][1] += cp[3] * gd * m1y; acc_v[1][2] += cp[3] * gd * m1z;

#define VV_BLOCK(vx, vy, vz, cA, cB, cC, vslotA, sslot, vslotB)                           \
    acc_v[vslotA][0] += (cA) * (vx) * m0;                                                 \
    acc_v[vslotA][1] += (cA) * (vy) * m0;                                                 \
    acc_v[vslotA][2] += (cA) * (vz) * m0;                                                 \
    acc_s[sslot] += (cB) * ((vx) * m1x + (vy) * m1y + (vz) * m1z) * 0.57735026919f;       \
    {                                                                                     \
      const float ccx = (vy) * m1z - (vz) * m1y;                                          \
      const float ccy = (vz) * m1x - (vx) * m1z;                                          \
      const float ccz = (vx) * m1y - (vy) * m1x;                                          \
      acc_v[vslotB][0] += (cC) * ccx * 0.70710678119f;                                    \
      acc_v[vslotB][1] += (cC) * ccy * 0.70710678119f;                                    \
      acc_v[vslotB][2] += (cC) * ccz * 0.70710678119f;                                    \
    }

    VV_BLOCK(g0x, g0y, g0z, cp[4], cp[5], cp[6], 2, 2, 3)
    VV_BLOCK(g1x, g1y, g1z, cp[7], cp[8], cp[9], 4, 3, 5)
    VV_BLOCK(g2x, g2y, g2z, cp[10], cp[11], cp[12], 6, 4, 7)
#undef VV_BLOCK
  }

  // ---- combine the two half-waves of each node via LDS ----
  if (half == 1) {
    #pragma unroll
    for (int j = 0; j < 5; ++j) red[nib][j][lane] = acc_s[j];
    #pragma unroll
    for (int p = 0; p < 8; ++p)
      #pragma unroll
      for (int i = 0; i < 3; ++i) red[nib][5 + p * 3 + i][lane] = acc_v[p][i];
    red[nib][29][lane] = dacc;
  }
  __syncthreads();
  if (half == 0) {
    #pragma unroll
    for (int j = 0; j < 5; ++j) acc_s[j] += red[nib][j][lane];
    #pragma unroll
    for (int p = 0; p < 8; ++p)
      #pragma unroll
      for (int i = 0; i < 3; ++i) acc_v[p][i] += red[nib][5 + p * 3 + i][lane];
    dacc += red[nib][29][lane];

    #pragma unroll
    for (int j = 0; j < 5; ++j)
      ms_h[(size_t)n * 320 + j * 64 + lane] = f2bf(acc_s[j]);
    #pragma unroll
    for (int p = 0; p < 8; ++p)
      #pragma unroll
      for (int i = 0; i < 3; ++i)
        mv_h[((size_t)n * 3 + i) * 512 + p * 64 + lane] = f2bf(acc_v[p][i]);
    if (lane == 0) dens[n] = dacc;
  }
}

// ---------------------------------------------------------------------------
extern "C" void kernel_launch(void* const* d_in, const int* in_sizes, int n_in,
                              void* d_out, int out_size, void* d_ws, size_t ws_size,
                              hipStream_t stream)
{
  const float* node_attrs = (const float*)d_in[0];
  const float* node_feats = (const float*)d_in[1];
  const float* edge_attrs = (const float*)d_in[2];
  const float* edge_feats = (const float*)d_in[3];
  const int*   edge_index = (const int*)d_in[4];
  const float* mm_inv     = (const float*)d_in[5];
  const float* mm_attrs   = (const float*)d_in[6];
  const float* W_up_s     = (const float*)d_in[7];
  const float* W_up_v     = (const float*)d_in[8];
  const float* w0         = (const float*)d_in[9];
  const float* w1         = (const float*)d_in[10];
  const float* w2         = (const float*)d_in[11];
  const float* w3         = (const float*)d_in[12];
  const float* mag_w      = (const float*)d_in[13];
  const float* dens_w     = (const float*)d_in[14];
  const float* lin_s      = (const float*)d_in[15];
  const float* lin_v      = (const float*)d_in[16];
  const float* skip_s     = (const float*)d_in[17];
  const float* skip_v     = (const float*)d_in[18];
  float* out = (float*)d_out;

  char* wp = (char*)d_ws;
  auto alloc = [&](size_t b) { char* p = wp; wp += (b + 255) & ~(size_t)255; return p; };
  float* s_buf  = (float*)alloc((size_t)NN * 64 * 4);       // 2.10 MB
  float* v_buf  = (float*)alloc((size_t)NN * 192 * 4);      // 6.29 MB
  float* ya_p   = (float*)alloc((size_t)EE * 4 * 4);        // 1.05 MB
  float* dq_p   = (float*)alloc((size_t)EE * 4);            // 0.26 MB
  int*   snd_p  = (int*)alloc((size_t)EE * 4);              // 0.26 MB
  u16*   efm_h  = (u16*)alloc((size_t)EE * 16 * 2);         // 2.10 MB
  u16*   efm_l  = (u16*)alloc((size_t)EE * 16 * 2);         // 2.10 MB
  u16*   hA_h   = (u16*)alloc((size_t)EE * 64 * 2);         // 8.39 MB (ms2/mv2 backing)
  u16*   hA_l   = (u16*)alloc((size_t)EE * 64 * 2);         // 8.39 MB
  u16*   hB_h   = (u16*)alloc((size_t)EE * 64 * 2);         // 8.39 MB (ms_h backing)
  u16*   cmbP   = (u16*)alloc((size_t)13 * EE * 64 * 2);    // 109 MB  [13][EE][64]
  u16*   mv_h   = (u16*)alloc((size_t)NN * 1536 * 2);       // 25.2 MB
  float* dens   = (float*)alloc((size_t)NN * 4);
  int*   counts = (int*)alloc((size_t)NN * 4);
  int*   offs   = (int*)alloc((size_t)(NN + 1) * 4);
  int*   cursor = (int*)alloc((size_t)NN * 4);
  int*   perm   = (int*)alloc((size_t)EE * 4);
  u16*   wt_h   = (u16*)alloc((size_t)WT_TOTAL * 2);        // 0.39 MB
  u16*   wt_l   = (u16*)alloc((size_t)WT_TOTAL * 2);        // 0.39 MB
  u16*   ms_h   = hB_h;            // NN*320*2 = 5.25 MB <= 8.39 MB
  float* ms2    = (float*)hA_h;    // 2.10 MB <= 8.39 MB
  float* mv2    = (float*)hA_l;    // 6.29 MB <= 8.39 MB

  const int* snd = edge_index;
  const int* rcv = edge_index + EE;

  // CSR + permuted edge data + pre-split fragment-ordered weight table
  hipMemsetAsync(counts, 0, (size_t)NN * 4, stream);
  k_count<<<EE / 256, 256, 0, stream>>>(rcv, counts);
  k_scan<<<1, 1024, 0, stream>>>(counts, offs, cursor);
  k_fill<<<EE / 256, 256, 0, stream>>>(rcv, cursor, perm);
  k_build<<<EE / 256, 256, 0, stream>>>(perm, snd, edge_attrs, edge_feats, mm_inv, dens_w,
                                        snd_p, ya_p, dq_p, efm_h, efm_l);
  k_permw<<<(WT_TOTAL + 255) / 256, 256, 0, stream>>>(w0, w1, w2, w3, mag_w, lin_s, lin_v,
                                                     skip_s, skip_v, wt_h, wt_l);

  // node up-projections (fp32 path)
  k_gemm<32><<<dim3(NN / 32, 1, 1), 256, 0, stream>>>(
      node_feats, 256, 1, 0, 0, W_up_s, 64, 64, 0.125f, s_buf, 64, 0);
  k_gemm<32><<<dim3(NN / 32, 1, 3), 256, 0, stream>>>(
      node_feats, 256, 3, 64, 1, W_up_v, 64, 64, 0.125f, v_buf, 192, 64);

  // FUSED edge pipeline: w0/w1/w2 + 13 product planes (tpv folded in)
  k_edge<<<EE / 64, 256, 0, stream>>>(efm_h, efm_l, wt_h, wt_l, cmbP);

  // per-node gather (2 half-waves/node) + tensor product + segment sum
  k_gather<<<NN / 2, 256, 0, stream>>>(snd_p, ya_p, dq_p, mm_attrs,
                                       s_buf, v_buf, cmbP, offs,
                                       ms_h, mv_h, dens);

  // node linears on MFMA (single-bf16 A) with density division fused
  k_mgemm<32, 0, false, 1, false><<<dim3(NN / 32, 1), 256, 0, stream>>>(
      ms_h, nullptr, 320, 320, nullptr, nullptr, 0, 0,
      wt_h + OFF_LINS, wt_l + OFF_LINS, 320, ms2, nullptr, 64, dens);
  k_mgemm<32, 0, false, 3, false><<<dim3(NN * 3 / 32, 1), 256, 0, stream>>>(
      mv_h, nullptr, 512, 512, nullptr, nullptr, 0, 0,
      wt_h + OFF_LINV, wt_l + OFF_LINV, 512, mv2, nullptr, 64, dens);

  // skip contraction on MFMA (merged s+v, direct write into out (N,64,4))
  k_skipm<<<NN / 32 + NN * 3 / 32, 256, 0, stream>>>(
      ms2, mv2, node_attrs, wt_h, wt_l, out);
}

// Round 14
// 251.201 us; speedup vs baseline: 1.1891x; 1.0435x over previous
//
#include <hip/hip_runtime.h>
#include <hip/hip_bf16.h>

#define NN 8192
#define EE 65536

typedef unsigned short u16;
typedef __attribute__((ext_vector_type(8))) short bf16x8;          // 8 bf16 = 4 VGPRs
typedef __attribute__((ext_vector_type(8))) unsigned short u16x8;  // 16 B load
typedef __attribute__((ext_vector_type(4))) float f32x4;

// Pre-split weight table offsets (elements, shared by h/l planes).
// R11 zero-trimmed layout (verbatim). LINS/LINV row-major.
//   W3M5: 40 tiles ((j*4+nt)*2+ks), j = tpv plane 0..4, K=64
//   MAG:  52 tiles (p*4+nt), p = wm plane 0..12, K=32
#define OFF_W0    0        // 4   tiles (nt)
#define OFF_W1    2048     // 8   tiles (nt*2+ks)
#define OFF_W2    6144     // 8   tiles
#define OFF_W3M5  10240    // 40  tiles
#define OFF_MAG   30720    // 52  tiles
#define OFF_LINS  57344    // 64 x 320 (row-major)
#define OFF_LINV  77824    // 64 x 512
#define OFF_SKS   110592   // 64 x 640  (skip_s reshaped [w][u*10+v], *1/fan)
#define OFF_SKV   151552   // 64 x 640  (skip_v)
#define WT_TOTAL  192512

// Plane schedule (single live tpv plane):
// kind: 0 = tpv (K=64, 2 ks sub-tiles, A = h), 1 = wm (K=32, A = efm).
__device__ const int PKIND[18] = {0,1,1, 0,1,1, 0,1,1,1, 0,1,1,1, 0,1,1,1};
__device__ const int PTILE[18] = {0,0,1, 3,2,3, 1,4,5,6, 2,7,8,9, 4,10,11,12};
__device__ const int PROLE[18] = {-1,0,1, -1,2,3, -1,4,5,6, -1,7,8,9, -1,10,11,12};

__device__ __forceinline__ u16 f2bf(float f) {
  __hip_bfloat16 h = __float2bfloat16(f);
  return *reinterpret_cast<u16*>(&h);
}
__device__ __forceinline__ float bf2f(u16 v) {
  union { unsigned int u; float f; } x; x.u = ((unsigned int)v) << 16; return x.f;
}
__device__ __forceinline__ void split2(float x, u16& h, u16& l) {
  __hip_bfloat16 bh = __float2bfloat16(x);
  h = *reinterpret_cast<u16*>(&bh);
  float r = x - __bfloat162float(bh);
  __hip_bfloat16 bl = __float2bfloat16(r);
  l = *reinterpret_cast<u16*>(&bl);
}

#define MFMA(a, b, c) __builtin_amdgcn_mfma_f32_16x16x32_bf16((a), (b), (c), 0, 0, 0)

// ---------------------------------------------------------------------------
// FUSED edge pipeline (R11, unchanged): staged/barriered with zero-tile cut.
// ---------------------------------------------------------------------------
__global__ __launch_bounds__(256, 4) void k_edge(
    const u16* __restrict__ efm_h, const u16* __restrict__ efm_l,
    const u16* __restrict__ wt_h, const u16* __restrict__ wt_l,
    u16* __restrict__ cmbP)
{
  __shared__ u16 Hh[64 * 72], Hl[64 * 72];   // h, K=64 (18432 B)
  __shared__ u16 Bs[2][2048];                // staged B tiles: h at 0, l at 1024 (8192 B)
  __shared__ u16 Ct[64 * 80];                // output staging, quad-XOR swizzled (10240 B)
  const int tid  = threadIdx.x;
  const size_t pos0 = (size_t)blockIdx.x * 64;
  const int wave = tid >> 6, lane = tid & 63;
  const int quad = lane >> 4, lrow = lane & 15;
  const int kbase = quad * 8;
  const int rw = wave * 16;

  // ---- E fragments directly from global (K=16 zero-padded to 32) ----
  bf16x8 eah = {}, eal = {};
  if (quad < 2) {
    eah = *reinterpret_cast<const bf16x8*>(&efm_h[(pos0 + rw + lrow) * 16 + kbase]);
    eal = *reinterpret_cast<const bf16x8*>(&efm_l[(pos0 + rw + lrow) * 16 + kbase]);
  }

  // ---- L0: h = silu(efm @ w0), K=32 (padded), N=64 — contiguous frag loads ----
  {
    #pragma unroll
    for (int nt = 0; nt < 4; ++nt) {
      const size_t bo = (size_t)nt * 512 + lane * 8;
      const bf16x8 fbh = *reinterpret_cast<const bf16x8*>(wt_h + OFF_W0 + bo);
      const bf16x8 fbl = *reinterpret_cast<const bf16x8*>(wt_l + OFF_W0 + bo);
      f32x4 acc = {};
      acc = MFMA(eah, fbh, acc); acc = MFMA(eah, fbl, acc); acc = MFMA(eal, fbh, acc);
      #pragma unroll
      for (int r = 0; r < 4; ++r) {
        float t = acc[r];
        t = t / (1.0f + __expf(-t));
        u16 hh, ll; split2(t, hh, ll);
        const int row = rw + quad * 4 + r, col = nt * 16 + lrow;
        Hh[row * 72 + col] = hh; Hl[row * 72 + col] = ll;
      }
    }
  }

  // ---- L1, L2: h = silu(h @ w), K=64, N=64, in-place ----
  #pragma unroll
  for (int layer = 0; layer < 2; ++layer) {
    const int OFF = layer ? OFF_W2 : OFF_W1;
    bf16x8 fah[2], fal[2];
    #pragma unroll
    for (int ks = 0; ks < 2; ++ks) {
      fah[ks] = *reinterpret_cast<const bf16x8*>(&Hh[(rw + lrow) * 72 + ks * 32 + kbase]);
      fal[ks] = *reinterpret_cast<const bf16x8*>(&Hl[(rw + lrow) * 72 + ks * 32 + kbase]);
    }
    f32x4 acc[4] = {};
    #pragma unroll
    for (int nt = 0; nt < 4; ++nt)
      #pragma unroll
      for (int ks = 0; ks < 2; ++ks) {
        const size_t bo = (size_t)(nt * 2 + ks) * 512 + lane * 8;
        const bf16x8 fbh = *reinterpret_cast<const bf16x8*>(wt_h + OFF + bo);
        const bf16x8 fbl = *reinterpret_cast<const bf16x8*>(wt_l + OFF + bo);
        acc[nt] = MFMA(fah[ks], fbh, acc[nt]);
        acc[nt] = MFMA(fah[ks], fbl, acc[nt]);
        acc[nt] = MFMA(fal[ks], fbh, acc[nt]);
      }
    #pragma unroll
    for (int nt = 0; nt < 4; ++nt)
      #pragma unroll
      for (int r = 0; r < 4; ++r) {
        float t = acc[nt][r];
        t = t / (1.0f + __expf(-t));
        u16 hh, ll; split2(t, hh, ll);
        const int row = rw + quad * 4 + r, col = nt * 16 + lrow;
        Hh[row * 72 + col] = hh; Hl[row * 72 + col] = ll;
      }
  }

  // ---- 18 plane computations, single live tpv plane, LDS-staged weights ----
  {
    bf16x8 fah[2], fal[2];
    #pragma unroll
    for (int ks = 0; ks < 2; ++ks) {
      fah[ks] = *reinterpret_cast<const bf16x8*>(&Hh[(rw + lrow) * 72 + ks * 32 + kbase]);
      fal[ks] = *reinterpret_cast<const bf16x8*>(&Hl[(rw + lrow) * 72 + ks * 32 + kbase]);
    }

    auto STAGE = [&](int pl, int nt, int buf) {
      if (PKIND[pl]) {
        const size_t src = (size_t)OFF_MAG + (size_t)(PTILE[pl] * 4 + nt) * 512;
        if (tid < 128) {
          const int b = (tid >= 64);
          const int off = (tid - (b ? 64 : 0)) * 8;
          *reinterpret_cast<uint4*>(&Bs[buf][(b ? 1024 : 0) + off]) =
              *reinterpret_cast<const uint4*>((b ? wt_l : wt_h) + src + off);
        }
      } else {
        const size_t src = (size_t)OFF_W3M5 + (size_t)(PTILE[pl] * 4 + nt) * 1024;
        const int b = (tid >= 128);
        const int off = (tid - (b ? 128 : 0)) * 8;
        *reinterpret_cast<uint4*>(&Bs[buf][(b ? 1024 : 0) + off]) =
            *reinterpret_cast<const uint4*>((b ? wt_l : wt_h) + src + off);
      }
    };

    auto STORE_P = [&](u16* dst) {
      #pragma unroll
      for (int i = 0; i < 2; ++i) {
        const int idx = lane + i * 64;       // 128 uint4 = 16 rows x 8 chunks
        const int rl = idx >> 3, c2 = idx & 7;
        const uint4 v4 = *reinterpret_cast<const uint4*>(
            &Ct[(rw + rl) * 80 + ((c2 * 8) ^ (((rl >> 2) & 3) << 4))]);
        *reinterpret_cast<uint4*>(&dst[(pos0 + rw + rl) * 64 + c2 * 8]) = v4;
      }
    };

    unsigned int tp[4][2];                   // current tpv plane only (8 u32)
    int buf = 0;
    STAGE(0, 0, 0);
    for (int pl = 0; pl < 18; ++pl) {
      const int kind = PKIND[pl], role = PROLE[pl];
      #pragma unroll
      for (int nt = 0; nt < 4; ++nt) {
        __syncthreads();                     // Bs[buf] staged; readers of buf^1 done
        if (nt < 3) STAGE(pl, nt + 1, buf ^ 1);
        else if (pl + 1 < 18) STAGE(pl + 1, 0, buf ^ 1);
        f32x4 acc = {};
        if (kind == 0) {
          #pragma unroll
          for (int ks = 0; ks < 2; ++ks) {
            const bf16x8 bh = *reinterpret_cast<const bf16x8*>(&Bs[buf][ks * 512 + lane * 8]);
            const bf16x8 bl = *reinterpret_cast<const bf16x8*>(&Bs[buf][1024 + ks * 512 + lane * 8]);
            acc = MFMA(fah[ks], bh, acc); acc = MFMA(fah[ks], bl, acc); acc = MFMA(fal[ks], bh, acc);
          }
        } else {
          const bf16x8 bh = *reinterpret_cast<const bf16x8*>(&Bs[buf][lane * 8]);
          const bf16x8 bl = *reinterpret_cast<const bf16x8*>(&Bs[buf][1024 + lane * 8]);
          acc = MFMA(eah, bh, acc); acc = MFMA(eah, bl, acc); acc = MFMA(eal, bh, acc);
        }
        if (role < 0) {
          tp[nt][0] = (unsigned)f2bf(acc[0]) | ((unsigned)f2bf(acc[1]) << 16);
          tp[nt][1] = (unsigned)f2bf(acc[2]) | ((unsigned)f2bf(acc[3]) << 16);
        } else {
          #pragma unroll
          for (int r = 0; r < 4; ++r) {
            const float tv = bf2f((u16)((tp[nt][r >> 1] >> ((r & 1) * 16)) & 0xffffu));
            Ct[(rw + quad * 4 + r) * 80 + ((nt * 16 + lrow) ^ (quad << 4))] = f2bf(acc[r] * tv);
          }
        }
        buf ^= 1;
      }
      if (role >= 0) STORE_P(cmbP + (size_t)role * ((size_t)EE * 64));
    }
  }
}

// ---------------------------------------------------------------------------
// Node linears, MERGED (R14): one dispatch for lin_s (blocks 0..255) and
// lin_v (blocks 256..1023). A single bf16 (R13), B h+l split: 2 MFMAs/step.
// Math identical to the two k_mgemm<32,0,false,{1,3},false> dispatches.
// ---------------------------------------------------------------------------
__global__ __launch_bounds__(256) void k_linm(
    const u16* __restrict__ ms_h, const u16* __restrict__ mv_h,
    const u16* __restrict__ wt_h, const u16* __restrict__ wt_l,
    float* __restrict__ ms2, float* __restrict__ mv2,
    const float* __restrict__ dens)
{
  __shared__ u16 Ah[32 * 40];
  __shared__ u16 Bh[64 * 40];
  __shared__ u16 Bl[64 * 40];
  const int tid  = threadIdx.x;
  const bool isv = blockIdx.x >= (NN / 32);
  const int row0 = (isv ? (int)blockIdx.x - NN / 32 : (int)blockIdx.x) * 32;
  const u16* X   = isv ? mv_h : ms_h;
  const int K    = isv ? 512 : 320;
  const u16* Wth = wt_h + (isv ? OFF_LINV : OFF_LINS);
  const u16* Wtl = wt_l + (isv ? OFF_LINV : OFF_LINS);
  float* O       = isv ? mv2 : ms2;
  const int wave = tid >> 6, lane = tid & 63;
  const int quad = lane >> 4, lrow = lane & 15;
  const int kbase = quad * 8;

  f32x4 acc[2] = {};

  for (int k0 = 0; k0 < K; k0 += 32) {
    if (tid < 128) {                         // A: 32 rows x 4 chunks (h only)
      const int r = tid >> 2, c = tid & 3;
      const uint4 v = *reinterpret_cast<const uint4*>(&X[(size_t)(row0 + r) * K + k0 + c * 8]);
      *reinterpret_cast<uint4*>(&Ah[r * 40 + c * 8]) = v;
    }
    #pragma unroll
    for (int i = 0; i < 2; ++i) {            // B: 64 cols x 4 chunks, h+l
      const int idx = tid + i * 256;
      const int b = idx >> 8, rc = idx & 255;
      const int n = rc >> 2, c = rc & 3;
      const uint4 v = *reinterpret_cast<const uint4*>(
          &(b ? Wtl : Wth)[(size_t)n * K + k0 + c * 8]);
      *reinterpret_cast<uint4*>(&(b ? Bl : Bh)[n * 40 + c * 8]) = v;
    }
    __syncthreads();

    bf16x8 fah[2], fbh, fbl;
    #pragma unroll
    for (int mt = 0; mt < 2; ++mt)
      fah[mt] = *reinterpret_cast<const bf16x8*>(&Ah[(mt * 16 + lrow) * 40 + kbase]);
    {
      const int ro = (wave * 16 + lrow) * 40 + kbase;
      fbh = *reinterpret_cast<const bf16x8*>(&Bh[ro]);
      fbl = *reinterpret_cast<const bf16x8*>(&Bl[ro]);
    }
    #pragma unroll
    for (int mt = 0; mt < 2; ++mt) {
      acc[mt] = MFMA(fah[mt], fbh, acc[mt]);
      acc[mt] = MFMA(fah[mt], fbl, acc[mt]);
    }
    __syncthreads();
  }

  #pragma unroll
  for (int mt = 0; mt < 2; ++mt)
    #pragma unroll
    for (int r = 0; r < 4; ++r) {
      const int grow = row0 + mt * 16 + quad * 4 + r;
      const int gcol = wave * 16 + lrow;
      const int nidx = isv ? (grow / 3) : grow;
      const float t = acc[mt][r] * (1.0f / (dens[nidx] + 1.0f));
      O[(size_t)grow * 64 + gcol] = t;
    }
}

// ---------------------------------------------------------------------------
// Skip contraction as MFMA GEMM, MERGED s+v, direct write into out (N,64,4).
// R14: A operand SINGLE bf16 (R13 showed the A l-plane costs zero absmax at
// the same pipeline depth): staging split2 -> f2bf (halves the VALU-heavy
// A-build incl. the per-element k/10 division), Al gone, 3 -> 2 MFMAs/step.
// ---------------------------------------------------------------------------
__global__ __launch_bounds__(256) void k_skipm(
    const float* __restrict__ ms2, const float* __restrict__ mv2,
    const float* __restrict__ na,
    const u16* __restrict__ wt_h, const u16* __restrict__ wt_l,
    float* __restrict__ out)
{
  __shared__ u16 Ah[32 * 40];
  __shared__ u16 Bh[64 * 40];
  __shared__ u16 Bl[64 * 40];
  const int tid  = threadIdx.x;
  const bool isv = blockIdx.x >= (NN / 32);
  const int row0 = (isv ? (blockIdx.x - NN / 32) : blockIdx.x) * 32;
  const float* C = isv ? mv2 : ms2;
  const u16* Bth = wt_h + (isv ? OFF_SKV : OFF_SKS);
  const u16* Btl = wt_l + (isv ? OFF_SKV : OFF_SKS);
  const int wave = tid >> 6, lane = tid & 63;
  const int quad = lane >> 4, lrow = lane & 15;
  const int kbase = quad * 8;

  f32x4 acc[2] = {};

  for (int k0 = 0; k0 < 640; k0 += 32) {
    #pragma unroll
    for (int i = 0; i < 4; ++i) {
      const int e = tid + i * 256;
      const int r = e >> 5, kk = e & 31;
      const int k = k0 + kk;
      const int u = k / 10, v = k - u * 10;
      const int row = row0 + r;
      const int n = isv ? (row / 3) : row;
      const float t = C[(size_t)row * 64 + u] * na[n * 10 + v];
      Ah[r * 40 + kk] = f2bf(t);
    }
    #pragma unroll
    for (int i = 0; i < 2; ++i) {
      const int idx = tid + i * 256;
      const int b = idx >> 8, rc = idx & 255;
      const int nw = rc >> 2, c = rc & 3;
      const uint4 v4 = *reinterpret_cast<const uint4*>(
          &(b ? Btl : Bth)[(size_t)nw * 640 + k0 + c * 8]);
      *reinterpret_cast<uint4*>(&(b ? Bl : Bh)[nw * 40 + c * 8]) = v4;
    }
    __syncthreads();

    bf16x8 fah[2], fbh, fbl;
    #pragma unroll
    for (int mt = 0; mt < 2; ++mt)
      fah[mt] = *reinterpret_cast<const bf16x8*>(&Ah[(mt * 16 + lrow) * 40 + kbase]);
    {
      const int ro = (wave * 16 + lrow) * 40 + kbase;
      fbh = *reinterpret_cast<const bf16x8*>(&Bh[ro]);
      fbl = *reinterpret_cast<const bf16x8*>(&Bl[ro]);
    }
    #pragma unroll
    for (int mt = 0; mt < 2; ++mt) {
      acc[mt] = MFMA(fah[mt], fbh, acc[mt]);
      acc[mt] = MFMA(fah[mt], fbl, acc[mt]);
    }
    __syncthreads();
  }

  #pragma unroll
  for (int mt = 0; mt < 2; ++mt)
    #pragma unroll
    for (int r = 0; r < 4; ++r) {
      const int row = row0 + mt * 16 + quad * 4 + r;
      const int w = wave * 16 + lrow;
      if (isv) {
        const int n = row / 3, i = row - n * 3;
        out[(size_t)n * 256 + w * 4 + 1 + i] = acc[mt][r];
      } else {
        out[(size_t)row * 256 + w * 4] = acc[mt][r];
      }
    }
}

// ---------------------------------------------------------------------------
// fp32 up-projections, MERGED (R14): z==0 -> s (xes=1), z=1..3 -> v comp z-1.
// K=64 exactly (one tile). Math identical to the two k_gemm<32> dispatches.
// ---------------------------------------------------------------------------
__global__ __launch_bounds__(256) void k_gemm2(
    const float* __restrict__ X,
    const float* __restrict__ W_s, const float* __restrict__ W_v,
    float* __restrict__ s_buf, float* __restrict__ v_buf)
{
  __shared__ float Xs[32 * 65];
  __shared__ float Ws[64 * 64];
  const int tid  = threadIdx.x;
  const int row0 = blockIdx.x * 32;
  const int z    = blockIdx.z;
  const bool iss = (z == 0);
  const int xes  = iss ? 1 : 3;
  const int xc   = iss ? 0 : 64 + (z - 1);
  const float* W = iss ? W_s : W_v;
  float* OUTp    = iss ? s_buf : v_buf;
  const int ors  = iss ? 64 : 192;
  const int oo   = iss ? 0 : (z - 1) * 64;
  const int ci = tid & 15, ri = tid >> 4;
  float acc[2][4] = {};

  for (int idx = tid; idx < 64 * 32; idx += 256) {
    const int r = idx >> 6, kk = idx & 63;
    Xs[r * 65 + kk] = X[(size_t)(row0 + r) * 256 + xc + (size_t)kk * xes];
  }
  for (int idx = tid; idx < 64 * 64; idx += 256) {
    Ws[idx] = W[idx];
  }
  __syncthreads();
  for (int kk = 0; kk < 64; ++kk) {
    const float4 wv = *reinterpret_cast<const float4*>(&Ws[kk * 64 + ci * 4]);
    #pragma unroll
    for (int j = 0; j < 2; ++j) {
      const float x = Xs[(ri * 2 + j) * 65 + kk];
      acc[j][0] += x * wv.x; acc[j][1] += x * wv.y;
      acc[j][2] += x * wv.z; acc[j][3] += x * wv.w;
    }
  }
  #pragma unroll
  for (int j = 0; j < 2; ++j) {
    const int row = row0 + ri * 2 + j;
    *reinterpret_cast<float4*>(OUTp + (size_t)row * ors + oo + ci * 4) =
        make_float4(acc[j][0] * 0.125f, acc[j][1] * 0.125f,
                    acc[j][2] * 0.125f, acc[j][3] * 0.125f);
  }
}

// ---------------------------------------------------------------------------
// CSR build
// ---------------------------------------------------------------------------
__global__ __launch_bounds__(256) void k_count(const int* __restrict__ rcv, int* __restrict__ counts) {
  const int e = blockIdx.x * 256 + threadIdx.x;
  atomicAdd(&counts[rcv[e]], 1);
}

__global__ __launch_bounds__(1024) void k_scan(const int* __restrict__ counts,
                                               int* __restrict__ offs, int* __restrict__ cursor) {
  __shared__ int part[1024];
  const int tid = threadIdx.x;
  int local[8];
  int s = 0;
  #pragma unroll
  for (int j = 0; j < 8; ++j) { local[j] = s; s += counts[tid * 8 + j]; }
  part[tid] = s;
  __syncthreads();
  for (int off = 1; off < 1024; off <<= 1) {
    int v = 0;
    if (tid >= off) v = part[tid - off];
    __syncthreads();
    part[tid] += v;
    __syncthreads();
  }
  const int base = part[tid] - s;
  #pragma unroll
  for (int j = 0; j < 8; ++j) {
    const int o = base + local[j];
    offs[tid * 8 + j] = o;
    cursor[tid * 8 + j] = o;
  }
  if (tid == 1023) offs[NN] = part[1023];
}

__global__ __launch_bounds__(256) void k_fill(const int* __restrict__ rcv,
                                              int* __restrict__ cursor, int* __restrict__ perm) {
  const int e = blockIdx.x * 256 + threadIdx.x;
  const int pos = atomicAdd(&cursor[rcv[e]], 1);
  perm[pos] = e;
}

// ---------------------------------------------------------------------------
// Build the pre-split, pre-scaled weight table (R11 layout, verbatim).
// ---------------------------------------------------------------------------
__global__ __launch_bounds__(256) void k_permw(
    const float* __restrict__ w0, const float* __restrict__ w1,
    const float* __restrict__ w2, const float* __restrict__ w3,
    const float* __restrict__ mag_w, const float* __restrict__ lin_s,
    const float* __restrict__ lin_v, const float* __restrict__ skip_s,
    const float* __restrict__ skip_v,
    u16* __restrict__ wt_h, u16* __restrict__ wt_l)
{
  const int id = blockIdx.x * 256 + threadIdx.x;   // WT_TOTAL threads
  float val = 0.f;
  if (id < OFF_W1) {                       // W0: 4 tiles (nt)
    const int i = id - OFF_W0;
    const int tile = i >> 9, rem = i & 511, lane = rem >> 3, e = rem & 7;
    const int quad = lane >> 4, lrow = lane & 15;
    const int n = tile * 16 + lrow, k = quad * 8 + e;
    val = (k < 16) ? w0[k * 64 + n] * 0.25f : 0.f;
  } else if (id < OFF_W2) {                // W1: 8 tiles (nt*2+ks)
    const int i = id - OFF_W1;
    const int tile = i >> 9, rem = i & 511, lane = rem >> 3, e = rem & 7;
    const int quad = lane >> 4, lrow = lane & 15;
    const int n = (tile >> 1) * 16 + lrow, k = (tile & 1) * 32 + quad * 8 + e;
    val = w1[k * 64 + n] * 0.125f;
  } else if (id < OFF_W3M5) {              // W2: 8 tiles
    const int i = id - OFF_W2;
    const int tile = i >> 9, rem = i & 511, lane = rem >> 3, e = rem & 7;
    const int quad = lane >> 4, lrow = lane & 15;
    const int n = (tile >> 1) * 16 + lrow, k = (tile & 1) * 32 + quad * 8 + e;
    val = w2[k * 64 + n] * 0.125f;
  } else if (id < OFF_MAG) {               // W3M5: 40 tiles ((j*4+nt)*2+ks), K=64
    const int i = id - OFF_W3M5;
    const int tile = i >> 9, rem = i & 511, lane = rem >> 3, e = rem & 7;
    const int quad = lane >> 4, lrow = lane & 15;
    const int gnt = tile >> 1, ks = tile & 1;
    const int n = (gnt >> 2) * 64 + (gnt & 3) * 16 + lrow;   // tpv plane j = n>>6
    const int k = ks * 32 + quad * 8 + e;                    // k < 64
    val = w3[k * 320 + n] * 0.125f;
  } else if (id < OFF_LINS) {              // MAG: 52 tiles (p*4+nt), K=32
    const int i = id - OFF_MAG;
    const int tile = i >> 9, rem = i & 511, lane = rem >> 3, e = rem & 7;
    const int quad = lane >> 4, lrow = lane & 15;
    const int n = (tile >> 2) * 64 + (tile & 3) * 16 + lrow; // p = n>>6, u = n&63
    const int k = quad * 8 + e;
    const int p = n >> 6, u = n & 63;
    val = (k < 16) ? mag_w[k * 832 + p * 64 + u] * 0.25f : 0.f;
  } else if (id < OFF_LINV) {
    const int i = id - OFF_LINS, n = i / 320, k = i - n * 320;
    val = lin_s[k * 64 + n] * 0.05590169944f;
  } else if (id < OFF_SKS) {
    const int i = id - OFF_LINV, n = i >> 9, k = i & 511;
    val = lin_v[k * 64 + n] * 0.04419417382f;
  } else if (id < OFF_SKV) {
    const int i = id - OFF_SKS, w = i / 640, k = i - w * 640;
    val = skip_s[k * 64 + w] * 0.03952847075f;   // [u*10+v][w], 1/sqrt(640)
  } else if (id < WT_TOTAL) {
    const int i = id - OFF_SKV, w = i / 640, k = i - w * 640;
    val = skip_v[k * 64 + w] * 0.03952847075f;
  } else {
    return;
  }
  u16 hh, ll;
  split2(val, hh, ll);
  wt_h[id] = hh;
  wt_l[id] = ll;
}

// ---------------------------------------------------------------------------
// Permute edge data into receiver-grouped (perm) order + precompute:
//   snd_perm, ya_perm, dq_perm (tanh(q^2)), efm split pair.
// ---------------------------------------------------------------------------
__global__ __launch_bounds__(256) void k_build(
    const int* __restrict__ perm, const int* __restrict__ snd,
    const float* __restrict__ edge_attrs, const float* __restrict__ edge_feats,
    const float* __restrict__ mm_inv, const float* __restrict__ dens_w,
    int* __restrict__ snd_perm, float* __restrict__ ya_perm,
    float* __restrict__ dq_perm, u16* __restrict__ efm_h, u16* __restrict__ efm_l)
{
  const int pos = blockIdx.x * 256 + threadIdx.x;
  const int e = perm[pos];
  const int s = snd[e];
  snd_perm[pos] = s;
  reinterpret_cast<float4*>(ya_perm)[pos] = reinterpret_cast<const float4*>(edge_attrs)[e];
  const float4 ef0 = reinterpret_cast<const float4*>(edge_feats)[e * 2];
  const float4 ef1 = reinterpret_cast<const float4*>(edge_feats)[e * 2 + 1];
  const float4 mi0 = reinterpret_cast<const float4*>(mm_inv)[s * 2];
  const float4 mi1 = reinterpret_cast<const float4*>(mm_inv)[s * 2 + 1];
  float q = ef0.x * dens_w[0] + ef0.y * dens_w[1] + ef0.z * dens_w[2] + ef0.w * dens_w[3]
          + ef1.x * dens_w[4] + ef1.y * dens_w[5] + ef1.z * dens_w[6] + ef1.w * dens_w[7];
  q *= 0.35355339059f;   // 1/sqrt(8)
  dq_perm[pos] = tanhf(q * q);
  float vals[16] = { ef0.x, ef0.y, ef0.z, ef0.w, ef1.x, ef1.y, ef1.z, ef1.w,
                     mi0.x, mi0.y, mi0.z, mi0.w, mi1.x, mi1.y, mi1.z, mi1.w };
  u16 hh[16], ll[16];
  #pragma unroll
  for (int i = 0; i < 16; ++i) split2(vals[i], hh[i], ll[i]);
  reinterpret_cast<uint4*>(&efm_h[(size_t)pos * 16])[0] = reinterpret_cast<uint4*>(hh)[0];
  reinterpret_cast<uint4*>(&efm_h[(size_t)pos * 16])[1] = reinterpret_cast<uint4*>(hh)[1];
  reinterpret_cast<uint4*>(&efm_l[(size_t)pos * 16])[0] = reinterpret_cast<uint4*>(ll)[0];
  reinterpret_cast<uint4*>(&efm_l[(size_t)pos * 16])[1] = reinterpret_cast<uint4*>(ll)[1];
}

// ---------------------------------------------------------------------------
// Gather: TWO half-waves per node (halved serial edge chain, LDS reduction).
// ms/mv written as SINGLE bf16 (R13).
// ---------------------------------------------------------------------------
__global__ __launch_bounds__(256) void k_gather(
    const int* __restrict__ snd_perm,
    const float* __restrict__ ya_perm,
    const float* __restrict__ dq_perm,
    const float* __restrict__ mm_attrs,
    const float* __restrict__ s_buf,
    const float* __restrict__ v_buf,
    const u16* __restrict__ cmbP,
    const int* __restrict__ offs,
    u16* __restrict__ ms_h, u16* __restrict__ mv_h,
    float* __restrict__ dens)
{
  __shared__ float red[2][30][64];
  const int tid  = threadIdx.x;
  const int lane = tid & 63;
  const int nib  = tid >> 7;                 // node within block (0/1)
  const int half = (tid >> 6) & 1;           // segment half (0/1)
  const int n = blockIdx.x * 2 + nib;

  float acc_s[5] = {0.f, 0.f, 0.f, 0.f, 0.f};
  float acc_v[8][3] = {};
  float dacc = 0.f;
  const int start0 = offs[n], end0 = offs[n + 1];
  const int mid = start0 + ((end0 - start0 + 1) >> 1);
  const int start = half ? mid : start0;
  const int end   = half ? end0 : mid;

  int s_nx = 0;
  if (start < end) s_nx = snd_perm[start];
  for (int pos = start; pos < end; ++pos) {
    const int s = s_nx;
    if (pos + 1 < end) s_nx = snd_perm[pos + 1];

    const float4 ya = reinterpret_cast<const float4*>(ya_perm)[pos];
    const float4 mm = reinterpret_cast<const float4*>(mm_attrs)[s];
    dacc += dq_perm[pos];
    const float y0 = ya.x, y1x = ya.y, y1y = ya.z, y1z = ya.w;
    const float m0 = mm.x, m1x = mm.y, m1y = mm.z, m1z = mm.w;
    const float xs  = s_buf[s * 64 + lane];
    const float xvx = v_buf[(s * 3 + 0) * 64 + lane];
    const float xvy = v_buf[(s * 3 + 1) * 64 + lane];
    const float xvz = v_buf[(s * 3 + 2) * 64 + lane];

    float cp[13];
    #pragma unroll
    for (int p = 0; p < 13; ++p)
      cp[p] = bf2f(cmbP[(size_t)p * ((size_t)EE * 64) + (size_t)pos * 64 + lane]);

    // geometry (tpv folded into cp in k_edge)
    const float gs0 = xs * y0;
    const float gd  = (xvx * y1x + xvy * y1y + xvz * y1z) * 0.57735026919f;
    const float g0x = xs * y1x, g0y = xs * y1y, g0z = xs * y1z;
    const float g1x = xvx * y0, g1y = xvy * y0, g1z = xvz * y0;
    const float g2x = (xvy * y1z - xvz * y1y) * 0.70710678119f;
    const float g2y = (xvz * y1x - xvx * y1z) * 0.70710678119f;
    const float g2z = (xvx * y1y - xvy * y1x) * 0.70710678119f;

    acc_s[0]    += cp[0] * gs0 * m0;
    acc_v[0][0] += cp[1] * gs0 * m1x; acc_v[0][1] += cp[1] * gs0 * m1y; acc_v[0][2] += cp[1] * gs0 * m1z;
    acc_s[1]    += cp[2] * gd * m0;
    acc_v[1][0] += cp[3] * gd * m1x; acc_v[1][1] += cp[3] * gd * m1y; acc_v[1][2] += cp[3] * gd * m1z;

#define VV_BLOCK(vx, vy, vz, cA, cB, cC, vslotA, sslot, vslotB)                           \
    acc_v[vslotA][0] += (cA) * (vx) * m0;                                                 \
    acc_v[vslotA][1] += (cA) * (vy) * m0;                                                 \
    acc_v[vslotA][2] += (cA) * (vz) * m0;                                                 \
    acc_s[sslot] += (cB) * ((vx) * m1x + (vy) * m1y + (vz) * m1z) * 0.57735026919f;       \
    {                                                                                     \
      const float ccx = (vy) * m1z - (vz) * m1y;                                          \
      const float ccy = (vz) * m1x - (vx) * m1z;                                          \
      const float ccz = (vx) * m1y - (vy) * m1x;                                          \
      acc_v[vslotB][0] += (cC) * ccx * 0.70710678119f;                                    \
      acc_v[vslotB][1] += (cC) * ccy * 0.70710678119f;                                    \
      acc_v[vslotB][2] += (cC) * ccz * 0.70710678119f;                                    \
    }

    VV_BLOCK(g0x, g0y, g0z, cp[4], cp[5], cp[6], 2, 2, 3)
    VV_BLOCK(g1x, g1y, g1z, cp[7], cp[8], cp[9], 4, 3, 5)
    VV_BLOCK(g2x, g2y, g2z, cp[10], cp[11], cp[12], 6, 4, 7)
#undef VV_BLOCK
  }

  // ---- combine the two half-waves of each node via LDS ----
  if (half == 1) {
    #pragma unroll
    for (int j = 0; j < 5; ++j) red[nib][j][lane] = acc_s[j];
    #pragma unroll
    for (int p = 0; p < 8; ++p)
      #pragma unroll
      for (int i = 0; i < 3; ++i) red[nib][5 + p * 3 + i][lane] = acc_v[p][i];
    red[nib][29][lane] = dacc;
  }
  __syncthreads();
  if (half == 0) {
    #pragma unroll
    for (int j = 0; j < 5; ++j) acc_s[j] += red[nib][j][lane];
    #pragma unroll
    for (int p = 0; p < 8; ++p)
      #pragma unroll
      for (int i = 0; i < 3; ++i) acc_v[p][i] += red[nib][5 + p * 3 + i][lane];
    dacc += red[nib][29][lane];

    #pragma unroll
    for (int j = 0; j < 5; ++j)
      ms_h[(size_t)n * 320 + j * 64 + lane] = f2bf(acc_s[j]);
    #pragma unroll
    for (int p = 0; p < 8; ++p)
      #pragma unroll
      for (int i = 0; i < 3; ++i)
        mv_h[((size_t)n * 3 + i) * 512 + p * 64 + lane] = f2bf(acc_v[p][i]);
    if (lane == 0) dens[n] = dacc;
  }
}

// ---------------------------------------------------------------------------
extern "C" void kernel_launch(void* const* d_in, const int* in_sizes, int n_in,
                              void* d_out, int out_size, void* d_ws, size_t ws_size,
                              hipStream_t stream)
{
  const float* node_attrs = (const float*)d_in[0];
  const float* node_feats = (const float*)d_in[1];
  const float* edge_attrs = (const float*)d_in[2];
  const float* edge_feats = (const float*)d_in[3];
  const int*   edge_index = (const int*)d_in[4];
  const float* mm_inv     = (const float*)d_in[5];
  const float* mm_attrs   = (const float*)d_in[6];
  const float* W_up_s     = (const float*)d_in[7];
  const float* W_up_v     = (const float*)d_in[8];
  const float* w0         = (const float*)d_in[9];
  const float* w1         = (const float*)d_in[10];
  const float* w2         = (const float*)d_in[11];
  const float* w3         = (const float*)d_in[12];
  const float* mag_w      = (const float*)d_in[13];
  const float* dens_w     = (const float*)d_in[14];
  const float* lin_s      = (const float*)d_in[15];
  const float* lin_v      = (const float*)d_in[16];
  const float* skip_s     = (const float*)d_in[17];
  const float* skip_v     = (const float*)d_in[18];
  float* out = (float*)d_out;

  char* wp = (char*)d_ws;
  auto alloc = [&](size_t b) { char* p = wp; wp += (b + 255) & ~(size_t)255; return p; };
  float* s_buf  = (float*)alloc((size_t)NN * 64 * 4);       // 2.10 MB
  float* v_buf  = (float*)alloc((size_t)NN * 192 * 4);      // 6.29 MB
  float* ya_p   = (float*)alloc((size_t)EE * 4 * 4);        // 1.05 MB
  float* dq_p   = (float*)alloc((size_t)EE * 4);            // 0.26 MB
  int*   snd_p  = (int*)alloc((size_t)EE * 4);              // 0.26 MB
  u16*   efm_h  = (u16*)alloc((size_t)EE * 16 * 2);         // 2.10 MB
  u16*   efm_l  = (u16*)alloc((size_t)EE * 16 * 2);         // 2.10 MB
  u16*   hA_h   = (u16*)alloc((size_t)EE * 64 * 2);         // 8.39 MB (ms2/mv2 backing)
  u16*   hA_l   = (u16*)alloc((size_t)EE * 64 * 2);         // 8.39 MB
  u16*   hB_h   = (u16*)alloc((size_t)EE * 64 * 2);         // 8.39 MB (ms_h backing)
  u16*   cmbP   = (u16*)alloc((size_t)13 * EE * 64 * 2);    // 109 MB  [13][EE][64]
  u16*   mv_h   = (u16*)alloc((size_t)NN * 1536 * 2);       // 25.2 MB
  float* dens   = (float*)alloc((size_t)NN * 4);
  int*   counts = (int*)alloc((size_t)NN * 4);
  int*   offs   = (int*)alloc((size_t)(NN + 1) * 4);
  int*   cursor = (int*)alloc((size_t)NN * 4);
  int*   perm   = (int*)alloc((size_t)EE * 4);
  u16*   wt_h   = (u16*)alloc((size_t)WT_TOTAL * 2);        // 0.39 MB
  u16*   wt_l   = (u16*)alloc((size_t)WT_TOTAL * 2);        // 0.39 MB
  u16*   ms_h   = hB_h;            // NN*320*2 = 5.25 MB <= 8.39 MB
  float* ms2    = (float*)hA_h;    // 2.10 MB <= 8.39 MB
  float* mv2    = (float*)hA_l;    // 6.29 MB <= 8.39 MB

  const int* snd = edge_index;
  const int* rcv = edge_index + EE;

  // CSR + permuted edge data + pre-split fragment-ordered weight table
  hipMemsetAsync(counts, 0, (size_t)NN * 4, stream);
  k_count<<<EE / 256, 256, 0, stream>>>(rcv, counts);
  k_scan<<<1, 1024, 0, stream>>>(counts, offs, cursor);
  k_fill<<<EE / 256, 256, 0, stream>>>(rcv, cursor, perm);
  k_build<<<EE / 256, 256, 0, stream>>>(perm, snd, edge_attrs, edge_feats, mm_inv, dens_w,
                                        snd_p, ya_p, dq_p, efm_h, efm_l);
  k_permw<<<(WT_TOTAL + 255) / 256, 256, 0, stream>>>(w0, w1, w2, w3, mag_w, lin_s, lin_v,
                                                     skip_s, skip_v, wt_h, wt_l);

  // node up-projections, merged (z==0: s, z=1..3: v components)
  k_gemm2<<<dim3(NN / 32, 1, 4), 256, 0, stream>>>(
      node_feats, W_up_s, W_up_v, s_buf, v_buf);

  // FUSED edge pipeline: w0/w1/w2 + 13 product planes (tpv folded in)
  k_edge<<<EE / 64, 256, 0, stream>>>(efm_h, efm_l, wt_h, wt_l, cmbP);

  // per-node gather (2 half-waves/node) + tensor product + segment sum
  k_gather<<<NN / 2, 256, 0, stream>>>(snd_p, ya_p, dq_p, mm_attrs,
                                       s_buf, v_buf, cmbP, offs,
                                       ms_h, mv_h, dens);

  // node linears, merged (blocks 0..255: lin_s; 256..1023: lin_v)
  k_linm<<<NN / 32 + NN * 3 / 32, 256, 0, stream>>>(
      ms_h, mv_h, wt_h, wt_l, ms2, mv2, dens);

  // skip contraction on MFMA (merged s+v, single-bf16 A, direct out write)
  k_skipm<<<NN / 32 + NN * 3 / 32, 256, 0, stream>>>(
      ms2, mv2, node_attrs, wt_h, wt_l, out);
}

// Round 15
// 246.318 us; speedup vs baseline: 1.2127x; 1.0198x over previous
//
#include <hip/hip_runtime.h>
#include <hip/hip_bf16.h>

#define NN 8192
#define EE 65536

typedef unsigned short u16;
typedef __attribute__((ext_vector_type(8))) short bf16x8;          // 8 bf16 = 4 VGPRs
typedef __attribute__((ext_vector_type(8))) unsigned short u16x8;  // 16 B load
typedef __attribute__((ext_vector_type(4))) float f32x4;

// Pre-split weight table offsets (elements, shared by h/l planes).
// R11 zero-trimmed layout (verbatim). LINS/LINV row-major.
//   W3M5: 40 tiles ((j*4+nt)*2+ks), j = tpv plane 0..4, K=64
//   MAG:  52 tiles (p*4+nt), p = wm plane 0..12, K=32
#define OFF_W0    0        // 4   tiles (nt)
#define OFF_W1    2048     // 8   tiles (nt*2+ks)
#define OFF_W2    6144     // 8   tiles
#define OFF_W3M5  10240    // 40  tiles
#define OFF_MAG   30720    // 52  tiles
#define OFF_LINS  57344    // 64 x 320 (row-major)
#define OFF_LINV  77824    // 64 x 512
#define OFF_SKS   110592   // 64 x 640  (skip_s reshaped [w][u*10+v], *1/fan)
#define OFF_SKV   151552   // 64 x 640  (skip_v)
#define WT_TOTAL  192512

// Plane schedule (single live tpv plane):
// kind: 0 = tpv (K=64, 2 ks sub-tiles, A = h), 1 = wm (K=32, A = efm).
__device__ const int PKIND[18] = {0,1,1, 0,1,1, 0,1,1,1, 0,1,1,1, 0,1,1,1};
__device__ const int PTILE[18] = {0,0,1, 3,2,3, 1,4,5,6, 2,7,8,9, 4,10,11,12};
__device__ const int PROLE[18] = {-1,0,1, -1,2,3, -1,4,5,6, -1,7,8,9, -1,10,11,12};

__device__ __forceinline__ u16 f2bf(float f) {
  __hip_bfloat16 h = __float2bfloat16(f);
  return *reinterpret_cast<u16*>(&h);
}
__device__ __forceinline__ float bf2f(u16 v) {
  union { unsigned int u; float f; } x; x.u = ((unsigned int)v) << 16; return x.f;
}
__device__ __forceinline__ void split2(float x, u16& h, u16& l) {
  __hip_bfloat16 bh = __float2bfloat16(x);
  h = *reinterpret_cast<u16*>(&bh);
  float r = x - __bfloat162float(bh);
  __hip_bfloat16 bl = __float2bfloat16(r);
  l = *reinterpret_cast<u16*>(&bl);
}

#define MFMA(a, b, c) __builtin_amdgcn_mfma_f32_16x16x32_bf16((a), (b), (c), 0, 0, 0)

// ---------------------------------------------------------------------------
// FUSED edge pipeline (R11, unchanged): staged/barriered with zero-tile cut.
// ---------------------------------------------------------------------------
__global__ __launch_bounds__(256, 4) void k_edge(
    const u16* __restrict__ efm_h, const u16* __restrict__ efm_l,
    const u16* __restrict__ wt_h, const u16* __restrict__ wt_l,
    u16* __restrict__ cmbP)
{
  __shared__ u16 Hh[64 * 72], Hl[64 * 72];   // h, K=64 (18432 B)
  __shared__ u16 Bs[2][2048];                // staged B tiles: h at 0, l at 1024 (8192 B)
  __shared__ u16 Ct[64 * 80];                // output staging, quad-XOR swizzled (10240 B)
  const int tid  = threadIdx.x;
  const size_t pos0 = (size_t)blockIdx.x * 64;
  const int wave = tid >> 6, lane = tid & 63;
  const int quad = lane >> 4, lrow = lane & 15;
  const int kbase = quad * 8;
  const int rw = wave * 16;

  // ---- E fragments directly from global (K=16 zero-padded to 32) ----
  bf16x8 eah = {}, eal = {};
  if (quad < 2) {
    eah = *reinterpret_cast<const bf16x8*>(&efm_h[(pos0 + rw + lrow) * 16 + kbase]);
    eal = *reinterpret_cast<const bf16x8*>(&efm_l[(pos0 + rw + lrow) * 16 + kbase]);
  }

  // ---- L0: h = silu(efm @ w0), K=32 (padded), N=64 — contiguous frag loads ----
  {
    #pragma unroll
    for (int nt = 0; nt < 4; ++nt) {
      const size_t bo = (size_t)nt * 512 + lane * 8;
      const bf16x8 fbh = *reinterpret_cast<const bf16x8*>(wt_h + OFF_W0 + bo);
      const bf16x8 fbl = *reinterpret_cast<const bf16x8*>(wt_l + OFF_W0 + bo);
      f32x4 acc = {};
      acc = MFMA(eah, fbh, acc); acc = MFMA(eah, fbl, acc); acc = MFMA(eal, fbh, acc);
      #pragma unroll
      for (int r = 0; r < 4; ++r) {
        float t = acc[r];
        t = t / (1.0f + __expf(-t));
        u16 hh, ll; split2(t, hh, ll);
        const int row = rw + quad * 4 + r, col = nt * 16 + lrow;
        Hh[row * 72 + col] = hh; Hl[row * 72 + col] = ll;
      }
    }
  }

  // ---- L1, L2: h = silu(h @ w), K=64, N=64, in-place ----
  #pragma unroll
  for (int layer = 0; layer < 2; ++layer) {
    const int OFF = layer ? OFF_W2 : OFF_W1;
    bf16x8 fah[2], fal[2];
    #pragma unroll
    for (int ks = 0; ks < 2; ++ks) {
      fah[ks] = *reinterpret_cast<const bf16x8*>(&Hh[(rw + lrow) * 72 + ks * 32 + kbase]);
      fal[ks] = *reinterpret_cast<const bf16x8*>(&Hl[(rw + lrow) * 72 + ks * 32 + kbase]);
    }
    f32x4 acc[4] = {};
    #pragma unroll
    for (int nt = 0; nt < 4; ++nt)
      #pragma unroll
      for (int ks = 0; ks < 2; ++ks) {
        const size_t bo = (size_t)(nt * 2 + ks) * 512 + lane * 8;
        const bf16x8 fbh = *reinterpret_cast<const bf16x8*>(wt_h + OFF + bo);
        const bf16x8 fbl = *reinterpret_cast<const bf16x8*>(wt_l + OFF + bo);
        acc[nt] = MFMA(fah[ks], fbh, acc[nt]);
        acc[nt] = MFMA(fah[ks], fbl, acc[nt]);
        acc[nt] = MFMA(fal[ks], fbh, acc[nt]);
      }
    #pragma unroll
    for (int nt = 0; nt < 4; ++nt)
      #pragma unroll
      for (int r = 0; r < 4; ++r) {
        float t = acc[nt][r];
        t = t / (1.0f + __expf(-t));
        u16 hh, ll; split2(t, hh, ll);
        const int row = rw + quad * 4 + r, col = nt * 16 + lrow;
        Hh[row * 72 + col] = hh; Hl[row * 72 + col] = ll;
      }
  }

  // ---- 18 plane computations, single live tpv plane, LDS-staged weights ----
  {
    bf16x8 fah[2], fal[2];
    #pragma unroll
    for (int ks = 0; ks < 2; ++ks) {
      fah[ks] = *reinterpret_cast<const bf16x8*>(&Hh[(rw + lrow) * 72 + ks * 32 + kbase]);
      fal[ks] = *reinterpret_cast<const bf16x8*>(&Hl[(rw + lrow) * 72 + ks * 32 + kbase]);
    }

    auto STAGE = [&](int pl, int nt, int buf) {
      if (PKIND[pl]) {
        const size_t src = (size_t)OFF_MAG + (size_t)(PTILE[pl] * 4 + nt) * 512;
        if (tid < 128) {
          const int b = (tid >= 64);
          const int off = (tid - (b ? 64 : 0)) * 8;
          *reinterpret_cast<uint4*>(&Bs[buf][(b ? 1024 : 0) + off]) =
              *reinterpret_cast<const uint4*>((b ? wt_l : wt_h) + src + off);
        }
      } else {
        const size_t src = (size_t)OFF_W3M5 + (size_t)(PTILE[pl] * 4 + nt) * 1024;
        const int b = (tid >= 128);
        const int off = (tid - (b ? 128 : 0)) * 8;
        *reinterpret_cast<uint4*>(&Bs[buf][(b ? 1024 : 0) + off]) =
            *reinterpret_cast<const uint4*>((b ? wt_l : wt_h) + src + off);
      }
    };

    auto STORE_P = [&](u16* dst) {
      #pragma unroll
      for (int i = 0; i < 2; ++i) {
        const int idx = lane + i * 64;       // 128 uint4 = 16 rows x 8 chunks
        const int rl = idx >> 3, c2 = idx & 7;
        const uint4 v4 = *reinterpret_cast<const uint4*>(
            &Ct[(rw + rl) * 80 + ((c2 * 8) ^ (((rl >> 2) & 3) << 4))]);
        *reinterpret_cast<uint4*>(&dst[(pos0 + rw + rl) * 64 + c2 * 8]) = v4;
      }
    };

    unsigned int tp[4][2];                   // current tpv plane only (8 u32)
    int buf = 0;
    STAGE(0, 0, 0);
    for (int pl = 0; pl < 18; ++pl) {
      const int kind = PKIND[pl], role = PROLE[pl];
      #pragma unroll
      for (int nt = 0; nt < 4; ++nt) {
        __syncthreads();                     // Bs[buf] staged; readers of buf^1 done
        if (nt < 3) STAGE(pl, nt + 1, buf ^ 1);
        else if (pl + 1 < 18) STAGE(pl + 1, 0, buf ^ 1);
        f32x4 acc = {};
        if (kind == 0) {
          #pragma unroll
          for (int ks = 0; ks < 2; ++ks) {
            const bf16x8 bh = *reinterpret_cast<const bf16x8*>(&Bs[buf][ks * 512 + lane * 8]);
            const bf16x8 bl = *reinterpret_cast<const bf16x8*>(&Bs[buf][1024 + ks * 512 + lane * 8]);
            acc = MFMA(fah[ks], bh, acc); acc = MFMA(fah[ks], bl, acc); acc = MFMA(fal[ks], bh, acc);
          }
        } else {
          const bf16x8 bh = *reinterpret_cast<const bf16x8*>(&Bs[buf][lane * 8]);
          const bf16x8 bl = *reinterpret_cast<const bf16x8*>(&Bs[buf][1024 + lane * 8]);
          acc = MFMA(eah, bh, acc); acc = MFMA(eah, bl, acc); acc = MFMA(eal, bh, acc);
        }
        if (role < 0) {
          tp[nt][0] = (unsigned)f2bf(acc[0]) | ((unsigned)f2bf(acc[1]) << 16);
          tp[nt][1] = (unsigned)f2bf(acc[2]) | ((unsigned)f2bf(acc[3]) << 16);
        } else {
          #pragma unroll
          for (int r = 0; r < 4; ++r) {
            const float tv = bf2f((u16)((tp[nt][r >> 1] >> ((r & 1) * 16)) & 0xffffu));
            Ct[(rw + quad * 4 + r) * 80 + ((nt * 16 + lrow) ^ (quad << 4))] = f2bf(acc[r] * tv);
          }
        }
        buf ^= 1;
      }
      if (role >= 0) STORE_P(cmbP + (size_t)role * ((size_t)EE * 64));
    }
  }
}

// ---------------------------------------------------------------------------
// Node linears + skip contraction, FUSED block-locally (R15).
// Same block->row mapping in both phases: block b owns rows 32b..32b+32 of
// the s (blocks 0..255) or v (256..1023) row space. Phase 1 = k_linm
// (A single-bf16, B h+l, density division at the end) writing its 32x64
// fp32 stripe to LDS (stride 65) instead of ms2/mv2; phase 2 = k_skipm
// reading its A-build source from that LDS stripe. Values bit-identical to
// the split kernels (fp32 global round-trip -> fp32 LDS). Deletes the
// ms2/mv2 buffers (8.4 MB write + 8.4 MB read) and one dispatch.
// ---------------------------------------------------------------------------
__global__ __launch_bounds__(256) void k_lsk(
    const u16* __restrict__ ms_h, const u16* __restrict__ mv_h,
    const float* __restrict__ na,
    const u16* __restrict__ wt_h, const u16* __restrict__ wt_l,
    const float* __restrict__ dens,
    float* __restrict__ out)
{
  __shared__ float Csh[32 * 65];             // 8320 B: phase-1 output stripe
  __shared__ u16 Ah[32 * 40];
  __shared__ u16 Bh[64 * 40];
  __shared__ u16 Bl[64 * 40];
  const int tid  = threadIdx.x;
  const bool isv = blockIdx.x >= (NN / 32);
  const int row0 = (isv ? (int)blockIdx.x - NN / 32 : (int)blockIdx.x) * 32;
  const int wave = tid >> 6, lane = tid & 63;
  const int quad = lane >> 4, lrow = lane & 15;
  const int kbase = quad * 8;

  // ===== phase 1: node linear (k_linm body) =====
  {
    const u16* X   = isv ? mv_h : ms_h;
    const int K    = isv ? 512 : 320;
    const u16* Wth = wt_h + (isv ? OFF_LINV : OFF_LINS);
    const u16* Wtl = wt_l + (isv ? OFF_LINV : OFF_LINS);

    f32x4 acc[2] = {};
    for (int k0 = 0; k0 < K; k0 += 32) {
      if (tid < 128) {                       // A: 32 rows x 4 chunks (h only)
        const int r = tid >> 2, c = tid & 3;
        const uint4 v = *reinterpret_cast<const uint4*>(&X[(size_t)(row0 + r) * K + k0 + c * 8]);
        *reinterpret_cast<uint4*>(&Ah[r * 40 + c * 8]) = v;
      }
      #pragma unroll
      for (int i = 0; i < 2; ++i) {          // B: 64 cols x 4 chunks, h+l
        const int idx = tid + i * 256;
        const int b = idx >> 8, rc = idx & 255;
        const int n = rc >> 2, c = rc & 3;
        const uint4 v = *reinterpret_cast<const uint4*>(
            &(b ? Wtl : Wth)[(size_t)n * K + k0 + c * 8]);
        *reinterpret_cast<uint4*>(&(b ? Bl : Bh)[n * 40 + c * 8]) = v;
      }
      __syncthreads();

      bf16x8 fah[2], fbh, fbl;
      #pragma unroll
      for (int mt = 0; mt < 2; ++mt)
        fah[mt] = *reinterpret_cast<const bf16x8*>(&Ah[(mt * 16 + lrow) * 40 + kbase]);
      {
        const int ro = (wave * 16 + lrow) * 40 + kbase;
        fbh = *reinterpret_cast<const bf16x8*>(&Bh[ro]);
        fbl = *reinterpret_cast<const bf16x8*>(&Bl[ro]);
      }
      #pragma unroll
      for (int mt = 0; mt < 2; ++mt) {
        acc[mt] = MFMA(fah[mt], fbh, acc[mt]);
        acc[mt] = MFMA(fah[mt], fbl, acc[mt]);
      }
      __syncthreads();
    }

    // write stripe to LDS with density division (bit-identical to ms2/mv2)
    #pragma unroll
    for (int mt = 0; mt < 2; ++mt)
      #pragma unroll
      for (int r = 0; r < 4; ++r) {
        const int rloc = mt * 16 + quad * 4 + r;
        const int grow = row0 + rloc;
        const int gcol = wave * 16 + lrow;
        const int nidx = isv ? (grow / 3) : grow;
        Csh[rloc * 65 + gcol] = acc[mt][r] * (1.0f / (dens[nidx] + 1.0f));
      }
  }
  __syncthreads();                           // Csh complete; Ah/Bh/Bl reads done

  // ===== phase 2: skip contraction (k_skipm body, A source = Csh) =====
  {
    const u16* Bth = wt_h + (isv ? OFF_SKV : OFF_SKS);
    const u16* Btl = wt_l + (isv ? OFF_SKV : OFF_SKS);

    f32x4 acc[2] = {};
    for (int k0 = 0; k0 < 640; k0 += 32) {
      #pragma unroll
      for (int i = 0; i < 4; ++i) {
        const int e = tid + i * 256;
        const int r = e >> 5, kk = e & 31;
        const int k = k0 + kk;
        const int u = k / 10, v = k - u * 10;
        const int row = row0 + r;
        const int n = isv ? (row / 3) : row;
        const float t = Csh[r * 65 + u] * na[n * 10 + v];
        Ah[r * 40 + kk] = f2bf(t);
      }
      #pragma unroll
      for (int i = 0; i < 2; ++i) {
        const int idx = tid + i * 256;
        const int b = idx >> 8, rc = idx & 255;
        const int nw = rc >> 2, c = rc & 3;
        const uint4 v4 = *reinterpret_cast<const uint4*>(
            &(b ? Btl : Bth)[(size_t)nw * 640 + k0 + c * 8]);
        *reinterpret_cast<uint4*>(&(b ? Bl : Bh)[nw * 40 + c * 8]) = v4;
      }
      __syncthreads();

      bf16x8 fah[2], fbh, fbl;
      #pragma unroll
      for (int mt = 0; mt < 2; ++mt)
        fah[mt] = *reinterpret_cast<const bf16x8*>(&Ah[(mt * 16 + lrow) * 40 + kbase]);
      {
        const int ro = (wave * 16 + lrow) * 40 + kbase;
        fbh = *reinterpret_cast<const bf16x8*>(&Bh[ro]);
        fbl = *reinterpret_cast<const bf16x8*>(&Bl[ro]);
      }
      #pragma unroll
      for (int mt = 0; mt < 2; ++mt) {
        acc[mt] = MFMA(fah[mt], fbh, acc[mt]);
        acc[mt] = MFMA(fah[mt], fbl, acc[mt]);
      }
      __syncthreads();
    }

    #pragma unroll
    for (int mt = 0; mt < 2; ++mt)
      #pragma unroll
      for (int r = 0; r < 4; ++r) {
        const int row = row0 + mt * 16 + quad * 4 + r;
        const int w = wave * 16 + lrow;
        if (isv) {
          const int n = row / 3, i = row - n * 3;
          out[(size_t)n * 256 + w * 4 + 1 + i] = acc[mt][r];
        } else {
          out[(size_t)row * 256 + w * 4] = acc[mt][r];
        }
      }
  }
}

// ---------------------------------------------------------------------------
// fp32 up-projections, MERGED: z==0 -> s (xes=1), z=1..3 -> v comp z-1.
// ---------------------------------------------------------------------------
__global__ __launch_bounds__(256) void k_gemm2(
    const float* __restrict__ X,
    const float* __restrict__ W_s, const float* __restrict__ W_v,
    float* __restrict__ s_buf, float* __restrict__ v_buf)
{
  __shared__ float Xs[32 * 65];
  __shared__ float Ws[64 * 64];
  const int tid  = threadIdx.x;
  const int row0 = blockIdx.x * 32;
  const int z    = blockIdx.z;
  const bool iss = (z == 0);
  const int xes  = iss ? 1 : 3;
  const int xc   = iss ? 0 : 64 + (z - 1);
  const float* W = iss ? W_s : W_v;
  float* OUTp    = iss ? s_buf : v_buf;
  const int ors  = iss ? 64 : 192;
  const int oo   = iss ? 0 : (z - 1) * 64;
  const int ci = tid & 15, ri = tid >> 4;
  float acc[2][4] = {};

  for (int idx = tid; idx < 64 * 32; idx += 256) {
    const int r = idx >> 6, kk = idx & 63;
    Xs[r * 65 + kk] = X[(size_t)(row0 + r) * 256 + xc + (size_t)kk * xes];
  }
  for (int idx = tid; idx < 64 * 64; idx += 256) {
    Ws[idx] = W[idx];
  }
  __syncthreads();
  for (int kk = 0; kk < 64; ++kk) {
    const float4 wv = *reinterpret_cast<const float4*>(&Ws[kk * 64 + ci * 4]);
    #pragma unroll
    for (int j = 0; j < 2; ++j) {
      const float x = Xs[(ri * 2 + j) * 65 + kk];
      acc[j][0] += x * wv.x; acc[j][1] += x * wv.y;
      acc[j][2] += x * wv.z; acc[j][3] += x * wv.w;
    }
  }
  #pragma unroll
  for (int j = 0; j < 2; ++j) {
    const int row = row0 + ri * 2 + j;
    *reinterpret_cast<float4*>(OUTp + (size_t)row * ors + oo + ci * 4) =
        make_float4(acc[j][0] * 0.125f, acc[j][1] * 0.125f,
                    acc[j][2] * 0.125f, acc[j][3] * 0.125f);
  }
}

// ---------------------------------------------------------------------------
// CSR build
// ---------------------------------------------------------------------------
__global__ __launch_bounds__(256) void k_count(const int* __restrict__ rcv, int* __restrict__ counts) {
  const int e = blockIdx.x * 256 + threadIdx.x;
  atomicAdd(&counts[rcv[e]], 1);
}

__global__ __launch_bounds__(1024) void k_scan(const int* __restrict__ counts,
                                               int* __restrict__ offs, int* __restrict__ cursor) {
  __shared__ int part[1024];
  const int tid = threadIdx.x;
  int local[8];
  int s = 0;
  #pragma unroll
  for (int j = 0; j < 8; ++j) { local[j] = s; s += counts[tid * 8 + j]; }
  part[tid] = s;
  __syncthreads();
  for (int off = 1; off < 1024; off <<= 1) {
    int v = 0;
    if (tid >= off) v = part[tid - off];
    __syncthreads();
    part[tid] += v;
    __syncthreads();
  }
  const int base = part[tid] - s;
  #pragma unroll
  for (int j = 0; j < 8; ++j) {
    const int o = base + local[j];
    offs[tid * 8 + j] = o;
    cursor[tid * 8 + j] = o;
  }
  if (tid == 1023) offs[NN] = part[1023];
}

__global__ __launch_bounds__(256) void k_fill(const int* __restrict__ rcv,
                                              int* __restrict__ cursor, int* __restrict__ perm) {
  const int e = blockIdx.x * 256 + threadIdx.x;
  const int pos = atomicAdd(&cursor[rcv[e]], 1);
  perm[pos] = e;
}

// ---------------------------------------------------------------------------
// Build the pre-split, pre-scaled weight table (R11 layout, verbatim).
// ---------------------------------------------------------------------------
__global__ __launch_bounds__(256) void k_permw(
    const float* __restrict__ w0, const float* __restrict__ w1,
    const float* __restrict__ w2, const float* __restrict__ w3,
    const float* __restrict__ mag_w, const float* __restrict__ lin_s,
    const float* __restrict__ lin_v, const float* __restrict__ skip_s,
    const float* __restrict__ skip_v,
    u16* __restrict__ wt_h, u16* __restrict__ wt_l)
{
  const int id = blockIdx.x * 256 + threadIdx.x;   // WT_TOTAL threads
  float val = 0.f;
  if (id < OFF_W1) {                       // W0: 4 tiles (nt)
    const int i = id - OFF_W0;
    const int tile = i >> 9, rem = i & 511, lane = rem >> 3, e = rem & 7;
    const int quad = lane >> 4, lrow = lane & 15;
    const int n = tile * 16 + lrow, k = quad * 8 + e;
    val = (k < 16) ? w0[k * 64 + n] * 0.25f : 0.f;
  } else if (id < OFF_W2) {                // W1: 8 tiles (nt*2+ks)
    const int i = id - OFF_W1;
    const int tile = i >> 9, rem = i & 511, lane = rem >> 3, e = rem & 7;
    const int quad = lane >> 4, lrow = lane & 15;
    const int n = (tile >> 1) * 16 + lrow, k = (tile & 1) * 32 + quad * 8 + e;
    val = w1[k * 64 + n] * 0.125f;
  } else if (id < OFF_W3M5) {              // W2: 8 tiles
    const int i = id - OFF_W2;
    const int tile = i >> 9, rem = i & 511, lane = rem >> 3, e = rem & 7;
    const int quad = lane >> 4, lrow = lane & 15;
    const int n = (tile >> 1) * 16 + lrow, k = (tile & 1) * 32 + quad * 8 + e;
    val = w2[k * 64 + n] * 0.125f;
  } else if (id < OFF_MAG) {               // W3M5: 40 tiles ((j*4+nt)*2+ks), K=64
    const int i = id - OFF_W3M5;
    const int tile = i >> 9, rem = i & 511, lane = rem >> 3, e = rem & 7;
    const int quad = lane >> 4, lrow = lane & 15;
    const int gnt = tile >> 1, ks = tile & 1;
    const int n = (gnt >> 2) * 64 + (gnt & 3) * 16 + lrow;   // tpv plane j = n>>6
    const int k = ks * 32 + quad * 8 + e;                    // k < 64
    val = w3[k * 320 + n] * 0.125f;
  } else if (id < OFF_LINS) {              // MAG: 52 tiles (p*4+nt), K=32
    const int i = id - OFF_MAG;
    const int tile = i >> 9, rem = i & 511, lane = rem >> 3, e = rem & 7;
    const int quad = lane >> 4, lrow = lane & 15;
    const int n = (tile >> 2) * 64 + (tile & 3) * 16 + lrow; // p = n>>6, u = n&63
    const int k = quad * 8 + e;
    const int p = n >> 6, u = n & 63;
    val = (k < 16) ? mag_w[k * 832 + p * 64 + u] * 0.25f : 0.f;
  } else if (id < OFF_LINV) {
    const int i = id - OFF_LINS, n = i / 320, k = i - n * 320;
    val = lin_s[k * 64 + n] * 0.05590169944f;
  } else if (id < OFF_SKS) {
    const int i = id - OFF_LINV, n = i >> 9, k = i & 511;
    val = lin_v[k * 64 + n] * 0.04419417382f;
  } else if (id < OFF_SKV) {
    const int i = id - OFF_SKS, w = i / 640, k = i - w * 640;
    val = skip_s[k * 64 + w] * 0.03952847075f;   // [u*10+v][w], 1/sqrt(640)
  } else if (id < WT_TOTAL) {
    const int i = id - OFF_SKV, w = i / 640, k = i - w * 640;
    val = skip_v[k * 64 + w] * 0.03952847075f;
  } else {
    return;
  }
  u16 hh, ll;
  split2(val, hh, ll);
  wt_h[id] = hh;
  wt_l[id] = ll;
}

// ---------------------------------------------------------------------------
// Permute edge data into receiver-grouped (perm) order + precompute:
//   snd_perm, ya_perm, dq_perm (tanh(q^2)), efm split pair.
// ---------------------------------------------------------------------------
__global__ __launch_bounds__(256) void k_build(
    const int* __restrict__ perm, const int* __restrict__ snd,
    const float* __restrict__ edge_attrs, const float* __restrict__ edge_feats,
    const float* __restrict__ mm_inv, const float* __restrict__ dens_w,
    int* __restrict__ snd_perm, float* __restrict__ ya_perm,
    float* __restrict__ dq_perm, u16* __restrict__ efm_h, u16* __restrict__ efm_l)
{
  const int pos = blockIdx.x * 256 + threadIdx.x;
  const int e = perm[pos];
  const int s = snd[e];
  snd_perm[pos] = s;
  reinterpret_cast<float4*>(ya_perm)[pos] = reinterpret_cast<const float4*>(edge_attrs)[e];
  const float4 ef0 = reinterpret_cast<const float4*>(edge_feats)[e * 2];
  const float4 ef1 = reinterpret_cast<const float4*>(edge_feats)[e * 2 + 1];
  const float4 mi0 = reinterpret_cast<const float4*>(mm_inv)[s * 2];
  const float4 mi1 = reinterpret_cast<const float4*>(mm_inv)[s * 2 + 1];
  float q = ef0.x * dens_w[0] + ef0.y * dens_w[1] + ef0.z * dens_w[2] + ef0.w * dens_w[3]
          + ef1.x * dens_w[4] + ef1.y * dens_w[5] + ef1.z * dens_w[6] + ef1.w * dens_w[7];
  q *= 0.35355339059f;   // 1/sqrt(8)
  dq_perm[pos] = tanhf(q * q);
  float vals[16] = { ef0.x, ef0.y, ef0.z, ef0.w, ef1.x, ef1.y, ef1.z, ef1.w,
                     mi0.x, mi0.y, mi0.z, mi0.w, mi1.x, mi1.y, mi1.z, mi1.w };
  u16 hh[16], ll[16];
  #pragma unroll
  for (int i = 0; i < 16; ++i) split2(vals[i], hh[i], ll[i]);
  reinterpret_cast<uint4*>(&efm_h[(size_t)pos * 16])[0] = reinterpret_cast<uint4*>(hh)[0];
  reinterpret_cast<uint4*>(&efm_h[(size_t)pos * 16])[1] = reinterpret_cast<uint4*>(hh)[1];
  reinterpret_cast<uint4*>(&efm_l[(size_t)pos * 16])[0] = reinterpret_cast<uint4*>(ll)[0];
  reinterpret_cast<uint4*>(&efm_l[(size_t)pos * 16])[1] = reinterpret_cast<uint4*>(ll)[1];
}

// ---------------------------------------------------------------------------
// Gather: TWO half-waves per node (halved serial edge chain, LDS reduction).
// ms/mv written as SINGLE bf16 (R13).
// ---------------------------------------------------------------------------
__global__ __launch_bounds__(256) void k_gather(
    const int* __restrict__ snd_perm,
    const float* __restrict__ ya_perm,
    const float* __restrict__ dq_perm,
    const float* __restrict__ mm_attrs,
    const float* __restrict__ s_buf,
    const float* __restrict__ v_buf,
    const u16* __restrict__ cmbP,
    const int* __restrict__ offs,
    u16* __restrict__ ms_h, u16* __restrict__ mv_h,
    float* __restrict__ dens)
{
  __shared__ float red[2][30][64];
  const int tid  = threadIdx.x;
  const int lane = tid & 63;
  const int nib  = tid >> 7;                 // node within block (0/1)
  const int half = (tid >> 6) & 1;           // segment half (0/1)
  const int n = blockIdx.x * 2 + nib;

  float acc_s[5] = {0.f, 0.f, 0.f, 0.f, 0.f};
  float acc_v[8][3] = {};
  float dacc = 0.f;
  const int start0 = offs[n], end0 = offs[n + 1];
  const int mid = start0 + ((end0 - start0 + 1) >> 1);
  const int start = half ? mid : start0;
  const int end   = half ? end0 : mid;

  int s_nx = 0;
  if (start < end) s_nx = snd_perm[start];
  for (int pos = start; pos < end; ++pos) {
    const int s = s_nx;
    if (pos + 1 < end) s_nx = snd_perm[pos + 1];

    const float4 ya = reinterpret_cast<const float4*>(ya_perm)[pos];
    const float4 mm = reinterpret_cast<const float4*>(mm_attrs)[s];
    dacc += dq_perm[pos];
    const float y0 = ya.x, y1x = ya.y, y1y = ya.z, y1z = ya.w;
    const float m0 = mm.x, m1x = mm.y, m1y = mm.z, m1z = mm.w;
    const float xs  = s_buf[s * 64 + lane];
    const float xvx = v_buf[(s * 3 + 0) * 64 + lane];
    const float xvy = v_buf[(s * 3 + 1) * 64 + lane];
    const float xvz = v_buf[(s * 3 + 2) * 64 + lane];

    float cp[13];
    #pragma unroll
    for (int p = 0; p < 13; ++p)
      cp[p] = bf2f(cmbP[(size_t)p * ((size_t)EE * 64) + (size_t)pos * 64 + lane]);

    // geometry (tpv folded into cp in k_edge)
    const float gs0 = xs * y0;
    const float gd  = (xvx * y1x + xvy * y1y + xvz * y1z) * 0.57735026919f;
    const float g0x = xs * y1x, g0y = xs * y1y, g0z = xs * y1z;
    const float g1x = xvx * y0, g1y = xvy * y0, g1z = xvz * y0;
    const float g2x = (xvy * y1z - xvz * y1y) * 0.70710678119f;
    const float g2y = (xvz * y1x - xvx * y1z) * 0.70710678119f;
    const float g2z = (xvx * y1y - xvy * y1x) * 0.70710678119f;

    acc_s[0]    += cp[0] * gs0 * m0;
    acc_v[0][0] += cp[1] * gs0 * m1x; acc_v[0][1] += cp[1] * gs0 * m1y; acc_v[0][2] += cp[1] * gs0 * m1z;
    acc_s[1]    += cp[2] * gd * m0;
    acc_v[1][0] += cp[3] * gd * m1x; acc_v[1][1] += cp[3] * gd * m1y; acc_v[1][2] += cp[3] * gd * m1z;

#define VV_BLOCK(vx, vy, vz, cA, cB, cC, vslotA, sslot, vslotB)                           \
    acc_v[vslotA][0] += (cA) * (vx) * m0;                                                 \
    acc_v[vslotA][1] += (cA) * (vy) * m0;                                                 \
    acc_v[vslotA][2] += (cA) * (vz) * m0;                                                 \
    acc_s[sslot] += (cB) * ((vx) * m1x + (vy) * m1y + (vz) * m1z) * 0.57735026919f;       \
    {                                                                                     \
      const float ccx = (vy) * m1z - (vz) * m1y;                                          \
      const float ccy = (vz) * m1x - (vx) * m1z;                                          \
      const float ccz = (vx) * m1y - (vy) * m1x;                                          \
      acc_v[vslotB][0] += (cC) * ccx * 0.70710678119f;                                    \
      acc_v[vslotB][1] += (cC) * ccy * 0.70710678119f;                                    \
      acc_v[vslotB][2] += (cC) * ccz * 0.70710678119f;                                    \
    }

    VV_BLOCK(g0x, g0y, g0z, cp[4], cp[5], cp[6], 2, 2, 3)
    VV_BLOCK(g1x, g1y, g1z, cp[7], cp[8], cp[9], 4, 3, 5)
    VV_BLOCK(g2x, g2y, g2z, cp[10], cp[11], cp[12], 6, 4, 7)
#undef VV_BLOCK
  }

  // ---- combine the two half-waves of each node via LDS ----
  if (half == 1) {
    #pragma unroll
    for (int j = 0; j < 5; ++j) red[nib][j][lane] = acc_s[j];
    #pragma unroll
    for (int p = 0; p < 8; ++p)
      #pragma unroll
      for (int i = 0; i < 3; ++i) red[nib][5 + p * 3 + i][lane] = acc_v[p][i];
    red[nib][29][lane] = dacc;
  }
  __syncthreads();
  if (half == 0) {
    #pragma unroll
    for (int j = 0; j < 5; ++j) acc_s[j] += red[nib][j][lane];
    #pragma unroll
    for (int p = 0; p < 8; ++p)
      #pragma unroll
      for (int i = 0; i < 3; ++i) acc_v[p][i] += red[nib][5 + p * 3 + i][lane];
    dacc += red[nib][29][lane];

    #pragma unroll
    for (int j = 0; j < 5; ++j)
      ms_h[(size_t)n * 320 + j * 64 + lane] = f2bf(acc_s[j]);
    #pragma unroll
    for (int p = 0; p < 8; ++p)
      #pragma unroll
      for (int i = 0; i < 3; ++i)
        mv_h[((size_t)n * 3 + i) * 512 + p * 64 + lane] = f2bf(acc_v[p][i]);
    if (lane == 0) dens[n] = dacc;
  }
}

// ---------------------------------------------------------------------------
extern "C" void kernel_launch(void* const* d_in, const int* in_sizes, int n_in,
                              void* d_out, int out_size, void* d_ws, size_t ws_size,
                              hipStream_t stream)
{
  const float* node_attrs = (const float*)d_in[0];
  const float* node_feats = (const float*)d_in[1];
  const float* edge_attrs = (const float*)d_in[2];
  const float* edge_feats = (const float*)d_in[3];
  const int*   edge_index = (const int*)d_in[4];
  const float* mm_inv     = (const float*)d_in[5];
  const float* mm_attrs   = (const float*)d_in[6];
  const float* W_up_s     = (const float*)d_in[7];
  const float* W_up_v     = (const float*)d_in[8];
  const float* w0         = (const float*)d_in[9];
  const float* w1         = (const float*)d_in[10];
  const float* w2         = (const float*)d_in[11];
  const float* w3         = (const float*)d_in[12];
  const float* mag_w      = (const float*)d_in[13];
  const float* dens_w     = (const float*)d_in[14];
  const float* lin_s      = (const float*)d_in[15];
  const float* lin_v      = (const float*)d_in[16];
  const float* skip_s     = (const float*)d_in[17];
  const float* skip_v     = (const float*)d_in[18];
  float* out = (float*)d_out;

  char* wp = (char*)d_ws;
  auto alloc = [&](size_t b) { char* p = wp; wp += (b + 255) & ~(size_t)255; return p; };
  float* s_buf  = (float*)alloc((size_t)NN * 64 * 4);       // 2.10 MB
  float* v_buf  = (float*)alloc((size_t)NN * 192 * 4);      // 6.29 MB
  float* ya_p   = (float*)alloc((size_t)EE * 4 * 4);        // 1.05 MB
  float* dq_p   = (float*)alloc((size_t)EE * 4);            // 0.26 MB
  int*   snd_p  = (int*)alloc((size_t)EE * 4);              // 0.26 MB
  u16*   efm_h  = (u16*)alloc((size_t)EE * 16 * 2);         // 2.10 MB
  u16*   efm_l  = (u16*)alloc((size_t)EE * 16 * 2);         // 2.10 MB
  u16*   ms_h   = (u16*)alloc((size_t)NN * 320 * 2);        // 5.25 MB
  u16*   cmbP   = (u16*)alloc((size_t)13 * EE * 64 * 2);    // 109 MB  [13][EE][64]
  u16*   mv_h   = (u16*)alloc((size_t)NN * 1536 * 2);       // 25.2 MB
  float* dens   = (float*)alloc((size_t)NN * 4);
  int*   counts = (int*)alloc((size_t)NN * 4);
  int*   offs   = (int*)alloc((size_t)(NN + 1) * 4);
  int*   cursor = (int*)alloc((size_t)NN * 4);
  int*   perm   = (int*)alloc((size_t)EE * 4);
  u16*   wt_h   = (u16*)alloc((size_t)WT_TOTAL * 2);        // 0.39 MB
  u16*   wt_l   = (u16*)alloc((size_t)WT_TOTAL * 2);        // 0.39 MB

  const int* snd = edge_index;
  const int* rcv = edge_index + EE;

  // CSR + permuted edge data + pre-split fragment-ordered weight table
  hipMemsetAsync(counts, 0, (size_t)NN * 4, stream);
  k_count<<<EE / 256, 256, 0, stream>>>(rcv, counts);
  k_scan<<<1, 1024, 0, stream>>>(counts, offs, cursor);
  k_fill<<<EE / 256, 256, 0, stream>>>(rcv, cursor, perm);
  k_build<<<EE / 256, 256, 0, stream>>>(perm, snd, edge_attrs, edge_feats, mm_inv, dens_w,
                                        snd_p, ya_p, dq_p, efm_h, efm_l);
  k_permw<<<(WT_TOTAL + 255) / 256, 256, 0, stream>>>(w0, w1, w2, w3, mag_w, lin_s, lin_v,
                                                     skip_s, skip_v, wt_h, wt_l);

  // node up-projections, merged (z==0: s, z=1..3: v components)
  k_gemm2<<<dim3(NN / 32, 1, 4), 256, 0, stream>>>(
      node_feats, W_up_s, W_up_v, s_buf, v_buf);

  // FUSED edge pipeline: w0/w1/w2 + 13 product planes (tpv folded in)
  k_edge<<<EE / 64, 256, 0, stream>>>(efm_h, efm_l, wt_h, wt_l, cmbP);

  // per-node gather (2 half-waves/node) + tensor product + segment sum
  k_gather<<<NN / 2, 256, 0, stream>>>(snd_p, ya_p, dq_p, mm_attrs,
                                       s_buf, v_buf, cmbP, offs,
                                       ms_h, mv_h, dens);

  // node linears + skip contraction, fused block-locally (direct out write)
  k_lsk<<<NN / 32 + NN * 3 / 32, 256, 0, stream>>>(
      ms_h, mv_h, node_attrs, wt_h, wt_l, dens, out);
}